// Round 1
// baseline (2751.893 us; speedup 1.0000x reference)
//
#include <hip/hip_runtime.h>
#include <math.h>

constexpr int B  = 2;
constexpr int N  = 2048;
constexpr int C  = 1024;
constexpr int H  = 16;
constexpr int DK = 64;
constexpr int NTOP = 512;
constexpr float SCALE = 0.125f;  // 1/sqrt(64)

// ---------------------------------------------------------------------------
// GEMM: out[m,n] = sum_k A[m,k] * W[n,k] + bias[n]
// A: (M,K) row-major, W: (Nout,K) row-major.
// MODE 0: scatter into q/k/v buffers (Nout = 3C), layout (B*H, N, DK)
// MODE 1: plain write to (B*N, C)
// ---------------------------------------------------------------------------
template <int MODE>
__global__ __launch_bounds__(256) void gemm_bias(
    const float* __restrict__ A, const float* __restrict__ W,
    const float* __restrict__ bias, float* __restrict__ out,
    float* __restrict__ qb, float* __restrict__ kb, float* __restrict__ vb,
    int M, int Nout, int K)
{
    __shared__ float As[64][17];  // [m][k], padded
    __shared__ float Bs[64][17];  // [n][k], padded

    const int tid = threadIdx.x;
    const int tx = tid & 15;        // col group
    const int ty = tid >> 4;        // row group
    const int m0 = blockIdx.y * 64;
    const int n0 = blockIdx.x * 64;

    float acc[4][4] = {};

    for (int k0 = 0; k0 < K; k0 += 16) {
        #pragma unroll
        for (int i = 0; i < 4; ++i) {
            int e  = tid + i * 256;      // [0,1024)
            int r  = e >> 4;             // row in tile
            int kk = e & 15;             // k in tile
            As[r][kk] = A[(size_t)(m0 + r) * K + k0 + kk];
            Bs[r][kk] = W[(size_t)(n0 + r) * K + k0 + kk];
        }
        __syncthreads();
        #pragma unroll
        for (int kk = 0; kk < 16; ++kk) {
            float a[4], b[4];
            #pragma unroll
            for (int i = 0; i < 4; ++i) a[i] = As[ty * 4 + i][kk];
            #pragma unroll
            for (int j = 0; j < 4; ++j) b[j] = Bs[tx + 16 * j][kk];
            #pragma unroll
            for (int i = 0; i < 4; ++i)
                #pragma unroll
                for (int j = 0; j < 4; ++j)
                    acc[i][j] = fmaf(a[i], b[j], acc[i][j]);
        }
        __syncthreads();
    }

    #pragma unroll
    for (int i = 0; i < 4; ++i) {
        int m  = m0 + ty * 4 + i;
        int bb = m / N;
        int n  = m % N;
        #pragma unroll
        for (int j = 0; j < 4; ++j) {
            int oc = n0 + tx + 16 * j;
            float val = acc[i][j] + bias[oc];
            if (MODE == 0) {
                int t = oc >> 10;            // 0=q,1=k,2=v
                int h = (oc >> 6) & 15;
                int d = oc & 63;
                float* dst = (t == 0) ? qb : (t == 1) ? kb : vb;
                dst[(((size_t)bb * H + h) * N + n) * DK + d] = val;
            } else {
                out[(size_t)m * C + oc] = val;
            }
        }
    }
}

// ---------------------------------------------------------------------------
// Row stats: M[bh,q] = scale*(max_k dot - mean_k dot); rowmax = scale*max_k dot
// One thread per q row. grid (N/256, B*H)
// ---------------------------------------------------------------------------
__global__ __launch_bounds__(256) void row_stats(
    const float* __restrict__ q, const float* __restrict__ k,
    float* __restrict__ Mout, float* __restrict__ rowmax)
{
    const int bh = blockIdx.y;
    const int qi = blockIdx.x * 256 + threadIdx.x;

    float qr[DK];
    const float* qrow = q + ((size_t)bh * N + qi) * DK;
    #pragma unroll
    for (int d = 0; d < DK; ++d) qr[d] = qrow[d];

    __shared__ float Ks[64][DK];
    float mx = -1e30f;
    float sm = 0.f;

    for (int kt = 0; kt < N; kt += 64) {
        __syncthreads();
        for (int e = threadIdx.x; e < 64 * DK; e += 256) {
            Ks[e >> 6][e & 63] = k[((size_t)bh * N + kt) * DK + e];
        }
        __syncthreads();
        #pragma unroll 2
        for (int j = 0; j < 64; ++j) {
            float s = 0.f;
            #pragma unroll
            for (int d = 0; d < DK; ++d) s = fmaf(qr[d], Ks[j][d], s);
            mx = fmaxf(mx, s);
            sm += s;
        }
    }
    const size_t idx = (size_t)bh * N + qi;
    Mout[idx]   = SCALE * mx - (SCALE * sm) / (float)N;
    rowmax[idx] = SCALE * mx;
}

// ---------------------------------------------------------------------------
// Top-k keep flags: rank-based, ties broken by lower index (== lax.top_k)
// grid: B*H blocks, 256 threads
// ---------------------------------------------------------------------------
__global__ __launch_bounds__(256) void topk_keep(
    const float* __restrict__ Mv, int* __restrict__ keep)
{
    const int bh = blockIdx.x;
    __shared__ float Ms[N];
    for (int e = threadIdx.x; e < N; e += 256) Ms[e] = Mv[(size_t)bh * N + e];
    __syncthreads();
    for (int qi = threadIdx.x; qi < N; qi += 256) {
        const float mq = Ms[qi];
        int rank = 0;
        for (int j = 0; j < N; ++j) {
            float mj = Ms[j];
            rank += (mj > mq) || (mj == mq && j < qi);
        }
        keep[(size_t)bh * N + qi] = (rank < NTOP) ? 1 : 0;
    }
}

// ---------------------------------------------------------------------------
// vmean[bh,d] = mean over k of v[bh,k,d].  grid: B*H blocks, 64 threads
// ---------------------------------------------------------------------------
__global__ __launch_bounds__(64) void vmean_kernel(
    const float* __restrict__ v, float* __restrict__ vmean)
{
    const int bh = blockIdx.x;
    const int d  = threadIdx.x;
    float s = 0.f;
    for (int kk = 0; kk < N; ++kk) s += v[((size_t)bh * N + kk) * DK + d];
    vmean[bh * DK + d] = s / (float)N;
}

// ---------------------------------------------------------------------------
// Attention: kept rows -> exact softmax (uses precomputed rowmax), single pass.
// non-kept rows -> vmean.  One thread per q row. grid (N/256, B*H)
// Output scattered to (B, N, C) with c = h*DK + d.
// ---------------------------------------------------------------------------
__global__ __launch_bounds__(256) void attn_kernel(
    const float* __restrict__ q, const float* __restrict__ k,
    const float* __restrict__ v, const float* __restrict__ rowmax,
    const int* __restrict__ keep, const float* __restrict__ vmean,
    float* __restrict__ attn_out)
{
    const int bh = blockIdx.y;
    const int qi = blockIdx.x * 256 + threadIdx.x;
    const int b  = bh / H;
    const int h  = bh % H;

    float qr[DK];
    const float* qrow = q + ((size_t)bh * N + qi) * DK;
    #pragma unroll
    for (int d = 0; d < DK; ++d) qr[d] = qrow[d];

    const float rmax = rowmax[(size_t)bh * N + qi];
    float acc[DK] = {};
    float l = 0.f;

    __shared__ float Ks[32][DK];
    __shared__ float Vs[32][DK];

    for (int kt = 0; kt < N; kt += 32) {
        __syncthreads();
        for (int e = threadIdx.x; e < 32 * DK; e += 256) {
            Ks[e >> 6][e & 63] = k[((size_t)bh * N + kt) * DK + e];
            Vs[e >> 6][e & 63] = v[((size_t)bh * N + kt) * DK + e];
        }
        __syncthreads();
        #pragma unroll 2
        for (int j = 0; j < 32; ++j) {
            float s = 0.f;
            #pragma unroll
            for (int d = 0; d < DK; ++d) s = fmaf(qr[d], Ks[j][d], s);
            float p = __expf(s * SCALE - rmax);
            l += p;
            #pragma unroll
            for (int d = 0; d < DK; ++d) acc[d] = fmaf(p, Vs[j][d], acc[d]);
        }
    }

    const float inv = 1.f / l;
    const int   kp  = keep[(size_t)bh * N + qi];
    const float* vm = vmean + bh * DK;
    float* orow = attn_out + ((size_t)b * N + qi) * C + h * DK;
    #pragma unroll
    for (int d = 0; d < DK; ++d) orow[d] = kp ? acc[d] * inv : vm[d];
}

// ---------------------------------------------------------------------------
extern "C" void kernel_launch(void* const* d_in, const int* in_sizes, int n_in,
                              void* d_out, int out_size, void* d_ws, size_t ws_size,
                              hipStream_t stream)
{
    const float* x    = (const float*)d_in[0];
    const float* Wqkv = (const float*)d_in[1];
    const float* bqkv = (const float*)d_in[2];
    const float* Wout = (const float*)d_in[3];
    const float* bout = (const float*)d_in[4];
    float* out = (float*)d_out;

    char* ws = (char*)d_ws;
    size_t off = 0;
    auto alloc = [&](size_t bytes) -> void* {
        void* p = ws + off;
        off += (bytes + 255) & ~(size_t)255;
        return p;
    };

    const size_t BHND = (size_t)B * H * N * DK;  // 4,194,304
    float* q        = (float*)alloc(BHND * 4);
    float* kbuf     = (float*)alloc(BHND * 4);
    float* vbuf     = (float*)alloc(BHND * 4);
    float* attn_out = (float*)alloc((size_t)B * N * C * 4);
    float* Mbuf     = (float*)alloc((size_t)B * H * N * 4);
    float* rmaxbuf  = (float*)alloc((size_t)B * H * N * 4);
    int*   keep     = (int*)  alloc((size_t)B * H * N * 4);
    float* vmeanbuf = (float*)alloc((size_t)B * H * DK * 4);

    // 1. QKV projection: (4096 x 1024) @ (3072 x 1024)^T
    gemm_bias<0><<<dim3(3072 / 64, (B * N) / 64), 256, 0, stream>>>(
        x, Wqkv, bqkv, nullptr, q, kbuf, vbuf, B * N, 3 * C, C);

    // 2. Row stats (max, mean of score rows)
    row_stats<<<dim3(N / 256, B * H), 256, 0, stream>>>(q, kbuf, Mbuf, rmaxbuf);

    // 3. Top-512 keep flags per (b,h)
    topk_keep<<<B * H, 256, 0, stream>>>(Mbuf, keep);

    // 4. V column means (output for fully-masked rows)
    vmean_kernel<<<B * H, 64, 0, stream>>>(vbuf, vmeanbuf);

    // 5. Attention
    attn_kernel<<<dim3(N / 256, B * H), 256, 0, stream>>>(
        q, kbuf, vbuf, rmaxbuf, keep, vmeanbuf, attn_out);

    // 6. Output projection: (4096 x 1024) @ (1024 x 1024)^T
    gemm_bias<1><<<dim3(C / 64, (B * N) / 64), 256, 0, stream>>>(
        attn_out, Wout, bout, out, nullptr, nullptr, nullptr, B * N, C, C);
}

// Round 2
// 2215.074 us; speedup vs baseline: 1.2423x; 1.2423x over previous
//
#include <hip/hip_runtime.h>
#include <math.h>

constexpr int B  = 2;
constexpr int N  = 2048;
constexpr int C  = 1024;
constexpr int H  = 16;
constexpr int DK = 64;
constexpr int NTOP = 512;
constexpr float SCALE = 0.125f;  // 1/sqrt(64)

// ---------------------------------------------------------------------------
// GEMM: out[m,n] = sum_k A[m,k]*W[n,k] + bias[n].  128x128 tile, 8x8/thread.
// MODE 0: scatter to q/k/v (B*H, N, DK).  MODE 1: plain (B*N, C).
// ---------------------------------------------------------------------------
template <int MODE>
__global__ __launch_bounds__(256) void gemm_bias(
    const float* __restrict__ A, const float* __restrict__ W,
    const float* __restrict__ bias, float* __restrict__ out,
    float* __restrict__ qb, float* __restrict__ kb, float* __restrict__ vb,
    int M, int Nout, int K)
{
    constexpr int BK = 16;
    __shared__ float As[BK][128];
    __shared__ float Bs[BK][128];

    const int tid = threadIdx.x;
    const int tx = tid & 15;
    const int ty = tid >> 4;
    const int m0 = blockIdx.y * 128;
    const int n0 = blockIdx.x * 128;
    const int ar  = tid >> 2;          // 0..63 staging row
    const int kk4 = (tid & 3) * 4;     // staging k offset

    const float* Aptr = A + (size_t)(m0 + ar) * K + kk4;
    const float* Wptr = W + (size_t)(n0 + ar) * K + kk4;

    float acc[8][8] = {};

    for (int k0 = 0; k0 < K; k0 += BK) {
        float4 a0 = *(const float4*)(Aptr + k0);
        float4 a1 = *(const float4*)(Aptr + (size_t)64 * K + k0);
        float4 b0 = *(const float4*)(Wptr + k0);
        float4 b1 = *(const float4*)(Wptr + (size_t)64 * K + k0);
        __syncthreads();
        As[kk4+0][ar]    = a0.x; As[kk4+1][ar]    = a0.y; As[kk4+2][ar]    = a0.z; As[kk4+3][ar]    = a0.w;
        As[kk4+0][ar+64] = a1.x; As[kk4+1][ar+64] = a1.y; As[kk4+2][ar+64] = a1.z; As[kk4+3][ar+64] = a1.w;
        Bs[kk4+0][ar]    = b0.x; Bs[kk4+1][ar]    = b0.y; Bs[kk4+2][ar]    = b0.z; Bs[kk4+3][ar]    = b0.w;
        Bs[kk4+0][ar+64] = b1.x; Bs[kk4+1][ar+64] = b1.y; Bs[kk4+2][ar+64] = b1.z; Bs[kk4+3][ar+64] = b1.w;
        __syncthreads();
        #pragma unroll
        for (int kk = 0; kk < BK; ++kk) {
            const float4 a0v = *(const float4*)&As[kk][ty*4];
            const float4 a1v = *(const float4*)&As[kk][ty*4+64];
            const float4 b0v = *(const float4*)&Bs[kk][tx*4];
            const float4 b1v = *(const float4*)&Bs[kk][tx*4+64];
            const float av[8] = {a0v.x,a0v.y,a0v.z,a0v.w,a1v.x,a1v.y,a1v.z,a1v.w};
            const float bv[8] = {b0v.x,b0v.y,b0v.z,b0v.w,b1v.x,b1v.y,b1v.z,b1v.w};
            #pragma unroll
            for (int i = 0; i < 8; ++i)
                #pragma unroll
                for (int j = 0; j < 8; ++j)
                    acc[i][j] = fmaf(av[i], bv[j], acc[i][j]);
        }
    }

    #pragma unroll
    for (int ii = 0; ii < 8; ++ii) {
        const int m  = m0 + ty*4 + (ii & 3) + (ii >> 2) * 64;
        const int bb = m >> 11;           // / N (2048)
        const int n  = m & (N - 1);
        #pragma unroll
        for (int jh = 0; jh < 2; ++jh) {
            const int oc = n0 + tx*4 + jh*64;
            float4 r;
            r.x = acc[ii][jh*4+0] + bias[oc+0];
            r.y = acc[ii][jh*4+1] + bias[oc+1];
            r.z = acc[ii][jh*4+2] + bias[oc+2];
            r.w = acc[ii][jh*4+3] + bias[oc+3];
            if (MODE == 0) {
                const int t = oc >> 10;
                const int h = (oc >> 6) & 15;
                const int d = oc & 63;
                float* dst = (t == 0) ? qb : (t == 1) ? kb : vb;
                *(float4*)&dst[(((size_t)bb * H + h) * N + n) * DK + d] = r;
            } else {
                *(float4*)&out[(size_t)m * C + oc] = r;
            }
        }
    }
}

// ---------------------------------------------------------------------------
// Row stats: block = 64 q-rows, K swept in 64-key tiles.
// thread (sq=tid&15, sk=tid>>4): q rows {sq+16t}, keys {4sk+j}.
// ---------------------------------------------------------------------------
__global__ __launch_bounds__(256) void row_stats(
    const float* __restrict__ qg_, const float* __restrict__ kg_,
    float* __restrict__ Mout, float* __restrict__ rowmax)
{
    constexpr int QB = 64, KB = 64, LS = 68;
    __shared__ float Qs[QB * LS];
    __shared__ float Ks[KB * LS];
    __shared__ float Mx[16][QB];
    __shared__ float Sm[16][QB];

    const int tid = threadIdx.x;
    const int bh = blockIdx.y;
    const int q0 = blockIdx.x * QB;
    const int sq = tid & 15;
    const int sk = tid >> 4;

    const size_t qbase = ((size_t)bh * N + q0) * DK;
    #pragma unroll
    for (int w = 0; w < 4; ++w) {
        int idx = (tid + w * 256) * 4;
        int r = idx >> 6, d = idx & 63;
        *(float4*)&Qs[r * LS + d] = *(const float4*)&qg_[qbase + idx];
    }

    float mx[4] = {-1e30f, -1e30f, -1e30f, -1e30f};
    float sm[4] = {};

    for (int kt = 0; kt < N; kt += KB) {
        const size_t kbase = ((size_t)bh * N + kt) * DK;
        __syncthreads();
        #pragma unroll
        for (int w = 0; w < 4; ++w) {
            int idx = (tid + w * 256) * 4;
            int r = idx >> 6, d = idx & 63;
            *(float4*)&Ks[r * LS + d] = *(const float4*)&kg_[kbase + idx];
        }
        __syncthreads();
        float s[4][4] = {};
        #pragma unroll
        for (int d4 = 0; d4 < 16; ++d4) {
            float4 qv[4], kv[4];
            #pragma unroll
            for (int t = 0; t < 4; ++t) qv[t] = *(const float4*)&Qs[(sq + 16*t) * LS + d4*4];
            #pragma unroll
            for (int j = 0; j < 4; ++j) kv[j] = *(const float4*)&Ks[(4*sk + j) * LS + d4*4];
            #pragma unroll
            for (int t = 0; t < 4; ++t)
                #pragma unroll
                for (int j = 0; j < 4; ++j)
                    s[t][j] += qv[t].x*kv[j].x + qv[t].y*kv[j].y + qv[t].z*kv[j].z + qv[t].w*kv[j].w;
        }
        #pragma unroll
        for (int t = 0; t < 4; ++t) {
            mx[t] = fmaxf(mx[t], fmaxf(fmaxf(s[t][0], s[t][1]), fmaxf(s[t][2], s[t][3])));
            sm[t] += s[t][0] + s[t][1] + s[t][2] + s[t][3];
        }
    }

    #pragma unroll
    for (int t = 0; t < 4; ++t) { Mx[sk][sq + 16*t] = mx[t]; Sm[sk][sq + 16*t] = sm[t]; }
    __syncthreads();
    if (tid < QB) {
        float m = -1e30f, s = 0.f;
        #pragma unroll
        for (int g = 0; g < 16; ++g) { m = fmaxf(m, Mx[g][tid]); s += Sm[g][tid]; }
        const size_t idx = (size_t)bh * N + q0 + tid;
        Mout[idx]   = SCALE * m - (SCALE * s) / (float)N;
        rowmax[idx] = SCALE * m;
    }
}

// ---------------------------------------------------------------------------
// Top-k keep flags (rank-based, ties by lower index). grid (N/256, B*H)
// ---------------------------------------------------------------------------
__global__ __launch_bounds__(256) void topk_keep(
    const float* __restrict__ Mv, int* __restrict__ keep)
{
    const int bh = blockIdx.y;
    const int qi = blockIdx.x * 256 + threadIdx.x;
    __shared__ float Ms[N];
    for (int e = threadIdx.x; e < N; e += 256) Ms[e] = Mv[(size_t)bh * N + e];
    __syncthreads();
    const float mq = Ms[qi];
    int rank = 0;
    for (int j = 0; j < N; ++j) {
        float mj = Ms[j];
        rank += (mj > mq) || (mj == mq && j < qi);
    }
    keep[(size_t)bh * N + qi] = (rank < NTOP) ? 1 : 0;
}

// ---------------------------------------------------------------------------
// vmean[bh,d] = mean_k v[bh,k,d].  grid B*H, 256 threads.
// ---------------------------------------------------------------------------
__global__ __launch_bounds__(256) void vmean_kernel(
    const float* __restrict__ v, float* __restrict__ vmean)
{
    const int bh = blockIdx.x;
    const int d   = threadIdx.x & 63;
    const int seg = threadIdx.x >> 6;
    float s = 0.f;
    for (int kk = seg; kk < N; kk += 4) s += v[((size_t)bh * N + kk) * DK + d];
    __shared__ float part[4][64];
    part[seg][d] = s;
    __syncthreads();
    if (threadIdx.x < 64) {
        float t = part[0][d] + part[1][d] + part[2][d] + part[3][d];
        vmean[bh * DK + d] = t / (float)N;
    }
}

// ---------------------------------------------------------------------------
// Attention: block = 64 q-rows x full K sweep (64-key tiles).
// score phase: thread (sq,sk) does 4q x 4k; PV phase: thread (dg,qh) 4q x 4d.
// K and V time-share one LDS buffer. Exact softmax via precomputed rowmax.
// ---------------------------------------------------------------------------
__global__ __launch_bounds__(256) void attn_kernel(
    const float* __restrict__ qg_, const float* __restrict__ kg_,
    const float* __restrict__ vg_, const float* __restrict__ rowmax,
    const int* __restrict__ keep, const float* __restrict__ vmean,
    float* __restrict__ attn_out)
{
    constexpr int QB = 64, KB = 64, LS = 68;
    __shared__ float Qs[QB * LS];
    __shared__ float KVs[KB * LS];
    __shared__ float Ps[QB * LS];
    __shared__ float Lp[16][QB];
    __shared__ float Linv[QB];

    const int tid = threadIdx.x;
    const int bh = blockIdx.y;
    const int q0 = blockIdx.x * QB;
    const int b = bh >> 4, h = bh & 15;
    const int sq = tid & 15, sk = tid >> 4;   // score mapping
    const int dg = tid & 15, qh = tid >> 4;   // PV mapping

    const size_t qbase = ((size_t)bh * N + q0) * DK;
    #pragma unroll
    for (int w = 0; w < 4; ++w) {
        int idx = (tid + w * 256) * 4;
        int r = idx >> 6, d = idx & 63;
        *(float4*)&Qs[r * LS + d] = *(const float4*)&qg_[qbase + idx];
    }
    float rmax[4], lp[4] = {};
    #pragma unroll
    for (int t = 0; t < 4; ++t)
        rmax[t] = rowmax[(size_t)bh * N + q0 + sq + 16*t];

    float oacc[4][4] = {};

    for (int kt = 0; kt < N; kt += KB) {
        const size_t kbase = ((size_t)bh * N + kt) * DK;
        __syncthreads();                       // prev PV done with KVs/Ps
        #pragma unroll
        for (int w = 0; w < 4; ++w) {
            int idx = (tid + w * 256) * 4;
            int r = idx >> 6, d = idx & 63;
            *(float4*)&KVs[r * LS + d] = *(const float4*)&kg_[kbase + idx];
        }
        __syncthreads();                       // K staged
        float s[4][4] = {};
        #pragma unroll
        for (int d4 = 0; d4 < 16; ++d4) {
            float4 qv[4], kv[4];
            #pragma unroll
            for (int t = 0; t < 4; ++t) qv[t] = *(const float4*)&Qs[(sq + 16*t) * LS + d4*4];
            #pragma unroll
            for (int j = 0; j < 4; ++j) kv[j] = *(const float4*)&KVs[(4*sk + j) * LS + d4*4];
            #pragma unroll
            for (int t = 0; t < 4; ++t)
                #pragma unroll
                for (int j = 0; j < 4; ++j)
                    s[t][j] += qv[t].x*kv[j].x + qv[t].y*kv[j].y + qv[t].z*kv[j].z + qv[t].w*kv[j].w;
        }
        #pragma unroll
        for (int t = 0; t < 4; ++t) {
            float4 p4;
            p4.x = __expf(s[t][0] * SCALE - rmax[t]);
            p4.y = __expf(s[t][1] * SCALE - rmax[t]);
            p4.z = __expf(s[t][2] * SCALE - rmax[t]);
            p4.w = __expf(s[t][3] * SCALE - rmax[t]);
            lp[t] += p4.x + p4.y + p4.z + p4.w;
            *(float4*)&Ps[(sq + 16*t) * LS + 4*sk] = p4;
        }
        __syncthreads();                       // Ps ready, K reads done
        #pragma unroll
        for (int w = 0; w < 4; ++w) {
            int idx = (tid + w * 256) * 4;
            int r = idx >> 6, d = idx & 63;
            *(float4*)&KVs[r * LS + d] = *(const float4*)&vg_[kbase + idx];
        }
        __syncthreads();                       // V staged
        #pragma unroll
        for (int j4 = 0; j4 < 16; ++j4) {
            float4 vv[4];
            #pragma unroll
            for (int j = 0; j < 4; ++j) vv[j] = *(const float4*)&KVs[(4*j4 + j) * LS + 4*dg];
            #pragma unroll
            for (int t = 0; t < 4; ++t) {
                const float4 pv = *(const float4*)&Ps[(qh + 16*t) * LS + 4*j4];
                oacc[t][0] += pv.x*vv[0].x + pv.y*vv[1].x + pv.z*vv[2].x + pv.w*vv[3].x;
                oacc[t][1] += pv.x*vv[0].y + pv.y*vv[1].y + pv.z*vv[2].y + pv.w*vv[3].y;
                oacc[t][2] += pv.x*vv[0].z + pv.y*vv[1].z + pv.z*vv[2].z + pv.w*vv[3].z;
                oacc[t][3] += pv.x*vv[0].w + pv.y*vv[1].w + pv.z*vv[2].w + pv.w*vv[3].w;
            }
        }
    }

    #pragma unroll
    for (int t = 0; t < 4; ++t) Lp[sk][sq + 16*t] = lp[t];
    __syncthreads();
    if (tid < QB) {
        float l = 0.f;
        #pragma unroll
        for (int g = 0; g < 16; ++g) l += Lp[g][tid];
        Linv[tid] = 1.0f / l;
    }
    __syncthreads();

    #pragma unroll
    for (int t = 0; t < 4; ++t) {
        const int qi = q0 + qh + 16*t;
        const int kp = keep[(size_t)bh * N + qi];
        const float inv = Linv[qh + 16*t];
        float4 r;
        if (kp) {
            r.x = oacc[t][0] * inv; r.y = oacc[t][1] * inv;
            r.z = oacc[t][2] * inv; r.w = oacc[t][3] * inv;
        } else {
            r = *(const float4*)&vmean[bh * DK + 4*dg];
        }
        *(float4*)&attn_out[((size_t)b * N + qi) * C + h * DK + 4*dg] = r;
    }
}

// ---------------------------------------------------------------------------
extern "C" void kernel_launch(void* const* d_in, const int* in_sizes, int n_in,
                              void* d_out, int out_size, void* d_ws, size_t ws_size,
                              hipStream_t stream)
{
    const float* x    = (const float*)d_in[0];
    const float* Wqkv = (const float*)d_in[1];
    const float* bqkv = (const float*)d_in[2];
    const float* Wout = (const float*)d_in[3];
    const float* bout = (const float*)d_in[4];
    float* out = (float*)d_out;

    char* ws = (char*)d_ws;
    size_t off = 0;
    auto alloc = [&](size_t bytes) -> void* {
        void* p = ws + off;
        off += (bytes + 255) & ~(size_t)255;
        return p;
    };

    const size_t BHND = (size_t)B * H * N * DK;
    float* q        = (float*)alloc(BHND * 4);
    float* kbuf     = (float*)alloc(BHND * 4);
    float* vbuf     = (float*)alloc(BHND * 4);
    float* attn_out = (float*)alloc((size_t)B * N * C * 4);
    float* Mbuf     = (float*)alloc((size_t)B * H * N * 4);
    float* rmaxbuf  = (float*)alloc((size_t)B * H * N * 4);
    int*   keep     = (int*)  alloc((size_t)B * H * N * 4);
    float* vmeanbuf = (float*)alloc((size_t)B * H * DK * 4);

    // 1. QKV projection
    gemm_bias<0><<<dim3(3 * C / 128, (B * N) / 128), 256, 0, stream>>>(
        x, Wqkv, bqkv, nullptr, q, kbuf, vbuf, B * N, 3 * C, C);

    // 2. Row stats
    row_stats<<<dim3(N / 64, B * H), 256, 0, stream>>>(q, kbuf, Mbuf, rmaxbuf);

    // 3. Top-512 keep flags
    topk_keep<<<dim3(N / 256, B * H), 256, 0, stream>>>(Mbuf, keep);

    // 4. V column means
    vmean_kernel<<<B * H, 256, 0, stream>>>(vbuf, vmeanbuf);

    // 5. Attention
    attn_kernel<<<dim3(N / 64, B * H), 256, 0, stream>>>(
        q, kbuf, vbuf, rmaxbuf, keep, vmeanbuf, attn_out);

    // 6. Output projection
    gemm_bias<1><<<dim3(C / 128, (B * N) / 128), 256, 0, stream>>>(
        attn_out, Wout, bout, out, nullptr, nullptr, nullptr, B * N, C, C);
}

// Round 3
// 1176.204 us; speedup vs baseline: 2.3396x; 1.8832x over previous
//
#include <hip/hip_runtime.h>
#include <math.h>

typedef unsigned short u16;
typedef __attribute__((ext_vector_type(8))) short short8v;  // 8 bf16 operand frag
typedef __attribute__((ext_vector_type(4))) float f32x4;    // MFMA accumulator

constexpr int B  = 2;
constexpr int N  = 2048;
constexpr int C  = 1024;
constexpr int H  = 16;
constexpr int DK = 64;
constexpr int NTOP = 512;
constexpr float SCALE = 0.125f;  // 1/sqrt(64)

// ---------------------------------------------------------------------------
// fp32 -> bf16 hi/lo split (RNE): hi = bf16(x), lo = bf16(x - hi)
// ---------------------------------------------------------------------------
__device__ __forceinline__ u16 bf16_rne(float x) {
    unsigned u = __float_as_uint(x);
    unsigned r = u + 0x7fffu + ((u >> 16) & 1u);
    return (u16)(r >> 16);
}

__global__ __launch_bounds__(256) void convert_hilo(
    const float* __restrict__ src, u16* __restrict__ hi, u16* __restrict__ lo, int n)
{
    int i = (blockIdx.x * 256 + threadIdx.x) * 4;
    if (i >= n) return;
    float4 v = *(const float4*)&src[i];
    u16 h0 = bf16_rne(v.x), h1 = bf16_rne(v.y), h2 = bf16_rne(v.z), h3 = bf16_rne(v.w);
    float f0 = __uint_as_float((unsigned)h0 << 16);
    float f1 = __uint_as_float((unsigned)h1 << 16);
    float f2 = __uint_as_float((unsigned)h2 << 16);
    float f3 = __uint_as_float((unsigned)h3 << 16);
    ushort4 hh = make_ushort4(h0, h1, h2, h3);
    ushort4 ll = make_ushort4(bf16_rne(v.x - f0), bf16_rne(v.y - f1),
                              bf16_rne(v.z - f2), bf16_rne(v.w - f3));
    *(ushort4*)&hi[i] = hh;
    *(ushort4*)&lo[i] = ll;
}

// ---------------------------------------------------------------------------
// Split-bf16 MFMA GEMM: out[m,n] = sum_k A[m,k]*W[n,k] + bias[n]
// A,(M,K) and W,(N,K) given as bf16 hi/lo pairs. 128x128 tile, BK=32,
// 4 waves in 2x2 grid, each wave 64x64 = 4x4 frags of 16x16x32.
// LDS slot-swizzle: slot' = slot ^ ((row>>1)&3)  (conflict-free frag reads).
// MODE 0: scatter to q/k/v (B*H,N,DK).  MODE 1: plain (B*N,C).
// ---------------------------------------------------------------------------
template <int MODE>
__global__ __launch_bounds__(256) void gemm_mfma(
    const u16* __restrict__ Ahi, const u16* __restrict__ Alo,
    const u16* __restrict__ Bhi, const u16* __restrict__ Blo,
    const float* __restrict__ bias, float* __restrict__ out,
    float* __restrict__ qb, float* __restrict__ kb, float* __restrict__ vb,
    int K)
{
    __shared__ __align__(16) u16 Ah[128 * 32], Al[128 * 32];
    __shared__ __align__(16) u16 Bh[128 * 32], Bl[128 * 32];

    const int tid = threadIdx.x;
    const int m0 = blockIdx.y * 128;
    const int n0 = blockIdx.x * 128;
    const int lane = tid & 63;
    const int wave = tid >> 6;
    const int wr = wave >> 1, wc = wave & 1;
    const int fr = lane & 15, sl = lane >> 4;

    f32x4 acc[4][4] = {};

    for (int k0 = 0; k0 < K; k0 += 32) {
        __syncthreads();
        #pragma unroll
        for (int c = 0; c < 2; ++c) {
            int ch = tid + c * 256;          // 512 chunks of 16B per buffer
            int row = ch >> 2, slot = ch & 3;
            int ldo = row * 32 + ((slot ^ ((row >> 1) & 3)) * 8);
            size_t ga = (size_t)(m0 + row) * K + k0 + slot * 8;
            size_t gb = (size_t)(n0 + row) * K + k0 + slot * 8;
            *(uint4*)&Ah[ldo] = *(const uint4*)&Ahi[ga];
            *(uint4*)&Al[ldo] = *(const uint4*)&Alo[ga];
            *(uint4*)&Bh[ldo] = *(const uint4*)&Bhi[gb];
            *(uint4*)&Bl[ldo] = *(const uint4*)&Blo[gb];
        }
        __syncthreads();

        short8v afh[4], afl[4], bfh[4], bfl[4];
        #pragma unroll
        for (int m = 0; m < 4; ++m) {
            int row = wr * 64 + m * 16 + fr;
            int off = row * 32 + ((sl ^ ((row >> 1) & 3)) * 8);
            afh[m] = *(const short8v*)&Ah[off];
            afl[m] = *(const short8v*)&Al[off];
        }
        #pragma unroll
        for (int n = 0; n < 4; ++n) {
            int row = wc * 64 + n * 16 + fr;
            int off = row * 32 + ((sl ^ ((row >> 1) & 3)) * 8);
            bfh[n] = *(const short8v*)&Bh[off];
            bfl[n] = *(const short8v*)&Bl[off];
        }
        #pragma unroll
        for (int m = 0; m < 4; ++m)
            #pragma unroll
            for (int n = 0; n < 4; ++n) {
                acc[m][n] = __builtin_amdgcn_mfma_f32_16x16x32_bf16(afh[m], bfh[n], acc[m][n], 0, 0, 0);
                acc[m][n] = __builtin_amdgcn_mfma_f32_16x16x32_bf16(afh[m], bfl[n], acc[m][n], 0, 0, 0);
                acc[m][n] = __builtin_amdgcn_mfma_f32_16x16x32_bf16(afl[m], bfh[n], acc[m][n], 0, 0, 0);
            }
    }

    // epilogue: C/D map col=lane&15, row=(lane>>4)*4+reg  [m89-verified]
    #pragma unroll
    for (int m = 0; m < 4; ++m)
        #pragma unroll
        for (int n = 0; n < 4; ++n)
            #pragma unroll
            for (int r = 0; r < 4; ++r) {
                int grow = m0 + wr * 64 + m * 16 + sl * 4 + r;
                int gcol = n0 + wc * 64 + n * 16 + fr;
                float val = acc[m][n][r] + bias[gcol];
                if (MODE == 0) {
                    int t = gcol >> 10, h = (gcol >> 6) & 15, d = gcol & 63;
                    int bb = grow >> 11, nn = grow & (N - 1);
                    float* dst = (t == 0) ? qb : (t == 1) ? kb : vb;
                    dst[(((size_t)bb * H + h) * N + nn) * DK + d] = val;
                } else {
                    out[(size_t)grow * C + gcol] = val;
                }
            }
}

// ---------------------------------------------------------------------------
// Row stats: block = 64 q-rows, K swept in 64-key tiles. (unchanged fp32)
// ---------------------------------------------------------------------------
__global__ __launch_bounds__(256) void row_stats(
    const float* __restrict__ qg_, const float* __restrict__ kg_,
    float* __restrict__ Mout, float* __restrict__ rowmax)
{
    constexpr int QB = 64, KB = 64, LS = 68;
    __shared__ float Qs[QB * LS];
    __shared__ float Ks[KB * LS];
    __shared__ float Mx[16][QB];
    __shared__ float Sm[16][QB];

    const int tid = threadIdx.x;
    const int bh = blockIdx.y;
    const int q0 = blockIdx.x * QB;
    const int sq = tid & 15;
    const int sk = tid >> 4;

    const size_t qbase = ((size_t)bh * N + q0) * DK;
    #pragma unroll
    for (int w = 0; w < 4; ++w) {
        int idx = (tid + w * 256) * 4;
        int r = idx >> 6, d = idx & 63;
        *(float4*)&Qs[r * LS + d] = *(const float4*)&qg_[qbase + idx];
    }

    float mx[4] = {-1e30f, -1e30f, -1e30f, -1e30f};
    float sm[4] = {};

    for (int kt = 0; kt < N; kt += KB) {
        const size_t kbase = ((size_t)bh * N + kt) * DK;
        __syncthreads();
        #pragma unroll
        for (int w = 0; w < 4; ++w) {
            int idx = (tid + w * 256) * 4;
            int r = idx >> 6, d = idx & 63;
            *(float4*)&Ks[r * LS + d] = *(const float4*)&kg_[kbase + idx];
        }
        __syncthreads();
        float s[4][4] = {};
        #pragma unroll
        for (int d4 = 0; d4 < 16; ++d4) {
            float4 qv[4], kv[4];
            #pragma unroll
            for (int t = 0; t < 4; ++t) qv[t] = *(const float4*)&Qs[(sq + 16*t) * LS + d4*4];
            #pragma unroll
            for (int j = 0; j < 4; ++j) kv[j] = *(const float4*)&Ks[(4*sk + j) * LS + d4*4];
            #pragma unroll
            for (int t = 0; t < 4; ++t)
                #pragma unroll
                for (int j = 0; j < 4; ++j)
                    s[t][j] += qv[t].x*kv[j].x + qv[t].y*kv[j].y + qv[t].z*kv[j].z + qv[t].w*kv[j].w;
        }
        #pragma unroll
        for (int t = 0; t < 4; ++t) {
            mx[t] = fmaxf(mx[t], fmaxf(fmaxf(s[t][0], s[t][1]), fmaxf(s[t][2], s[t][3])));
            sm[t] += s[t][0] + s[t][1] + s[t][2] + s[t][3];
        }
    }

    #pragma unroll
    for (int t = 0; t < 4; ++t) { Mx[sk][sq + 16*t] = mx[t]; Sm[sk][sq + 16*t] = sm[t]; }
    __syncthreads();
    if (tid < QB) {
        float m = -1e30f, s = 0.f;
        #pragma unroll
        for (int g = 0; g < 16; ++g) { m = fmaxf(m, Mx[g][tid]); s += Sm[g][tid]; }
        const size_t idx = (size_t)bh * N + q0 + tid;
        Mout[idx]   = SCALE * m - (SCALE * s) / (float)N;
        rowmax[idx] = SCALE * m;
    }
}

// ---------------------------------------------------------------------------
// Top-k: keep flag + compacted index list (rank is unique per row).
// ---------------------------------------------------------------------------
__global__ __launch_bounds__(256) void topk_keep(
    const float* __restrict__ Mv, int* __restrict__ keep, int* __restrict__ kidx)
{
    const int bh = blockIdx.y;
    const int qi = blockIdx.x * 256 + threadIdx.x;
    __shared__ float Ms[N];
    for (int e = threadIdx.x; e < N; e += 256) Ms[e] = Mv[(size_t)bh * N + e];
    __syncthreads();
    const float mq = Ms[qi];
    int rank = 0;
    for (int j = 0; j < N; ++j) {
        float mj = Ms[j];
        rank += (mj > mq) || (mj == mq && j < qi);
    }
    keep[(size_t)bh * N + qi] = (rank < NTOP) ? 1 : 0;
    if (rank < NTOP) kidx[bh * NTOP + rank] = qi;
}

// ---------------------------------------------------------------------------
// vmean[bh,d] = mean_k v[bh,k,d].
// ---------------------------------------------------------------------------
__global__ __launch_bounds__(256) void vmean_kernel(
    const float* __restrict__ v, float* __restrict__ vmean)
{
    const int bh = blockIdx.x;
    const int d   = threadIdx.x & 63;
    const int seg = threadIdx.x >> 6;
    float s = 0.f;
    for (int kk = seg; kk < N; kk += 4) s += v[((size_t)bh * N + kk) * DK + d];
    __shared__ float part[4][64];
    part[seg][d] = s;
    __syncthreads();
    if (threadIdx.x < 64) {
        float t = part[0][d] + part[1][d] + part[2][d] + part[3][d];
        vmean[bh * DK + d] = t / (float)N;
    }
}

// ---------------------------------------------------------------------------
// Fill non-kept rows of attn_out with vmean. grid (N/64, B*H)
// ---------------------------------------------------------------------------
__global__ __launch_bounds__(256) void fill_nonkept(
    const int* __restrict__ keep, const float* __restrict__ vmean,
    float* __restrict__ attn_out)
{
    const int bh = blockIdx.y;
    const int b = bh >> 4, h = bh & 15;
    const int d = threadIdx.x & 63;
    const int rr = threadIdx.x >> 6;
    const float vm = vmean[bh * DK + d];
    #pragma unroll
    for (int i = 0; i < 16; ++i) {
        int row = blockIdx.x * 64 + i * 4 + rr;
        if (!keep[(size_t)bh * N + row])
            attn_out[((size_t)b * N + row) * C + h * DK + d] = vm;
    }
}

// ---------------------------------------------------------------------------
// Attention on the 512 kept rows only (gathered via kidx). grid (NTOP/64, B*H)
// ---------------------------------------------------------------------------
__global__ __launch_bounds__(256) void attn_kernel(
    const float* __restrict__ qg_, const float* __restrict__ kg_,
    const float* __restrict__ vg_, const float* __restrict__ rowmax,
    const int* __restrict__ kidx, float* __restrict__ attn_out)
{
    constexpr int QB = 64, KB = 64, LS = 68;
    __shared__ float Qs[QB * LS];
    __shared__ float KVs[KB * LS];
    __shared__ float Ps[QB * LS];
    __shared__ float Lp[16][QB];
    __shared__ float Linv[QB];

    const int tid = threadIdx.x;
    const int bh = blockIdx.y;
    const int q0 = blockIdx.x * QB;
    const int b = bh >> 4, h = bh & 15;
    const int sq = tid & 15, sk = tid >> 4;   // score mapping
    const int dg = tid & 15, qh = tid >> 4;   // PV mapping

    const int* kix = kidx + bh * NTOP + q0;

    #pragma unroll
    for (int w = 0; w < 4; ++w) {
        int idx = (tid + w * 256) * 4;
        int r = idx >> 6, d = idx & 63;
        int row = kix[r];
        *(float4*)&Qs[r * LS + d] = *(const float4*)&qg_[((size_t)bh * N + row) * DK + d];
    }
    float rmax[4], lp[4] = {};
    #pragma unroll
    for (int t = 0; t < 4; ++t)
        rmax[t] = rowmax[(size_t)bh * N + kix[sq + 16*t]];

    float oacc[4][4] = {};

    for (int kt = 0; kt < N; kt += KB) {
        const size_t kbase = ((size_t)bh * N + kt) * DK;
        __syncthreads();
        #pragma unroll
        for (int w = 0; w < 4; ++w) {
            int idx = (tid + w * 256) * 4;
            int r = idx >> 6, d = idx & 63;
            *(float4*)&KVs[r * LS + d] = *(const float4*)&kg_[kbase + idx];
        }
        __syncthreads();
        float s[4][4] = {};
        #pragma unroll
        for (int d4 = 0; d4 < 16; ++d4) {
            float4 qv[4], kv[4];
            #pragma unroll
            for (int t = 0; t < 4; ++t) qv[t] = *(const float4*)&Qs[(sq + 16*t) * LS + d4*4];
            #pragma unroll
            for (int j = 0; j < 4; ++j) kv[j] = *(const float4*)&KVs[(4*sk + j) * LS + d4*4];
            #pragma unroll
            for (int t = 0; t < 4; ++t)
                #pragma unroll
                for (int j = 0; j < 4; ++j)
                    s[t][j] += qv[t].x*kv[j].x + qv[t].y*kv[j].y + qv[t].z*kv[j].z + qv[t].w*kv[j].w;
        }
        #pragma unroll
        for (int t = 0; t < 4; ++t) {
            float4 p4;
            p4.x = __expf(s[t][0] * SCALE - rmax[t]);
            p4.y = __expf(s[t][1] * SCALE - rmax[t]);
            p4.z = __expf(s[t][2] * SCALE - rmax[t]);
            p4.w = __expf(s[t][3] * SCALE - rmax[t]);
            lp[t] += p4.x + p4.y + p4.z + p4.w;
            *(float4*)&Ps[(sq + 16*t) * LS + 4*sk] = p4;
        }
        __syncthreads();
        #pragma unroll
        for (int w = 0; w < 4; ++w) {
            int idx = (tid + w * 256) * 4;
            int r = idx >> 6, d = idx & 63;
            *(float4*)&KVs[r * LS + d] = *(const float4*)&vg_[kbase + idx];
        }
        __syncthreads();
        #pragma unroll
        for (int j4 = 0; j4 < 16; ++j4) {
            float4 vv[4];
            #pragma unroll
            for (int j = 0; j < 4; ++j) vv[j] = *(const float4*)&KVs[(4*j4 + j) * LS + 4*dg];
            #pragma unroll
            for (int t = 0; t < 4; ++t) {
                const float4 pv = *(const float4*)&Ps[(qh + 16*t) * LS + 4*j4];
                oacc[t][0] += pv.x*vv[0].x + pv.y*vv[1].x + pv.z*vv[2].x + pv.w*vv[3].x;
                oacc[t][1] += pv.x*vv[0].y + pv.y*vv[1].y + pv.z*vv[2].y + pv.w*vv[3].y;
                oacc[t][2] += pv.x*vv[0].z + pv.y*vv[1].z + pv.z*vv[2].z + pv.w*vv[3].z;
                oacc[t][3] += pv.x*vv[0].w + pv.y*vv[1].w + pv.z*vv[2].w + pv.w*vv[3].w;
            }
        }
    }

    #pragma unroll
    for (int t = 0; t < 4; ++t) Lp[sk][sq + 16*t] = lp[t];
    __syncthreads();
    if (tid < QB) {
        float l = 0.f;
        #pragma unroll
        for (int g = 0; g < 16; ++g) l += Lp[g][tid];
        Linv[tid] = 1.0f / l;
    }
    __syncthreads();

    #pragma unroll
    for (int t = 0; t < 4; ++t) {
        const int qi = kix[qh + 16*t];
        const float inv = Linv[qh + 16*t];
        float4 r;
        r.x = oacc[t][0] * inv; r.y = oacc[t][1] * inv;
        r.z = oacc[t][2] * inv; r.w = oacc[t][3] * inv;
        *(float4*)&attn_out[((size_t)b * N + qi) * C + h * DK + 4*dg] = r;
    }
}

// ---------------------------------------------------------------------------
extern "C" void kernel_launch(void* const* d_in, const int* in_sizes, int n_in,
                              void* d_out, int out_size, void* d_ws, size_t ws_size,
                              hipStream_t stream)
{
    const float* x    = (const float*)d_in[0];
    const float* Wqkv = (const float*)d_in[1];
    const float* bqkv = (const float*)d_in[2];
    const float* Wout = (const float*)d_in[3];
    const float* bout = (const float*)d_in[4];
    float* out = (float*)d_out;

    char* ws = (char*)d_ws;
    size_t off = 0;
    auto alloc = [&](size_t bytes) -> void* {
        void* p = ws + off;
        off += (bytes + 255) & ~(size_t)255;
        return p;
    };

    const size_t BHND = (size_t)B * H * N * DK;       // 4 Mi elems
    float* q        = (float*)alloc(BHND * 4);
    float* kbuf     = (float*)alloc(BHND * 4);
    float* vbuf     = (float*)alloc(BHND * 4);
    float* attn_out = (float*)alloc((size_t)B * N * C * 4);
    u16* cvAhi = (u16*)alloc((size_t)B * N * C * 2);  // x / attn_out hi
    u16* cvAlo = (u16*)alloc((size_t)B * N * C * 2);
    u16* cvBhi = (u16*)alloc((size_t)3 * C * C * 2);  // Wqkv / Wout hi
    u16* cvBlo = (u16*)alloc((size_t)3 * C * C * 2);
    float* Mbuf     = (float*)alloc((size_t)B * H * N * 4);
    float* rmaxbuf  = (float*)alloc((size_t)B * H * N * 4);
    int*   keep     = (int*)  alloc((size_t)B * H * N * 4);
    int*   kidx     = (int*)  alloc((size_t)B * H * NTOP * 4);
    float* vmeanbuf = (float*)alloc((size_t)B * H * DK * 4);

    const int nX = B * N * C;        // 4M
    const int nW = 3 * C * C;        // 3M
    const int nWo = C * C;           // 1M

    // 1. convert x, Wqkv to bf16 hi/lo
    convert_hilo<<<nX / 1024, 256, 0, stream>>>(x, cvAhi, cvAlo, nX);
    convert_hilo<<<nW / 1024, 256, 0, stream>>>(Wqkv, cvBhi, cvBlo, nW);

    // 2. QKV projection (split-bf16 MFMA), scatter to q/k/v
    gemm_mfma<0><<<dim3(3 * C / 128, (B * N) / 128), 256, 0, stream>>>(
        cvAhi, cvAlo, cvBhi, cvBlo, bqkv, nullptr, q, kbuf, vbuf, C);

    // 3. Row stats
    row_stats<<<dim3(N / 64, B * H), 256, 0, stream>>>(q, kbuf, Mbuf, rmaxbuf);

    // 4. Top-512 keep flags + compacted indices
    topk_keep<<<dim3(N / 256, B * H), 256, 0, stream>>>(Mbuf, keep, kidx);

    // 5. V column means, fill non-kept rows
    vmean_kernel<<<B * H, 256, 0, stream>>>(vbuf, vmeanbuf);
    fill_nonkept<<<dim3(N / 64, B * H), 256, 0, stream>>>(keep, vmeanbuf, attn_out);

    // 6. Attention on kept rows only
    attn_kernel<<<dim3(NTOP / 64, B * H), 256, 0, stream>>>(
        q, kbuf, vbuf, rmaxbuf, kidx, attn_out);

    // 7. Output projection (split-bf16 MFMA)
    convert_hilo<<<nX / 1024, 256, 0, stream>>>(attn_out, cvAhi, cvAlo, nX);
    convert_hilo<<<nWo / 1024, 256, 0, stream>>>(Wout, cvBhi, cvBlo, nWo);
    gemm_mfma<1><<<dim3(C / 128, (B * N) / 128), 256, 0, stream>>>(
        cvAhi, cvAlo, cvBhi, cvBlo, bout, out, nullptr, nullptr, nullptr, C);
}

// Round 5
// 1142.087 us; speedup vs baseline: 2.4095x; 1.0299x over previous
//
#include <hip/hip_runtime.h>
#include <math.h>

typedef unsigned short u16;
typedef __attribute__((ext_vector_type(8))) short short8v;  // 8 bf16 operand frag
typedef __attribute__((ext_vector_type(4))) float f32x4;    // MFMA accumulator

constexpr int B  = 2;
constexpr int N  = 2048;
constexpr int C  = 1024;
constexpr int H  = 16;
constexpr int DK = 64;
constexpr int NTOP = 512;
constexpr float SCALE = 0.125f;  // 1/sqrt(64)
constexpr int   BAND_CAP = 1024;
constexpr float BAND_EPS = 2e-3f;   // >> 4-term split-bf16 M error bound (~3e-4)

// ---------------------------------------------------------------------------
// fp32 -> bf16 hi/lo split (RNE): hi = bf16(x), lo = bf16(x - hi)
// ---------------------------------------------------------------------------
__device__ __forceinline__ u16 bf16_rne(float x) {
    unsigned u = __float_as_uint(x);
    unsigned r = u + 0x7fffu + ((u >> 16) & 1u);
    return (u16)(r >> 16);
}

__global__ __launch_bounds__(256) void convert_hilo(
    const float* __restrict__ src, u16* __restrict__ hi, u16* __restrict__ lo, int n)
{
    int i = (blockIdx.x * 256 + threadIdx.x) * 4;
    if (i >= n) return;
    float4 v = *(const float4*)&src[i];
    u16 h0 = bf16_rne(v.x), h1 = bf16_rne(v.y), h2 = bf16_rne(v.z), h3 = bf16_rne(v.w);
    float f0 = __uint_as_float((unsigned)h0 << 16);
    float f1 = __uint_as_float((unsigned)h1 << 16);
    float f2 = __uint_as_float((unsigned)h2 << 16);
    float f3 = __uint_as_float((unsigned)h3 << 16);
    ushort4 hh = make_ushort4(h0, h1, h2, h3);
    ushort4 ll = make_ushort4(bf16_rne(v.x - f0), bf16_rne(v.y - f1),
                              bf16_rne(v.z - f2), bf16_rne(v.w - f3));
    *(ushort4*)&hi[i] = hh;
    *(ushort4*)&lo[i] = ll;
}

// ---------------------------------------------------------------------------
// Split-bf16 MFMA GEMM: 128x128 tile, BK=32, 4 waves. (verified r3)
// ---------------------------------------------------------------------------
template <int MODE>
__global__ __launch_bounds__(256) void gemm_mfma(
    const u16* __restrict__ Ahi, const u16* __restrict__ Alo,
    const u16* __restrict__ Bhi, const u16* __restrict__ Blo,
    const float* __restrict__ bias, float* __restrict__ out,
    float* __restrict__ qb, float* __restrict__ kb, float* __restrict__ vb,
    int K)
{
    __shared__ __align__(16) u16 Ah[128 * 32], Al[128 * 32];
    __shared__ __align__(16) u16 Bh[128 * 32], Bl[128 * 32];

    const int tid = threadIdx.x;
    const int m0 = blockIdx.y * 128;
    const int n0 = blockIdx.x * 128;
    const int lane = tid & 63;
    const int wave = tid >> 6;
    const int wr = wave >> 1, wc = wave & 1;
    const int fr = lane & 15, sl = lane >> 4;

    f32x4 acc[4][4] = {};

    for (int k0 = 0; k0 < K; k0 += 32) {
        __syncthreads();
        #pragma unroll
        for (int c = 0; c < 2; ++c) {
            int ch = tid + c * 256;
            int row = ch >> 2, slot = ch & 3;
            int ldo = row * 32 + ((slot ^ ((row >> 1) & 3)) * 8);
            size_t ga = (size_t)(m0 + row) * K + k0 + slot * 8;
            size_t gb = (size_t)(n0 + row) * K + k0 + slot * 8;
            *(uint4*)&Ah[ldo] = *(const uint4*)&Ahi[ga];
            *(uint4*)&Al[ldo] = *(const uint4*)&Alo[ga];
            *(uint4*)&Bh[ldo] = *(const uint4*)&Bhi[gb];
            *(uint4*)&Bl[ldo] = *(const uint4*)&Blo[gb];
        }
        __syncthreads();

        short8v afh[4], afl[4], bfh[4], bfl[4];
        #pragma unroll
        for (int m = 0; m < 4; ++m) {
            int row = wr * 64 + m * 16 + fr;
            int off = row * 32 + ((sl ^ ((row >> 1) & 3)) * 8);
            afh[m] = *(const short8v*)&Ah[off];
            afl[m] = *(const short8v*)&Al[off];
        }
        #pragma unroll
        for (int n = 0; n < 4; ++n) {
            int row = wc * 64 + n * 16 + fr;
            int off = row * 32 + ((sl ^ ((row >> 1) & 3)) * 8);
            bfh[n] = *(const short8v*)&Bh[off];
            bfl[n] = *(const short8v*)&Bl[off];
        }
        #pragma unroll
        for (int m = 0; m < 4; ++m)
            #pragma unroll
            for (int n = 0; n < 4; ++n) {
                acc[m][n] = __builtin_amdgcn_mfma_f32_16x16x32_bf16(afh[m], bfh[n], acc[m][n], 0, 0, 0);
                acc[m][n] = __builtin_amdgcn_mfma_f32_16x16x32_bf16(afh[m], bfl[n], acc[m][n], 0, 0, 0);
                acc[m][n] = __builtin_amdgcn_mfma_f32_16x16x32_bf16(afl[m], bfh[n], acc[m][n], 0, 0, 0);
            }
    }

    #pragma unroll
    for (int m = 0; m < 4; ++m)
        #pragma unroll
        for (int n = 0; n < 4; ++n)
            #pragma unroll
            for (int r = 0; r < 4; ++r) {
                int grow = m0 + wr * 64 + m * 16 + sl * 4 + r;
                int gcol = n0 + wc * 64 + n * 16 + fr;
                float val = acc[m][n][r] + bias[gcol];
                if (MODE == 0) {
                    int t = gcol >> 10, h = (gcol >> 6) & 15, d = gcol & 63;
                    int bb = grow >> 11, nn = grow & (N - 1);
                    float* dst = (t == 0) ? qb : (t == 1) ? kb : vb;
                    dst[(((size_t)bb * H + h) * N + nn) * DK + d] = val;
                } else {
                    out[(size_t)grow * C + gcol] = val;
                }
            }
}

// ---------------------------------------------------------------------------
// mean[bh,d] = mean_k src[bh,k,d].  grid B*H, 256 threads.  (used for v and k)
// ---------------------------------------------------------------------------
__global__ __launch_bounds__(256) void vmean_kernel(
    const float* __restrict__ v, float* __restrict__ vmean)
{
    const int bh = blockIdx.x;
    const int d   = threadIdx.x & 63;
    const int seg = threadIdx.x >> 6;
    float s = 0.f;
    for (int kk = seg; kk < N; kk += 4) s += v[((size_t)bh * N + kk) * DK + d];
    __shared__ float part[4][64];
    part[seg][d] = s;
    __syncthreads();
    if (threadIdx.x < 64) {
        float t = part[0][d] + part[1][d] + part[2][d] + part[3][d];
        vmean[bh * DK + d] = t / (float)N;
    }
}

// ---------------------------------------------------------------------------
// Mdot[bh,row] = dot(q_row, kmean_bh)  (== mean over keys of q.k, exactly)
// ---------------------------------------------------------------------------
__global__ __launch_bounds__(256) void qdot_kernel(
    const float* __restrict__ q, const float* __restrict__ kmean,
    float* __restrict__ Mdot)
{
    const int bh = blockIdx.y;
    const int row = blockIdx.x * 256 + threadIdx.x;
    __shared__ float km[DK];
    if (threadIdx.x < DK) km[threadIdx.x] = kmean[bh * DK + threadIdx.x];
    __syncthreads();
    const float* qr = &q[((size_t)bh * N + row) * DK];
    float s = 0.f;
    #pragma unroll
    for (int d4 = 0; d4 < DK; d4 += 4) {
        float4 v = *(const float4*)&qr[d4];
        s += v.x * km[d4] + v.y * km[d4 + 1] + v.z * km[d4 + 2] + v.w * km[d4 + 3];
    }
    Mdot[(size_t)bh * N + row] = s;
}

// ---------------------------------------------------------------------------
// MFMA row-max (4-term split-bf16). Approximate M; boundary refined later.
// ---------------------------------------------------------------------------
__global__ __launch_bounds__(256) void row_stats_mfma(
    const u16* __restrict__ qh_, const u16* __restrict__ ql_,
    const u16* __restrict__ kh_, const u16* __restrict__ kl_,
    const float* __restrict__ Mdot, float* __restrict__ Mout,
    float* __restrict__ rowmax)
{
    __shared__ __align__(16) u16 Kh[64 * 64];
    __shared__ __align__(16) u16 Kl[64 * 64];
    const int tid = threadIdx.x, lane = tid & 63, wave = tid >> 6;
    const int bh = blockIdx.y;
    const int q0 = blockIdx.x * 128 + wave * 32;
    const int fr = lane & 15, g = lane >> 4;

    short8v qfh[2][2], qfl[2][2];
    #pragma unroll
    for (int m = 0; m < 2; ++m)
        #pragma unroll
        for (int kk = 0; kk < 2; ++kk) {
            size_t qa = ((size_t)bh * N + q0 + m * 16 + fr) * DK + kk * 32 + g * 8;
            qfh[m][kk] = *(const short8v*)&qh_[qa];
            qfl[m][kk] = *(const short8v*)&ql_[qa];
        }

    f32x4 mx[2];
    mx[0] = (f32x4){-1e30f, -1e30f, -1e30f, -1e30f};
    mx[1] = mx[0];

    for (int kt = 0; kt < N; kt += 64) {
        __syncthreads();
        for (int c = tid; c < 512; c += 256) {
            int row = c >> 3, slot = c & 7;
            int off = row * 64 + ((slot ^ (row & 7)) * 8);
            size_t ga = ((size_t)bh * N + kt + row) * DK + slot * 8;
            *(uint4*)&Kh[off] = *(const uint4*)&kh_[ga];
            *(uint4*)&Kl[off] = *(const uint4*)&kl_[ga];
        }
        __syncthreads();
        short8v bfh[4][2], bfl[4][2];
        #pragma unroll
        for (int n = 0; n < 4; ++n)
            #pragma unroll
            for (int kk = 0; kk < 2; ++kk) {
                int key = n * 16 + fr;
                int off = key * 64 + (((g + kk * 4) ^ (key & 7)) * 8);
                bfh[n][kk] = *(const short8v*)&Kh[off];
                bfl[n][kk] = *(const short8v*)&Kl[off];
            }
        #pragma unroll
        for (int m = 0; m < 2; ++m)
            #pragma unroll
            for (int n = 0; n < 4; ++n) {
                f32x4 a = {};
                #pragma unroll
                for (int kk = 0; kk < 2; ++kk) {
                    a = __builtin_amdgcn_mfma_f32_16x16x32_bf16(qfl[m][kk], bfl[n][kk], a, 0, 0, 0);
                    a = __builtin_amdgcn_mfma_f32_16x16x32_bf16(qfl[m][kk], bfh[n][kk], a, 0, 0, 0);
                    a = __builtin_amdgcn_mfma_f32_16x16x32_bf16(qfh[m][kk], bfl[n][kk], a, 0, 0, 0);
                    a = __builtin_amdgcn_mfma_f32_16x16x32_bf16(qfh[m][kk], bfh[n][kk], a, 0, 0, 0);
                }
                #pragma unroll
                for (int r = 0; r < 4; ++r) mx[m][r] = fmaxf(mx[m][r], a[r]);
            }
    }

    #pragma unroll
    for (int w = 1; w < 16; w <<= 1)
        #pragma unroll
        for (int m = 0; m < 2; ++m)
            #pragma unroll
            for (int r = 0; r < 4; ++r)
                mx[m][r] = fmaxf(mx[m][r], __shfl_xor(mx[m][r], w, 64));

    if (fr == 0) {
        #pragma unroll
        for (int m = 0; m < 2; ++m)
            #pragma unroll
            for (int r = 0; r < 4; ++r) {
                int row = q0 + m * 16 + g * 4 + r;
                size_t idx = (size_t)bh * N + row;
                float v = mx[m][r];
                rowmax[idx] = SCALE * v;
                Mout[idx]   = SCALE * (v - Mdot[idx]);
            }
    }
}

// ---------------------------------------------------------------------------
// Boundary refinement: threshold -> band -> fp64 exact M for band rows.
// ---------------------------------------------------------------------------
__global__ void zero_cnt(int* cnt) { if (threadIdx.x < B * H) cnt[threadIdx.x] = 0; }

__global__ __launch_bounds__(256) void topk_thr(
    const float* __restrict__ Mv, float* __restrict__ thr)
{
    const int bh = blockIdx.y;
    const int qi = blockIdx.x * 256 + threadIdx.x;
    __shared__ float Ms[N];
    for (int e = threadIdx.x; e < N; e += 256) Ms[e] = Mv[(size_t)bh * N + e];
    __syncthreads();
    const float mq = Ms[qi];
    int rank = 0;
    for (int j = 0; j < N; ++j) {
        float mj = Ms[j];
        rank += (mj > mq) || (mj == mq && j < qi);
    }
    if (rank == NTOP - 1) thr[bh] = mq;   // smallest kept (approx boundary)
}

__global__ __launch_bounds__(256) void band_collect(
    const float* __restrict__ Mv, const float* __restrict__ thr,
    int* __restrict__ cnt, int* __restrict__ band)
{
    const int bh = blockIdx.y;
    const int row = blockIdx.x * 256 + threadIdx.x;
    const float m = Mv[(size_t)bh * N + row];
    if (fabsf(m - thr[bh]) <= BAND_EPS) {
        int pos = atomicAdd(&cnt[bh], 1);
        if (pos < BAND_CAP) band[bh * BAND_CAP + pos] = row;
    }
}

// one wave per band row: exact M via fp64 accumulation (order-deterministic)
__global__ __launch_bounds__(256) void refine_kernel(
    const float* __restrict__ q, const float* __restrict__ k,
    const int* __restrict__ cnt, const int* __restrict__ band,
    float* __restrict__ Mv)
{
    const int bh = blockIdx.y;
    const int wave = threadIdx.x >> 6, lane = threadIdx.x & 63;
    const int ci = blockIdx.x * 4 + wave;
    const int n = min(cnt[bh], BAND_CAP);
    if (ci >= n) return;
    const int row = band[bh * BAND_CAP + ci];
    const float* qr = &q[((size_t)bh * N + row) * DK];
    float qf[DK];
    #pragma unroll
    for (int d = 0; d < DK; ++d) qf[d] = qr[d];
    double mx = -1e30, sm = 0.0;
    for (int kk = lane; kk < N; kk += 64) {
        const float* kr = &k[((size_t)bh * N + kk) * DK];
        double s = 0.0;
        #pragma unroll
        for (int d = 0; d < DK; ++d) s += (double)qf[d] * (double)kr[d];
        mx = fmax(mx, s);
        sm += s;
    }
    #pragma unroll
    for (int w = 1; w < 64; w <<= 1) {
        mx = fmax(mx, __shfl_xor(mx, w, 64));
        sm += __shfl_xor(sm, w, 64);
    }
    if (lane == 0)
        Mv[(size_t)bh * N + row] = (float)((double)SCALE * (mx - sm / (double)N));
}

// ---------------------------------------------------------------------------
// Final top-k on refined M: keep flag + compacted index list.
// ---------------------------------------------------------------------------
__global__ __launch_bounds__(256) void topk_keep(
    const float* __restrict__ Mv, int* __restrict__ keep, int* __restrict__ kidx)
{
    const int bh = blockIdx.y;
    const int qi = blockIdx.x * 256 + threadIdx.x;
    __shared__ float Ms[N];
    for (int e = threadIdx.x; e < N; e += 256) Ms[e] = Mv[(size_t)bh * N + e];
    __syncthreads();
    const float mq = Ms[qi];
    int rank = 0;
    for (int j = 0; j < N; ++j) {
        float mj = Ms[j];
        rank += (mj > mq) || (mj == mq && j < qi);
    }
    keep[(size_t)bh * N + qi] = (rank < NTOP) ? 1 : 0;
    if (rank < NTOP) kidx[bh * NTOP + rank] = qi;
}

// ---------------------------------------------------------------------------
// Fill non-kept rows of attn_out with vmean. grid (N/64, B*H)
// ---------------------------------------------------------------------------
__global__ __launch_bounds__(256) void fill_nonkept(
    const int* __restrict__ keep, const float* __restrict__ vmean,
    float* __restrict__ attn_out)
{
    const int bh = blockIdx.y;
    const int b = bh >> 4, h = bh & 15;
    const int d = threadIdx.x & 63;
    const int rr = threadIdx.x >> 6;
    const float vm = vmean[bh * DK + d];
    #pragma unroll
    for (int i = 0; i < 16; ++i) {
        int row = blockIdx.x * 64 + i * 4 + rr;
        if (!keep[(size_t)bh * N + row])
            attn_out[((size_t)b * N + row) * C + h * DK + d] = vm;
    }
}

// ---------------------------------------------------------------------------
// Attention on the 512 kept rows only. grid (NTOP/64, B*H)
// ---------------------------------------------------------------------------
__global__ __launch_bounds__(256) void attn_kernel(
    const float* __restrict__ qg_, const float* __restrict__ kg_,
    const float* __restrict__ vg_, const float* __restrict__ rowmax,
    const int* __restrict__ kidx, float* __restrict__ attn_out)
{
    constexpr int QB = 64, KB = 64, LS = 68;
    __shared__ float Qs[QB * LS];
    __shared__ float KVs[KB * LS];
    __shared__ float Ps[QB * LS];
    __shared__ float Lp[16][QB];
    __shared__ float Linv[QB];

    const int tid = threadIdx.x;
    const int bh = blockIdx.y;
    const int q0 = blockIdx.x * QB;
    const int b = bh >> 4, h = bh & 15;
    const int sq = tid & 15, sk = tid >> 4;
    const int dg = tid & 15, qh = tid >> 4;

    const int* kix = kidx + bh * NTOP + q0;

    #pragma unroll
    for (int w = 0; w < 4; ++w) {
        int idx = (tid + w * 256) * 4;
        int r = idx >> 6, d = idx & 63;
        int row = kix[r];
        *(float4*)&Qs[r * LS + d] = *(const float4*)&qg_[((size_t)bh * N + row) * DK + d];
    }
    float rmax[4], lp[4] = {};
    #pragma unroll
    for (int t = 0; t < 4; ++t)
        rmax[t] = rowmax[(size_t)bh * N + kix[sq + 16*t]];

    float oacc[4][4] = {};

    for (int kt = 0; kt < N; kt += KB) {
        const size_t kbase = ((size_t)bh * N + kt) * DK;
        __syncthreads();
        #pragma unroll
        for (int w = 0; w < 4; ++w) {
            int idx = (tid + w * 256) * 4;
            int r = idx >> 6, d = idx & 63;
            *(float4*)&KVs[r * LS + d] = *(const float4*)&kg_[kbase + idx];
        }
        __syncthreads();
        float s[4][4] = {};
        #pragma unroll
        for (int d4 = 0; d4 < 16; ++d4) {
            float4 qv[4], kv[4];
            #pragma unroll
            for (int t = 0; t < 4; ++t) qv[t] = *(const float4*)&Qs[(sq + 16*t) * LS + d4*4];
            #pragma unroll
            for (int j = 0; j < 4; ++j) kv[j] = *(const float4*)&KVs[(4*sk + j) * LS + d4*4];
            #pragma unroll
            for (int t = 0; t < 4; ++t)
                #pragma unroll
                for (int j = 0; j < 4; ++j)
                    s[t][j] += qv[t].x*kv[j].x + qv[t].y*kv[j].y + qv[t].z*kv[j].z + qv[t].w*kv[j].w;
        }
        #pragma unroll
        for (int t = 0; t < 4; ++t) {
            float4 p4;
            p4.x = __expf(s[t][0] * SCALE - rmax[t]);
            p4.y = __expf(s[t][1] * SCALE - rmax[t]);
            p4.z = __expf(s[t][2] * SCALE - rmax[t]);
            p4.w = __expf(s[t][3] * SCALE - rmax[t]);
            lp[t] += p4.x + p4.y + p4.z + p4.w;
            *(float4*)&Ps[(sq + 16*t) * LS + 4*sk] = p4;
        }
        __syncthreads();
        #pragma unroll
        for (int w = 0; w < 4; ++w) {
            int idx = (tid + w * 256) * 4;
            int r = idx >> 6, d = idx & 63;
            *(float4*)&KVs[r * LS + d] = *(const float4*)&vg_[kbase + idx];
        }
        __syncthreads();
        #pragma unroll
        for (int j4 = 0; j4 < 16; ++j4) {
            float4 vv[4];
            #pragma unroll
            for (int j = 0; j < 4; ++j) vv[j] = *(const float4*)&KVs[(4*j4 + j) * LS + 4*dg];
            #pragma unroll
            for (int t = 0; t < 4; ++t) {
                const float4 pv = *(const float4*)&Ps[(qh + 16*t) * LS + 4*j4];
                oacc[t][0] += pv.x*vv[0].x + pv.y*vv[1].x + pv.z*vv[2].x + pv.w*vv[3].x;
                oacc[t][1] += pv.x*vv[0].y + pv.y*vv[1].y + pv.z*vv[2].y + pv.w*vv[3].y;
                oacc[t][2] += pv.x*vv[0].z + pv.y*vv[1].z + pv.z*vv[2].z + pv.w*vv[3].z;
                oacc[t][3] += pv.x*vv[0].w + pv.y*vv[1].w + pv.z*vv[2].w + pv.w*vv[3].w;
            }
        }
    }

    #pragma unroll
    for (int t = 0; t < 4; ++t) Lp[sk][sq + 16*t] = lp[t];
    __syncthreads();
    if (tid < QB) {
        float l = 0.f;
        #pragma unroll
        for (int g = 0; g < 16; ++g) l += Lp[g][tid];
        Linv[tid] = 1.0f / l;
    }
    __syncthreads();

    #pragma unroll
    for (int t = 0; t < 4; ++t) {
        const int qi = kix[qh + 16*t];
        const float inv = Linv[qh + 16*t];
        float4 r;
        r.x = oacc[t][0] * inv; r.y = oacc[t][1] * inv;
        r.z = oacc[t][2] * inv; r.w = oacc[t][3] * inv;
        *(float4*)&attn_out[((size_t)b * N + qi) * C + h * DK + 4*dg] = r;
    }
}

// ---------------------------------------------------------------------------
extern "C" void kernel_launch(void* const* d_in, const int* in_sizes, int n_in,
                              void* d_out, int out_size, void* d_ws, size_t ws_size,
                              hipStream_t stream)
{
    const float* x    = (const float*)d_in[0];
    const float* Wqkv = (const float*)d_in[1];
    const float* bqkv = (const float*)d_in[2];
    const float* Wout = (const float*)d_in[3];
    const float* bout = (const float*)d_in[4];
    float* out = (float*)d_out;

    char* ws = (char*)d_ws;
    size_t off = 0;
    auto alloc = [&](size_t bytes) -> void* {
        void* p = ws + off;
        off += (bytes + 255) & ~(size_t)255;
        return p;
    };

    const size_t BHND = (size_t)B * H * N * DK;       // 4 Mi elems
    float* q        = (float*)alloc(BHND * 4);
    float* kbuf     = (float*)alloc(BHND * 4);
    float* vbuf     = (float*)alloc(BHND * 4);
    float* attn_out = (float*)alloc((size_t)B * N * C * 4);
    u16* cvAhi = (u16*)alloc((size_t)B * N * C * 2);  // x / q_hi / attn_out hi
    u16* cvAlo = (u16*)alloc((size_t)B * N * C * 2);
    u16* cvBhi = (u16*)alloc((size_t)3 * C * C * 2);
    u16* cvBlo = (u16*)alloc((size_t)3 * C * C * 2);
    u16* khi   = (u16*)alloc(BHND * 2);
    u16* klo   = (u16*)alloc(BHND * 2);
    float* Mbuf     = (float*)alloc((size_t)B * H * N * 4);
    float* rmaxbuf  = (float*)alloc((size_t)B * H * N * 4);
    float* Mdot     = (float*)alloc((size_t)B * H * N * 4);
    int*   keep     = (int*)  alloc((size_t)B * H * N * 4);
    int*   kidx     = (int*)  alloc((size_t)B * H * NTOP * 4);
    float* vmeanbuf = (float*)alloc((size_t)B * H * DK * 4);
    float* kmeanbuf = (float*)alloc((size_t)B * H * DK * 4);
    float* thrbuf   = (float*)alloc((size_t)B * H * 4);
    int*   cntbuf   = (int*)  alloc((size_t)B * H * 4);
    int*   bandbuf  = (int*)  alloc((size_t)B * H * BAND_CAP * 4);

    const int nX = B * N * C;        // 4M
    const int nW = 3 * C * C;        // 3M
    const int nWo = C * C;           // 1M

    // 1. convert x, Wqkv to bf16 hi/lo
    convert_hilo<<<nX / 1024, 256, 0, stream>>>(x, cvAhi, cvAlo, nX);
    convert_hilo<<<nW / 1024, 256, 0, stream>>>(Wqkv, cvBhi, cvBlo, nW);

    // 2. QKV projection (split-bf16 MFMA), scatter to q/k/v
    gemm_mfma<0><<<dim3(3 * C / 128, (B * N) / 128), 256, 0, stream>>>(
        cvAhi, cvAlo, cvBhi, cvBlo, bqkv, nullptr, q, kbuf, vbuf, C);

    // 3. convert q,k to hi/lo (q reuses cvA buffers)
    u16* qhi = cvAhi; u16* qlo = cvAlo;
    convert_hilo<<<nX / 1024, 256, 0, stream>>>(q, qhi, qlo, nX);
    convert_hilo<<<nX / 1024, 256, 0, stream>>>(kbuf, khi, klo, nX);

    // 4. column means of v (output fill) and k (exact mean-score term)
    vmean_kernel<<<B * H, 256, 0, stream>>>(vbuf, vmeanbuf);
    vmean_kernel<<<B * H, 256, 0, stream>>>(kbuf, kmeanbuf);

    // 5. mean term per row: Mdot = q . kmean
    qdot_kernel<<<dim3(N / 256, B * H), 256, 0, stream>>>(q, kmeanbuf, Mdot);

    // 6. MFMA approximate row max -> M, rowmax
    row_stats_mfma<<<dim3(N / 128, B * H), 256, 0, stream>>>(
        qhi, qlo, khi, klo, Mdot, Mbuf, rmaxbuf);

    // 7. boundary refinement: threshold -> band -> fp64 exact M
    zero_cnt<<<1, 64, 0, stream>>>(cntbuf);
    topk_thr<<<dim3(N / 256, B * H), 256, 0, stream>>>(Mbuf, thrbuf);
    band_collect<<<dim3(N / 256, B * H), 256, 0, stream>>>(Mbuf, thrbuf, cntbuf, bandbuf);
    refine_kernel<<<dim3(BAND_CAP / 4, B * H), 256, 0, stream>>>(q, kbuf, cntbuf, bandbuf, Mbuf);

    // 8. final top-512 keep flags + compacted indices
    topk_keep<<<dim3(N / 256, B * H), 256, 0, stream>>>(Mbuf, keep, kidx);

    // 9. fill non-kept rows; attention on kept rows
    fill_nonkept<<<dim3(N / 64, B * H), 256, 0, stream>>>(keep, vmeanbuf, attn_out);
    attn_kernel<<<dim3(NTOP / 64, B * H), 256, 0, stream>>>(
        q, kbuf, vbuf, rmaxbuf, kidx, attn_out);

    // 10. Output projection (split-bf16 MFMA)
    convert_hilo<<<nX / 1024, 256, 0, stream>>>(attn_out, cvAhi, cvAlo, nX);
    convert_hilo<<<nWo / 1024, 256, 0, stream>>>(Wout, cvBhi, cvBlo, nWo);
    gemm_mfma<1><<<dim3(C / 128, (B * N) / 128), 256, 0, stream>>>(
        cvAhi, cvAlo, cvBhi, cvBlo, bout, out, nullptr, nullptr, nullptr, C);
}

// Round 6
// 688.887 us; speedup vs baseline: 3.9947x; 1.6579x over previous
//
#include <hip/hip_runtime.h>
#include <math.h>

typedef unsigned short u16;
typedef __attribute__((ext_vector_type(8))) short short8v;  // 8 bf16 operand frag
typedef __attribute__((ext_vector_type(4))) float f32x4;    // MFMA accumulator

constexpr int B  = 2;
constexpr int N  = 2048;
constexpr int C  = 1024;
constexpr int H  = 16;
constexpr int DK = 64;
constexpr int NTOP = 512;
constexpr float SCALE = 0.125f;  // 1/sqrt(64)
constexpr int   BAND_CAP = 1024;
constexpr float BAND_EPS = 2e-3f;   // >> 4-term split-bf16 M error bound (~3e-5)

// ---------------------------------------------------------------------------
// fp32 -> bf16 hi/lo split (RNE): hi = bf16(x), lo = bf16(x - hi)
// ---------------------------------------------------------------------------
__device__ __forceinline__ u16 bf16_rne(float x) {
    unsigned u = __float_as_uint(x);
    unsigned r = u + 0x7fffu + ((u >> 16) & 1u);
    return (u16)(r >> 16);
}

__global__ __launch_bounds__(256) void convert_hilo(
    const float* __restrict__ src, u16* __restrict__ hi, u16* __restrict__ lo, int n)
{
    int i = (blockIdx.x * 256 + threadIdx.x) * 4;
    if (i >= n) return;
    float4 v = *(const float4*)&src[i];
    u16 h0 = bf16_rne(v.x), h1 = bf16_rne(v.y), h2 = bf16_rne(v.z), h3 = bf16_rne(v.w);
    float f0 = __uint_as_float((unsigned)h0 << 16);
    float f1 = __uint_as_float((unsigned)h1 << 16);
    float f2 = __uint_as_float((unsigned)h2 << 16);
    float f3 = __uint_as_float((unsigned)h3 << 16);
    ushort4 hh = make_ushort4(h0, h1, h2, h3);
    ushort4 ll = make_ushort4(bf16_rne(v.x - f0), bf16_rne(v.y - f1),
                              bf16_rne(v.z - f2), bf16_rne(v.w - f3));
    *(ushort4*)&hi[i] = hh;
    *(ushort4*)&lo[i] = ll;
}

// ---------------------------------------------------------------------------
// Transposed convert: v (bh, key, d) fp32 -> vt hi/lo (bh, d, key) bf16.
// grid (N/64, B*H), 256 threads.
// ---------------------------------------------------------------------------
__global__ __launch_bounds__(256) void convert_hilo_T(
    const float* __restrict__ v, u16* __restrict__ th, u16* __restrict__ tl)
{
    constexpr int LS = 68;
    __shared__ u16 Sh[64 * LS], Sl[64 * LS];
    const int bh = blockIdx.y;
    const int kt = blockIdx.x * 64;
    const int tid = threadIdx.x;
    #pragma unroll
    for (int p = 0; p < 4; ++p) {
        int idx = tid * 4 + p * 1024;
        int key = idx >> 6, d = idx & 63;
        float4 x4 = *(const float4*)&v[((size_t)bh * N + kt + key) * DK + d];
        float xs[4] = {x4.x, x4.y, x4.z, x4.w};
        ushort4 hh, ll;
        u16* hp = (u16*)&hh; u16* lp = (u16*)&ll;
        #pragma unroll
        for (int j = 0; j < 4; ++j) {
            u16 h = bf16_rne(xs[j]);
            hp[j] = h;
            lp[j] = bf16_rne(xs[j] - __uint_as_float((unsigned)h << 16));
        }
        *(ushort4*)&Sh[key * LS + d] = hh;
        *(ushort4*)&Sl[key * LS + d] = ll;
    }
    __syncthreads();
    const int d = tid >> 2, seg = tid & 3;
    u16 bufh[16], bufl[16];
    #pragma unroll
    for (int i = 0; i < 16; ++i) {
        bufh[i] = Sh[(seg * 16 + i) * LS + d];
        bufl[i] = Sl[(seg * 16 + i) * LS + d];
    }
    size_t oa = ((size_t)bh * DK + d) * N + kt + seg * 16;
    *(uint4*)&th[oa] = ((uint4*)bufh)[0];
    *(uint4*)&th[oa + 8] = ((uint4*)bufh)[1];
    *(uint4*)&tl[oa] = ((uint4*)bufl)[0];
    *(uint4*)&tl[oa + 8] = ((uint4*)bufl)[1];
}

// ---------------------------------------------------------------------------
// Split-bf16 MFMA GEMM: 128x128 tile, BK=32, 4 waves. (verified r3)
// ---------------------------------------------------------------------------
template <int MODE>
__global__ __launch_bounds__(256) void gemm_mfma(
    const u16* __restrict__ Ahi, const u16* __restrict__ Alo,
    const u16* __restrict__ Bhi, const u16* __restrict__ Blo,
    const float* __restrict__ bias, float* __restrict__ out,
    float* __restrict__ qb, float* __restrict__ kb, float* __restrict__ vb,
    int K)
{
    __shared__ __align__(16) u16 Ah[128 * 32], Al[128 * 32];
    __shared__ __align__(16) u16 Bh[128 * 32], Bl[128 * 32];

    const int tid = threadIdx.x;
    const int m0 = blockIdx.y * 128;
    const int n0 = blockIdx.x * 128;
    const int lane = tid & 63;
    const int wave = tid >> 6;
    const int wr = wave >> 1, wc = wave & 1;
    const int fr = lane & 15, sl = lane >> 4;

    f32x4 acc[4][4] = {};

    for (int k0 = 0; k0 < K; k0 += 32) {
        __syncthreads();
        #pragma unroll
        for (int c = 0; c < 2; ++c) {
            int ch = tid + c * 256;
            int row = ch >> 2, slot = ch & 3;
            int ldo = row * 32 + ((slot ^ ((row >> 1) & 3)) * 8);
            size_t ga = (size_t)(m0 + row) * K + k0 + slot * 8;
            size_t gb = (size_t)(n0 + row) * K + k0 + slot * 8;
            *(uint4*)&Ah[ldo] = *(const uint4*)&Ahi[ga];
            *(uint4*)&Al[ldo] = *(const uint4*)&Alo[ga];
            *(uint4*)&Bh[ldo] = *(const uint4*)&Bhi[gb];
            *(uint4*)&Bl[ldo] = *(const uint4*)&Blo[gb];
        }
        __syncthreads();

        short8v afh[4], afl[4], bfh[4], bfl[4];
        #pragma unroll
        for (int m = 0; m < 4; ++m) {
            int row = wr * 64 + m * 16 + fr;
            int off = row * 32 + ((sl ^ ((row >> 1) & 3)) * 8);
            afh[m] = *(const short8v*)&Ah[off];
            afl[m] = *(const short8v*)&Al[off];
        }
        #pragma unroll
        for (int n = 0; n < 4; ++n) {
            int row = wc * 64 + n * 16 + fr;
            int off = row * 32 + ((sl ^ ((row >> 1) & 3)) * 8);
            bfh[n] = *(const short8v*)&Bh[off];
            bfl[n] = *(const short8v*)&Bl[off];
        }
        #pragma unroll
        for (int m = 0; m < 4; ++m)
            #pragma unroll
            for (int n = 0; n < 4; ++n) {
                acc[m][n] = __builtin_amdgcn_mfma_f32_16x16x32_bf16(afh[m], bfh[n], acc[m][n], 0, 0, 0);
                acc[m][n] = __builtin_amdgcn_mfma_f32_16x16x32_bf16(afh[m], bfl[n], acc[m][n], 0, 0, 0);
                acc[m][n] = __builtin_amdgcn_mfma_f32_16x16x32_bf16(afl[m], bfh[n], acc[m][n], 0, 0, 0);
            }
    }

    #pragma unroll
    for (int m = 0; m < 4; ++m)
        #pragma unroll
        for (int n = 0; n < 4; ++n)
            #pragma unroll
            for (int r = 0; r < 4; ++r) {
                int grow = m0 + wr * 64 + m * 16 + sl * 4 + r;
                int gcol = n0 + wc * 64 + n * 16 + fr;
                float val = acc[m][n][r] + bias[gcol];
                if (MODE == 0) {
                    int t = gcol >> 10, h = (gcol >> 6) & 15, d = gcol & 63;
                    int bb = grow >> 11, nn = grow & (N - 1);
                    float* dst = (t == 0) ? qb : (t == 1) ? kb : vb;
                    dst[(((size_t)bb * H + h) * N + nn) * DK + d] = val;
                } else {
                    out[(size_t)grow * C + gcol] = val;
                }
            }
}

// ---------------------------------------------------------------------------
// mean[bh,d] = mean_k src[bh,k,d].  grid B*H, 256 threads.
// ---------------------------------------------------------------------------
__global__ __launch_bounds__(256) void vmean_kernel(
    const float* __restrict__ v, float* __restrict__ vmean)
{
    const int bh = blockIdx.x;
    const int d   = threadIdx.x & 63;
    const int seg = threadIdx.x >> 6;
    float s = 0.f;
    for (int kk = seg; kk < N; kk += 4) s += v[((size_t)bh * N + kk) * DK + d];
    __shared__ float part[4][64];
    part[seg][d] = s;
    __syncthreads();
    if (threadIdx.x < 64) {
        float t = part[0][d] + part[1][d] + part[2][d] + part[3][d];
        vmean[bh * DK + d] = t / (float)N;
    }
}

// ---------------------------------------------------------------------------
// Mdot[bh,row] = dot(q_row, kmean_bh)
// ---------------------------------------------------------------------------
__global__ __launch_bounds__(256) void qdot_kernel(
    const float* __restrict__ q, const float* __restrict__ kmean,
    float* __restrict__ Mdot)
{
    const int bh = blockIdx.y;
    const int row = blockIdx.x * 256 + threadIdx.x;
    __shared__ float km[DK];
    if (threadIdx.x < DK) km[threadIdx.x] = kmean[bh * DK + threadIdx.x];
    __syncthreads();
    const float* qr = &q[((size_t)bh * N + row) * DK];
    float s = 0.f;
    #pragma unroll
    for (int d4 = 0; d4 < DK; d4 += 4) {
        float4 v = *(const float4*)&qr[d4];
        s += v.x * km[d4] + v.y * km[d4 + 1] + v.z * km[d4 + 2] + v.w * km[d4 + 3];
    }
    Mdot[(size_t)bh * N + row] = s;
}

// ---------------------------------------------------------------------------
// MFMA row-max (4-term split-bf16). Approximate M; boundary refined later.
// ---------------------------------------------------------------------------
__global__ __launch_bounds__(256) void row_stats_mfma(
    const u16* __restrict__ qh_, const u16* __restrict__ ql_,
    const u16* __restrict__ kh_, const u16* __restrict__ kl_,
    const float* __restrict__ Mdot, float* __restrict__ Mout,
    float* __restrict__ rowmax)
{
    __shared__ __align__(16) u16 Kh[64 * 64];
    __shared__ __align__(16) u16 Kl[64 * 64];
    const int tid = threadIdx.x, lane = tid & 63, wave = tid >> 6;
    const int bh = blockIdx.y;
    const int q0 = blockIdx.x * 128 + wave * 32;
    const int fr = lane & 15, g = lane >> 4;

    short8v qfh[2][2], qfl[2][2];
    #pragma unroll
    for (int m = 0; m < 2; ++m)
        #pragma unroll
        for (int kk = 0; kk < 2; ++kk) {
            size_t qa = ((size_t)bh * N + q0 + m * 16 + fr) * DK + kk * 32 + g * 8;
            qfh[m][kk] = *(const short8v*)&qh_[qa];
            qfl[m][kk] = *(const short8v*)&ql_[qa];
        }

    f32x4 mx[2];
    mx[0] = (f32x4){-1e30f, -1e30f, -1e30f, -1e30f};
    mx[1] = mx[0];

    for (int kt = 0; kt < N; kt += 64) {
        __syncthreads();
        for (int c = tid; c < 512; c += 256) {
            int row = c >> 3, slot = c & 7;
            int off = row * 64 + ((slot ^ (row & 7)) * 8);
            size_t ga = ((size_t)bh * N + kt + row) * DK + slot * 8;
            *(uint4*)&Kh[off] = *(const uint4*)&kh_[ga];
            *(uint4*)&Kl[off] = *(const uint4*)&kl_[ga];
        }
        __syncthreads();
        short8v bfh[4][2], bfl[4][2];
        #pragma unroll
        for (int n = 0; n < 4; ++n)
            #pragma unroll
            for (int kk = 0; kk < 2; ++kk) {
                int key = n * 16 + fr;
                int off = key * 64 + (((g + kk * 4) ^ (key & 7)) * 8);
                bfh[n][kk] = *(const short8v*)&Kh[off];
                bfl[n][kk] = *(const short8v*)&Kl[off];
            }
        #pragma unroll
        for (int m = 0; m < 2; ++m)
            #pragma unroll
            for (int n = 0; n < 4; ++n) {
                f32x4 a = {};
                #pragma unroll
                for (int kk = 0; kk < 2; ++kk) {
                    a = __builtin_amdgcn_mfma_f32_16x16x32_bf16(qfl[m][kk], bfl[n][kk], a, 0, 0, 0);
                    a = __builtin_amdgcn_mfma_f32_16x16x32_bf16(qfl[m][kk], bfh[n][kk], a, 0, 0, 0);
                    a = __builtin_amdgcn_mfma_f32_16x16x32_bf16(qfh[m][kk], bfl[n][kk], a, 0, 0, 0);
                    a = __builtin_amdgcn_mfma_f32_16x16x32_bf16(qfh[m][kk], bfh[n][kk], a, 0, 0, 0);
                }
                #pragma unroll
                for (int r = 0; r < 4; ++r) mx[m][r] = fmaxf(mx[m][r], a[r]);
            }
    }

    #pragma unroll
    for (int w = 1; w < 16; w <<= 1)
        #pragma unroll
        for (int m = 0; m < 2; ++m)
            #pragma unroll
            for (int r = 0; r < 4; ++r)
                mx[m][r] = fmaxf(mx[m][r], __shfl_xor(mx[m][r], w, 64));

    if (fr == 0) {
        #pragma unroll
        for (int m = 0; m < 2; ++m)
            #pragma unroll
            for (int r = 0; r < 4; ++r) {
                int row = q0 + m * 16 + g * 4 + r;
                size_t idx = (size_t)bh * N + row;
                float v = mx[m][r];
                rowmax[idx] = SCALE * v;
                Mout[idx]   = SCALE * (v - Mdot[idx]);
            }
    }
}

// ---------------------------------------------------------------------------
// Boundary refinement: threshold -> band -> fp64 exact M for band rows.
// ---------------------------------------------------------------------------
__global__ void zero_cnt(int* cnt) { if (threadIdx.x < B * H) cnt[threadIdx.x] = 0; }

__global__ __launch_bounds__(256) void topk_thr(
    const float* __restrict__ Mv, float* __restrict__ thr)
{
    const int bh = blockIdx.y;
    const int qi = blockIdx.x * 256 + threadIdx.x;
    __shared__ float Ms[N];
    for (int e = threadIdx.x; e < N; e += 256) Ms[e] = Mv[(size_t)bh * N + e];
    __syncthreads();
    const float mq = Ms[qi];
    int rank = 0;
    for (int j = 0; j < N; ++j) {
        float mj = Ms[j];
        rank += (mj > mq) || (mj == mq && j < qi);
    }
    if (rank == NTOP - 1) thr[bh] = mq;   // smallest kept (approx boundary)
}

__global__ __launch_bounds__(256) void band_collect(
    const float* __restrict__ Mv, const float* __restrict__ thr,
    int* __restrict__ cnt, int* __restrict__ band)
{
    const int bh = blockIdx.y;
    const int row = blockIdx.x * 256 + threadIdx.x;
    const float m = Mv[(size_t)bh * N + row];
    if (fabsf(m - thr[bh]) <= BAND_EPS) {
        int pos = atomicAdd(&cnt[bh], 1);
        if (pos < BAND_CAP) band[bh * BAND_CAP + pos] = row;
    }
}

// Block-per-candidate (strided): LDS-staged coalesced K, fp64 exact dot.
// grid (32, B*H), 256 threads.
__global__ __launch_bounds__(256) void refine_kernel(
    const float* __restrict__ q, const float* __restrict__ k,
    const int* __restrict__ cnt, const int* __restrict__ band,
    float* __restrict__ Mv)
{
    constexpr int LS = 69;   // (5*lane + d) % 32 -> 2-way, conflict-free
    __shared__ float Ks[64 * LS];
    __shared__ float qs[DK];
    const int bh = blockIdx.y;
    const int tid = threadIdx.x;
    const int n = min(cnt[bh], BAND_CAP);
    for (int ci = blockIdx.x; ci < n; ci += 32) {
        const int row = band[bh * BAND_CAP + ci];
        __syncthreads();   // previous iteration fully done with Ks/qs
        if (tid < DK) qs[tid] = q[((size_t)bh * N + row) * DK + tid];
        double mx = -1e30, sm = 0.0;
        for (int kt = 0; kt < N; kt += 64) {
            __syncthreads();
            #pragma unroll
            for (int p = 0; p < 4; ++p) {
                int idx = tid * 4 + p * 1024;
                int kr = idx >> 6, d = idx & 63;
                float4 x4 = *(const float4*)&k[((size_t)bh * N + kt + kr) * DK + d];
                Ks[kr * LS + d]     = x4.x;
                Ks[kr * LS + d + 1] = x4.y;
                Ks[kr * LS + d + 2] = x4.z;
                Ks[kr * LS + d + 3] = x4.w;
            }
            __syncthreads();
            if (tid < 64) {
                double s = 0.0;
                #pragma unroll
                for (int d = 0; d < DK; ++d)
                    s += (double)qs[d] * (double)Ks[tid * LS + d];
                mx = fmax(mx, s);
                sm += s;
            }
        }
        if (tid < 64) {
            #pragma unroll
            for (int w = 1; w < 64; w <<= 1) {
                mx = fmax(mx, __shfl_xor(mx, w, 64));
                sm += __shfl_xor(sm, w, 64);
            }
            if (tid == 0)
                Mv[(size_t)bh * N + row] = (float)((double)SCALE * (mx - sm / (double)N));
        }
    }
}

// ---------------------------------------------------------------------------
// Final top-k on refined M: keep flag + compacted index list.
// ---------------------------------------------------------------------------
__global__ __launch_bounds__(256) void topk_keep(
    const float* __restrict__ Mv, int* __restrict__ keep, int* __restrict__ kidx)
{
    const int bh = blockIdx.y;
    const int qi = blockIdx.x * 256 + threadIdx.x;
    __shared__ float Ms[N];
    for (int e = threadIdx.x; e < N; e += 256) Ms[e] = Mv[(size_t)bh * N + e];
    __syncthreads();
    const float mq = Ms[qi];
    int rank = 0;
    for (int j = 0; j < N; ++j) {
        float mj = Ms[j];
        rank += (mj > mq) || (mj == mq && j < qi);
    }
    keep[(size_t)bh * N + qi] = (rank < NTOP) ? 1 : 0;
    if (rank < NTOP) kidx[bh * NTOP + rank] = qi;
}

// ---------------------------------------------------------------------------
// Fill non-kept rows of attn_out with vmean. grid (N/64, B*H)
// ---------------------------------------------------------------------------
__global__ __launch_bounds__(256) void fill_nonkept(
    const int* __restrict__ keep, const float* __restrict__ vmean,
    float* __restrict__ attn_out)
{
    const int bh = blockIdx.y;
    const int b = bh >> 4, h = bh & 15;
    const int d = threadIdx.x & 63;
    const int rr = threadIdx.x >> 6;
    const float vm = vmean[bh * DK + d];
    #pragma unroll
    for (int i = 0; i < 16; ++i) {
        int row = blockIdx.x * 64 + i * 4 + rr;
        if (!keep[(size_t)bh * N + row])
            attn_out[((size_t)b * N + row) * C + h * DK + d] = vm;
    }
}

// ---------------------------------------------------------------------------
// MFMA attention on kept rows. Block = 64 q rows (4 waves x 16).
// Score: 3-term split-bf16 QK^T (K staged like row_stats). Softmax in-reg.
// P -> bf16 hi/lo -> per-wave LDS (XOR slot swizzle). PV: 3-term vs V^T LDS.
// 1D grid 256, XCD-swizzled: bh's 8 blocks co-located per XCD.
// ---------------------------------------------------------------------------
__global__ __launch_bounds__(256) void attn_mfma(
    const u16* __restrict__ qh_, const u16* __restrict__ ql_,
    const u16* __restrict__ kh_, const u16* __restrict__ kl_,
    const u16* __restrict__ vth_, const u16* __restrict__ vtl_,
    const float* __restrict__ rowmax, const int* __restrict__ kidx,
    float* __restrict__ attn_out)
{
    __shared__ __align__(16) u16 Kh[64 * 64], Kl[64 * 64];
    __shared__ __align__(16) u16 Vh[64 * 64], Vl[64 * 64];
    __shared__ __align__(16) u16 Ph[4][16 * 64], Pl[4][16 * 64];

    const int tid = threadIdx.x, lane = tid & 63, wave = tid >> 6;
    const int wg = blockIdx.x;
    const int bh = ((wg >> 6) << 3) | (wg & 7);   // co-locate bh on XCD wg&7
    const int xblk = (wg >> 3) & 7;
    const int b = bh >> 4, h = bh & 15;
    const int q0 = xblk * 64 + wave * 16;
    const int fr = lane & 15, sl = lane >> 4;

    const int* kix = kidx + bh * NTOP;
    const int qrow_f = kix[q0 + fr];              // A-frag row
    int qr_o[4]; float rmax_r[4];
    #pragma unroll
    for (int r = 0; r < 4; ++r) {
        qr_o[r] = kix[q0 + sl * 4 + r];           // C/D row
        rmax_r[r] = rowmax[(size_t)bh * N + qr_o[r]];
    }

    short8v qfh[2], qfl[2];
    #pragma unroll
    for (int kk = 0; kk < 2; ++kk) {
        size_t qa = ((size_t)bh * N + qrow_f) * DK + kk * 32 + sl * 8;
        qfh[kk] = *(const short8v*)&qh_[qa];
        qfl[kk] = *(const short8v*)&ql_[qa];
    }

    f32x4 opv[4] = {};
    float lsum[4] = {};

    for (int kt = 0; kt < N; kt += 64) {
        __syncthreads();
        for (int c = tid; c < 512; c += 256) {
            int row = c >> 3, slot = c & 7;
            int off = row * 64 + ((slot ^ (row & 7)) * 8);
            size_t kga = ((size_t)bh * N + kt + row) * DK + slot * 8;
            size_t vga = ((size_t)bh * DK + row) * N + kt + slot * 8;
            *(uint4*)&Kh[off] = *(const uint4*)&kh_[kga];
            *(uint4*)&Kl[off] = *(const uint4*)&kl_[kga];
            *(uint4*)&Vh[off] = *(const uint4*)&vth_[vga];
            *(uint4*)&Vl[off] = *(const uint4*)&vtl_[vga];
        }
        __syncthreads();

        // score + softmax + P store
        #pragma unroll
        for (int n = 0; n < 4; ++n) {
            f32x4 a = {};
            #pragma unroll
            for (int kk = 0; kk < 2; ++kk) {
                int key = n * 16 + fr;
                int off = key * 64 + (((sl + kk * 4) ^ (key & 7)) * 8);
                short8v bh_f = *(const short8v*)&Kh[off];
                short8v bl_f = *(const short8v*)&Kl[off];
                a = __builtin_amdgcn_mfma_f32_16x16x32_bf16(qfl[kk], bh_f, a, 0, 0, 0);
                a = __builtin_amdgcn_mfma_f32_16x16x32_bf16(qfh[kk], bl_f, a, 0, 0, 0);
                a = __builtin_amdgcn_mfma_f32_16x16x32_bf16(qfh[kk], bh_f, a, 0, 0, 0);
            }
            #pragma unroll
            for (int r = 0; r < 4; ++r) {
                float p = __expf(a[r] * SCALE - rmax_r[r]);
                lsum[r] += p;
                u16 ph = bf16_rne(p);
                u16 pl = bf16_rne(p - __uint_as_float((unsigned)ph << 16));
                int q_l = sl * 4 + r;
                int key = n * 16 + fr;
                int off = q_l * 64 + (((key >> 3) ^ (q_l & 7)) * 8) + (key & 7);
                Ph[wave][off] = ph;
                Pl[wave][off] = pl;
            }
        }

        // PV: D[q][d] += P * V^T   (P reads are same-wave; compiler inserts waits)
        #pragma unroll
        for (int kk = 0; kk < 2; ++kk) {
            int aoff = fr * 64 + (((kk * 4 + sl) ^ (fr & 7)) * 8);
            short8v pah = *(const short8v*)&Ph[wave][aoff];
            short8v pal = *(const short8v*)&Pl[wave][aoff];
            #pragma unroll
            for (int n = 0; n < 4; ++n) {
                int d = n * 16 + fr;
                int voff = d * 64 + (((kk * 4 + sl) ^ (d & 7)) * 8);
                short8v vhf = *(const short8v*)&Vh[voff];
                short8v vlf = *(const short8v*)&Vl[voff];
                opv[n] = __builtin_amdgcn_mfma_f32_16x16x32_bf16(pal, vhf, opv[n], 0, 0, 0);
                opv[n] = __builtin_amdgcn_mfma_f32_16x16x32_bf16(pah, vlf, opv[n], 0, 0, 0);
                opv[n] = __builtin_amdgcn_mfma_f32_16x16x32_bf16(pah, vhf, opv[n], 0, 0, 0);
            }
        }
    }

    #pragma unroll
    for (int w = 1; w < 16; w <<= 1)
        #pragma unroll
        for (int r = 0; r < 4; ++r)
            lsum[r] += __shfl_xor(lsum[r], w, 64);

    #pragma unroll
    for (int r = 0; r < 4; ++r) {
        const float inv = 1.0f / lsum[r];
        float* orow = attn_out + ((size_t)b * N + qr_o[r]) * C + h * DK;
        #pragma unroll
        for (int n = 0; n < 4; ++n)
            orow[n * 16 + fr] = opv[n][r] * inv;
    }
}

// ---------------------------------------------------------------------------
extern "C" void kernel_launch(void* const* d_in, const int* in_sizes, int n_in,
                              void* d_out, int out_size, void* d_ws, size_t ws_size,
                              hipStream_t stream)
{
    const float* x    = (const float*)d_in[0];
    const float* Wqkv = (const float*)d_in[1];
    const float* bqkv = (const float*)d_in[2];
    const float* Wout = (const float*)d_in[3];
    const float* bout = (const float*)d_in[4];
    float* out = (float*)d_out;

    char* ws = (char*)d_ws;
    size_t off = 0;
    auto alloc = [&](size_t bytes) -> void* {
        void* p = ws + off;
        off += (bytes + 255) & ~(size_t)255;
        return p;
    };

    const size_t BHND = (size_t)B * H * N * DK;       // 4 Mi elems
    float* q        = (float*)alloc(BHND * 4);
    float* kbuf     = (float*)alloc(BHND * 4);
    float* vbuf     = (float*)alloc(BHND * 4);
    float* attn_out = (float*)alloc((size_t)B * N * C * 4);
    u16* cvAhi = (u16*)alloc((size_t)B * N * C * 2);  // x / q_hi / attn_out hi
    u16* cvAlo = (u16*)alloc((size_t)B * N * C * 2);
    u16* cvBhi = (u16*)alloc((size_t)3 * C * C * 2);
    u16* cvBlo = (u16*)alloc((size_t)3 * C * C * 2);
    u16* khi   = (u16*)alloc(BHND * 2);
    u16* klo   = (u16*)alloc(BHND * 2);
    u16* vthi  = (u16*)alloc(BHND * 2);
    u16* vtlo  = (u16*)alloc(BHND * 2);
    float* Mbuf     = (float*)alloc((size_t)B * H * N * 4);
    float* rmaxbuf  = (float*)alloc((size_t)B * H * N * 4);
    float* Mdot     = (float*)alloc((size_t)B * H * N * 4);
    int*   keep     = (int*)  alloc((size_t)B * H * N * 4);
    int*   kidx     = (int*)  alloc((size_t)B * H * NTOP * 4);
    float* vmeanbuf = (float*)alloc((size_t)B * H * DK * 4);
    float* kmeanbuf = (float*)alloc((size_t)B * H * DK * 4);
    float* thrbuf   = (float*)alloc((size_t)B * H * 4);
    int*   cntbuf   = (int*)  alloc((size_t)B * H * 4);
    int*   bandbuf  = (int*)  alloc((size_t)B * H * BAND_CAP * 4);

    const int nX = B * N * C;        // 4M
    const int nW = 3 * C * C;        // 3M
    const int nWo = C * C;           // 1M

    // 1. convert x, Wqkv to bf16 hi/lo
    convert_hilo<<<nX / 1024, 256, 0, stream>>>(x, cvAhi, cvAlo, nX);
    convert_hilo<<<nW / 1024, 256, 0, stream>>>(Wqkv, cvBhi, cvBlo, nW);

    // 2. QKV projection (split-bf16 MFMA), scatter to q/k/v
    gemm_mfma<0><<<dim3(3 * C / 128, (B * N) / 128), 256, 0, stream>>>(
        cvAhi, cvAlo, cvBhi, cvBlo, bqkv, nullptr, q, kbuf, vbuf, C);

    // 3. convert q,k hi/lo; v transposed hi/lo
    u16* qhi = cvAhi; u16* qlo = cvAlo;
    convert_hilo<<<nX / 1024, 256, 0, stream>>>(q, qhi, qlo, nX);
    convert_hilo<<<nX / 1024, 256, 0, stream>>>(kbuf, khi, klo, nX);
    convert_hilo_T<<<dim3(N / 64, B * H), 256, 0, stream>>>(vbuf, vthi, vtlo);

    // 4. column means of v (output fill) and k (exact mean-score term)
    vmean_kernel<<<B * H, 256, 0, stream>>>(vbuf, vmeanbuf);
    vmean_kernel<<<B * H, 256, 0, stream>>>(kbuf, kmeanbuf);

    // 5. mean term per row: Mdot = q . kmean
    qdot_kernel<<<dim3(N / 256, B * H), 256, 0, stream>>>(q, kmeanbuf, Mdot);

    // 6. MFMA approximate row max -> M, rowmax
    row_stats_mfma<<<dim3(N / 128, B * H), 256, 0, stream>>>(
        qhi, qlo, khi, klo, Mdot, Mbuf, rmaxbuf);

    // 7. boundary refinement: threshold -> band -> fp64 exact M
    zero_cnt<<<1, 64, 0, stream>>>(cntbuf);
    topk_thr<<<dim3(N / 256, B * H), 256, 0, stream>>>(Mbuf, thrbuf);
    band_collect<<<dim3(N / 256, B * H), 256, 0, stream>>>(Mbuf, thrbuf, cntbuf, bandbuf);
    refine_kernel<<<dim3(32, B * H), 256, 0, stream>>>(q, kbuf, cntbuf, bandbuf, Mbuf);

    // 8. final top-512 keep flags + compacted indices
    topk_keep<<<dim3(N / 256, B * H), 256, 0, stream>>>(Mbuf, keep, kidx);

    // 9. fill non-kept rows; MFMA attention on kept rows
    fill_nonkept<<<dim3(N / 64, B * H), 256, 0, stream>>>(keep, vmeanbuf, attn_out);
    attn_mfma<<<256, 256, 0, stream>>>(
        qhi, qlo, khi, klo, vthi, vtlo, rmaxbuf, kidx, attn_out);

    // 10. Output projection (split-bf16 MFMA)
    convert_hilo<<<nX / 1024, 256, 0, stream>>>(attn_out, cvAhi, cvAlo, nX);
    convert_hilo<<<nWo / 1024, 256, 0, stream>>>(Wout, cvBhi, cvBlo, nWo);
    gemm_mfma<1><<<dim3(C / 128, (B * N) / 128), 256, 0, stream>>>(
        cvAhi, cvAlo, cvBhi, cvBlo, bout, out, nullptr, nullptr, nullptr, C);
}

// Round 7
// 476.428 us; speedup vs baseline: 5.7761x; 1.4459x over previous
//
#include <hip/hip_runtime.h>
#include <math.h>

typedef unsigned short u16;
typedef __attribute__((ext_vector_type(8))) short short8v;  // 8 bf16 operand frag
typedef __attribute__((ext_vector_type(4))) float f32x4;    // MFMA accumulator

constexpr int B  = 2;
constexpr int N  = 2048;
constexpr int C  = 1024;
constexpr int H  = 16;
constexpr int DK = 64;
constexpr int NTOP = 512;
constexpr float SCALE = 0.125f;  // 1/sqrt(64)
constexpr int   BAND_CAP = 1024;
constexpr float BAND_EPS = 2e-3f;   // >> 4-term split-bf16 M error bound (~3e-5)
constexpr int   CSEG = 16;          // column-sum segments per bh

// ---------------------------------------------------------------------------
// fp32 -> bf16 hi/lo split (RNE): hi = bf16(x), lo = bf16(x - hi)
// ---------------------------------------------------------------------------
__device__ __forceinline__ u16 bf16_rne(float x) {
    unsigned u = __float_as_uint(x);
    unsigned r = u + 0x7fffu + ((u >> 16) & 1u);
    return (u16)(r >> 16);
}

__global__ __launch_bounds__(256) void convert_hilo(
    const float* __restrict__ src, u16* __restrict__ hi, u16* __restrict__ lo, int n)
{
    int i = (blockIdx.x * 256 + threadIdx.x) * 4;
    if (i >= n) return;
    float4 v = *(const float4*)&src[i];
    u16 h0 = bf16_rne(v.x), h1 = bf16_rne(v.y), h2 = bf16_rne(v.z), h3 = bf16_rne(v.w);
    float f0 = __uint_as_float((unsigned)h0 << 16);
    float f1 = __uint_as_float((unsigned)h1 << 16);
    float f2 = __uint_as_float((unsigned)h2 << 16);
    float f3 = __uint_as_float((unsigned)h3 << 16);
    ushort4 hh = make_ushort4(h0, h1, h2, h3);
    ushort4 ll = make_ushort4(bf16_rne(v.x - f0), bf16_rne(v.y - f1),
                              bf16_rne(v.z - f2), bf16_rne(v.w - f3));
    *(ushort4*)&hi[i] = hh;
    *(ushort4*)&lo[i] = ll;
}

// ---------------------------------------------------------------------------
// Transposed convert: v (bh, key, d) fp32 -> vt hi/lo (bh, d, key) bf16.
// grid (N/64, B*H), 256 threads.
// ---------------------------------------------------------------------------
__global__ __launch_bounds__(256) void convert_hilo_T(
    const float* __restrict__ v, u16* __restrict__ th, u16* __restrict__ tl)
{
    constexpr int LS = 68;
    __shared__ u16 Sh[64 * LS], Sl[64 * LS];
    const int bh = blockIdx.y;
    const int kt = blockIdx.x * 64;
    const int tid = threadIdx.x;
    #pragma unroll
    for (int p = 0; p < 4; ++p) {
        int idx = tid * 4 + p * 1024;
        int key = idx >> 6, d = idx & 63;
        float4 x4 = *(const float4*)&v[((size_t)bh * N + kt + key) * DK + d];
        float xs[4] = {x4.x, x4.y, x4.z, x4.w};
        ushort4 hh, ll;
        u16* hp = (u16*)&hh; u16* lp = (u16*)&ll;
        #pragma unroll
        for (int j = 0; j < 4; ++j) {
            u16 h = bf16_rne(xs[j]);
            hp[j] = h;
            lp[j] = bf16_rne(xs[j] - __uint_as_float((unsigned)h << 16));
        }
        *(ushort4*)&Sh[key * LS + d] = hh;
        *(ushort4*)&Sl[key * LS + d] = ll;
    }
    __syncthreads();
    const int d = tid >> 2, seg = tid & 3;
    u16 bufh[16], bufl[16];
    #pragma unroll
    for (int i = 0; i < 16; ++i) {
        bufh[i] = Sh[(seg * 16 + i) * LS + d];
        bufl[i] = Sl[(seg * 16 + i) * LS + d];
    }
    size_t oa = ((size_t)bh * DK + d) * N + kt + seg * 16;
    *(uint4*)&th[oa] = ((uint4*)bufh)[0];
    *(uint4*)&th[oa + 8] = ((uint4*)bufh)[1];
    *(uint4*)&tl[oa] = ((uint4*)bufl)[0];
    *(uint4*)&tl[oa + 8] = ((uint4*)bufl)[1];
}

// ---------------------------------------------------------------------------
// Split-bf16 MFMA GEMM: 128x128 tile, BK=32, 4 waves. (verified r3)
// ---------------------------------------------------------------------------
template <int MODE>
__global__ __launch_bounds__(256) void gemm_mfma(
    const u16* __restrict__ Ahi, const u16* __restrict__ Alo,
    const u16* __restrict__ Bhi, const u16* __restrict__ Blo,
    const float* __restrict__ bias, float* __restrict__ out,
    float* __restrict__ qb, float* __restrict__ kb, float* __restrict__ vb,
    int K)
{
    __shared__ __align__(16) u16 Ah[128 * 32], Al[128 * 32];
    __shared__ __align__(16) u16 Bh[128 * 32], Bl[128 * 32];

    const int tid = threadIdx.x;
    const int m0 = blockIdx.y * 128;
    const int n0 = blockIdx.x * 128;
    const int lane = tid & 63;
    const int wave = tid >> 6;
    const int wr = wave >> 1, wc = wave & 1;
    const int fr = lane & 15, sl = lane >> 4;

    f32x4 acc[4][4] = {};

    for (int k0 = 0; k0 < K; k0 += 32) {
        __syncthreads();
        #pragma unroll
        for (int c = 0; c < 2; ++c) {
            int ch = tid + c * 256;
            int row = ch >> 2, slot = ch & 3;
            int ldo = row * 32 + ((slot ^ ((row >> 1) & 3)) * 8);
            size_t ga = (size_t)(m0 + row) * K + k0 + slot * 8;
            size_t gb = (size_t)(n0 + row) * K + k0 + slot * 8;
            *(uint4*)&Ah[ldo] = *(const uint4*)&Ahi[ga];
            *(uint4*)&Al[ldo] = *(const uint4*)&Alo[ga];
            *(uint4*)&Bh[ldo] = *(const uint4*)&Bhi[gb];
            *(uint4*)&Bl[ldo] = *(const uint4*)&Blo[gb];
        }
        __syncthreads();

        short8v afh[4], afl[4], bfh[4], bfl[4];
        #pragma unroll
        for (int m = 0; m < 4; ++m) {
            int row = wr * 64 + m * 16 + fr;
            int off = row * 32 + ((sl ^ ((row >> 1) & 3)) * 8);
            afh[m] = *(const short8v*)&Ah[off];
            afl[m] = *(const short8v*)&Al[off];
        }
        #pragma unroll
        for (int n = 0; n < 4; ++n) {
            int row = wc * 64 + n * 16 + fr;
            int off = row * 32 + ((sl ^ ((row >> 1) & 3)) * 8);
            bfh[n] = *(const short8v*)&Bh[off];
            bfl[n] = *(const short8v*)&Bl[off];
        }
        #pragma unroll
        for (int m = 0; m < 4; ++m)
            #pragma unroll
            for (int n = 0; n < 4; ++n) {
                acc[m][n] = __builtin_amdgcn_mfma_f32_16x16x32_bf16(afh[m], bfh[n], acc[m][n], 0, 0, 0);
                acc[m][n] = __builtin_amdgcn_mfma_f32_16x16x32_bf16(afh[m], bfl[n], acc[m][n], 0, 0, 0);
                acc[m][n] = __builtin_amdgcn_mfma_f32_16x16x32_bf16(afl[m], bfh[n], acc[m][n], 0, 0, 0);
            }
    }

    #pragma unroll
    for (int m = 0; m < 4; ++m)
        #pragma unroll
        for (int n = 0; n < 4; ++n)
            #pragma unroll
            for (int r = 0; r < 4; ++r) {
                int grow = m0 + wr * 64 + m * 16 + sl * 4 + r;
                int gcol = n0 + wc * 64 + n * 16 + fr;
                float val = acc[m][n][r] + bias[gcol];
                if (MODE == 0) {
                    int t = gcol >> 10, h = (gcol >> 6) & 15, d = gcol & 63;
                    int bb = grow >> 11, nn = grow & (N - 1);
                    float* dst = (t == 0) ? qb : (t == 1) ? kb : vb;
                    dst[(((size_t)bb * H + h) * N + nn) * DK + d] = val;
                } else {
                    out[(size_t)grow * C + gcol] = val;
                }
            }
}

// ---------------------------------------------------------------------------
// Column sums, two deterministic passes.
// pass 1: partial[bh][seg][d] = sum of 128 keys.  grid (CSEG, B*H)
// pass 2: mean[bh][d] = sum(partial) / N.        grid (B*H), 64 thr
// ---------------------------------------------------------------------------
__global__ __launch_bounds__(256) void colsum_part(
    const float* __restrict__ src, float* __restrict__ partial)
{
    const int bh = blockIdx.y, seg = blockIdx.x;
    const int d = threadIdx.x & 63;
    const int sub = threadIdx.x >> 6;
    const int k0 = seg * (N / CSEG);
    float s = 0.f;
    for (int kk = sub; kk < N / CSEG; kk += 4)
        s += src[((size_t)bh * N + k0 + kk) * DK + d];
    __shared__ float part[4][64];
    part[sub][d] = s;
    __syncthreads();
    if (threadIdx.x < 64)
        partial[((size_t)bh * CSEG + seg) * DK + d] =
            part[0][d] + part[1][d] + part[2][d] + part[3][d];
}

__global__ __launch_bounds__(64) void colsum_final(
    const float* __restrict__ partial, float* __restrict__ mean)
{
    const int bh = blockIdx.x, d = threadIdx.x;
    float s = 0.f;
    #pragma unroll
    for (int g = 0; g < CSEG; ++g) s += partial[((size_t)bh * CSEG + g) * DK + d];
    mean[bh * DK + d] = s / (float)N;
}

// ---------------------------------------------------------------------------
// Mdot[bh,row] = dot(q_row, kmean_bh)
// ---------------------------------------------------------------------------
__global__ __launch_bounds__(256) void qdot_kernel(
    const float* __restrict__ q, const float* __restrict__ kmean,
    float* __restrict__ Mdot)
{
    const int bh = blockIdx.y;
    const int row = blockIdx.x * 256 + threadIdx.x;
    __shared__ float km[DK];
    if (threadIdx.x < DK) km[threadIdx.x] = kmean[bh * DK + threadIdx.x];
    __syncthreads();
    const float* qr = &q[((size_t)bh * N + row) * DK];
    float s = 0.f;
    #pragma unroll
    for (int d4 = 0; d4 < DK; d4 += 4) {
        float4 v = *(const float4*)&qr[d4];
        s += v.x * km[d4] + v.y * km[d4 + 1] + v.z * km[d4 + 2] + v.w * km[d4 + 3];
    }
    Mdot[(size_t)bh * N + row] = s;
}

// ---------------------------------------------------------------------------
// MFMA row-max (4-term split-bf16). Approximate M; boundary refined later.
// ---------------------------------------------------------------------------
__global__ __launch_bounds__(256) void row_stats_mfma(
    const u16* __restrict__ qh_, const u16* __restrict__ ql_,
    const u16* __restrict__ kh_, const u16* __restrict__ kl_,
    const float* __restrict__ Mdot, float* __restrict__ Mout,
    float* __restrict__ rowmax)
{
    __shared__ __align__(16) u16 Kh[64 * 64];
    __shared__ __align__(16) u16 Kl[64 * 64];
    const int tid = threadIdx.x, lane = tid & 63, wave = tid >> 6;
    const int bh = blockIdx.y;
    const int q0 = blockIdx.x * 128 + wave * 32;
    const int fr = lane & 15, g = lane >> 4;

    short8v qfh[2][2], qfl[2][2];
    #pragma unroll
    for (int m = 0; m < 2; ++m)
        #pragma unroll
        for (int kk = 0; kk < 2; ++kk) {
            size_t qa = ((size_t)bh * N + q0 + m * 16 + fr) * DK + kk * 32 + g * 8;
            qfh[m][kk] = *(const short8v*)&qh_[qa];
            qfl[m][kk] = *(const short8v*)&ql_[qa];
        }

    f32x4 mx[2];
    mx[0] = (f32x4){-1e30f, -1e30f, -1e30f, -1e30f};
    mx[1] = mx[0];

    for (int kt = 0; kt < N; kt += 64) {
        __syncthreads();
        for (int c = tid; c < 512; c += 256) {
            int row = c >> 3, slot = c & 7;
            int off = row * 64 + ((slot ^ (row & 7)) * 8);
            size_t ga = ((size_t)bh * N + kt + row) * DK + slot * 8;
            *(uint4*)&Kh[off] = *(const uint4*)&kh_[ga];
            *(uint4*)&Kl[off] = *(const uint4*)&kl_[ga];
        }
        __syncthreads();
        short8v bfh[4][2], bfl[4][2];
        #pragma unroll
        for (int n = 0; n < 4; ++n)
            #pragma unroll
            for (int kk = 0; kk < 2; ++kk) {
                int key = n * 16 + fr;
                int off = key * 64 + (((g + kk * 4) ^ (key & 7)) * 8);
                bfh[n][kk] = *(const short8v*)&Kh[off];
                bfl[n][kk] = *(const short8v*)&Kl[off];
            }
        #pragma unroll
        for (int m = 0; m < 2; ++m)
            #pragma unroll
            for (int n = 0; n < 4; ++n) {
                f32x4 a = {};
                #pragma unroll
                for (int kk = 0; kk < 2; ++kk) {
                    a = __builtin_amdgcn_mfma_f32_16x16x32_bf16(qfl[m][kk], bfl[n][kk], a, 0, 0, 0);
                    a = __builtin_amdgcn_mfma_f32_16x16x32_bf16(qfl[m][kk], bfh[n][kk], a, 0, 0, 0);
                    a = __builtin_amdgcn_mfma_f32_16x16x32_bf16(qfh[m][kk], bfl[n][kk], a, 0, 0, 0);
                    a = __builtin_amdgcn_mfma_f32_16x16x32_bf16(qfh[m][kk], bfh[n][kk], a, 0, 0, 0);
                }
                #pragma unroll
                for (int r = 0; r < 4; ++r) mx[m][r] = fmaxf(mx[m][r], a[r]);
            }
    }

    #pragma unroll
    for (int w = 1; w < 16; w <<= 1)
        #pragma unroll
        for (int m = 0; m < 2; ++m)
            #pragma unroll
            for (int r = 0; r < 4; ++r)
                mx[m][r] = fmaxf(mx[m][r], __shfl_xor(mx[m][r], w, 64));

    if (fr == 0) {
        #pragma unroll
        for (int m = 0; m < 2; ++m)
            #pragma unroll
            for (int r = 0; r < 4; ++r) {
                int row = q0 + m * 16 + g * 4 + r;
                size_t idx = (size_t)bh * N + row;
                float v = mx[m][r];
                rowmax[idx] = SCALE * v;
                Mout[idx]   = SCALE * (v - Mdot[idx]);
            }
    }
}

// ---------------------------------------------------------------------------
// Boundary refinement: threshold -> band -> fp64 exact M for band rows.
// ---------------------------------------------------------------------------
__global__ void zero_cnt(int* cnt) { if (threadIdx.x < B * H) cnt[threadIdx.x] = 0; }

__global__ __launch_bounds__(256) void topk_thr(
    const float* __restrict__ Mv, float* __restrict__ thr)
{
    const int bh = blockIdx.y;
    const int qi = blockIdx.x * 256 + threadIdx.x;
    __shared__ float Ms[N];
    for (int e = threadIdx.x; e < N; e += 256) Ms[e] = Mv[(size_t)bh * N + e];
    __syncthreads();
    const float mq = Ms[qi];
    int rank = 0;
    for (int j = 0; j < N; ++j) {
        float mj = Ms[j];
        rank += (mj > mq) || (mj == mq && j < qi);
    }
    if (rank == NTOP - 1) thr[bh] = mq;   // smallest kept (approx boundary)
}

__global__ __launch_bounds__(256) void band_collect(
    const float* __restrict__ Mv, const float* __restrict__ thr,
    int* __restrict__ cnt, int* __restrict__ band)
{
    const int bh = blockIdx.y;
    const int row = blockIdx.x * 256 + threadIdx.x;
    const float m = Mv[(size_t)bh * N + row];
    if (fabsf(m - thr[bh]) <= BAND_EPS) {
        int pos = atomicAdd(&cnt[bh], 1);
        if (pos < BAND_CAP) band[bh * BAND_CAP + pos] = row;
    }
}

// Block-per-candidate (strided): LDS-staged coalesced K, fp64 exact dot.
// grid (32, B*H), 256 threads.
__global__ __launch_bounds__(256) void refine_kernel(
    const float* __restrict__ q, const float* __restrict__ k,
    const int* __restrict__ cnt, const int* __restrict__ band,
    float* __restrict__ Mv)
{
    constexpr int LS = 69;
    __shared__ float Ks[64 * LS];
    __shared__ float qs[DK];
    const int bh = blockIdx.y;
    const int tid = threadIdx.x;
    const int n = min(cnt[bh], BAND_CAP);
    for (int ci = blockIdx.x; ci < n; ci += 32) {
        const int row = band[bh * BAND_CAP + ci];
        __syncthreads();
        if (tid < DK) qs[tid] = q[((size_t)bh * N + row) * DK + tid];
        double mx = -1e30, sm = 0.0;
        for (int kt = 0; kt < N; kt += 64) {
            __syncthreads();
            #pragma unroll
            for (int p = 0; p < 4; ++p) {
                int idx = tid * 4 + p * 1024;
                int kr = idx >> 6, d = idx & 63;
                float4 x4 = *(const float4*)&k[((size_t)bh * N + kt + kr) * DK + d];
                Ks[kr * LS + d]     = x4.x;
                Ks[kr * LS + d + 1] = x4.y;
                Ks[kr * LS + d + 2] = x4.z;
                Ks[kr * LS + d + 3] = x4.w;
            }
            __syncthreads();
            if (tid < 64) {
                double s = 0.0;
                #pragma unroll
                for (int d = 0; d < DK; ++d)
                    s += (double)qs[d] * (double)Ks[tid * LS + d];
                mx = fmax(mx, s);
                sm += s;
            }
        }
        if (tid < 64) {
            #pragma unroll
            for (int w = 1; w < 64; w <<= 1) {
                mx = fmax(mx, __shfl_xor(mx, w, 64));
                sm += __shfl_xor(sm, w, 64);
            }
            if (tid == 0)
                Mv[(size_t)bh * N + row] = (float)((double)SCALE * (mx - sm / (double)N));
        }
    }
}

// ---------------------------------------------------------------------------
// Final top-k on refined M: keep flag + compacted index list.
// ---------------------------------------------------------------------------
__global__ __launch_bounds__(256) void topk_keep(
    const float* __restrict__ Mv, int* __restrict__ keep, int* __restrict__ kidx)
{
    const int bh = blockIdx.y;
    const int qi = blockIdx.x * 256 + threadIdx.x;
    __shared__ float Ms[N];
    for (int e = threadIdx.x; e < N; e += 256) Ms[e] = Mv[(size_t)bh * N + e];
    __syncthreads();
    const float mq = Ms[qi];
    int rank = 0;
    for (int j = 0; j < N; ++j) {
        float mj = Ms[j];
        rank += (mj > mq) || (mj == mq && j < qi);
    }
    keep[(size_t)bh * N + qi] = (rank < NTOP) ? 1 : 0;
    if (rank < NTOP) kidx[bh * NTOP + rank] = qi;
}

// ---------------------------------------------------------------------------
// Fill non-kept rows of attn_out with vmean. grid (N/64, B*H)
// ---------------------------------------------------------------------------
__global__ __launch_bounds__(256) void fill_nonkept(
    const int* __restrict__ keep, const float* __restrict__ vmean,
    float* __restrict__ attn_out)
{
    const int bh = blockIdx.y;
    const int b = bh >> 4, h = bh & 15;
    const int d = threadIdx.x & 63;
    const int rr = threadIdx.x >> 6;
    const float vm = vmean[bh * DK + d];
    #pragma unroll
    for (int i = 0; i < 16; ++i) {
        int row = blockIdx.x * 64 + i * 4 + rr;
        if (!keep[(size_t)bh * N + row])
            attn_out[((size_t)b * N + row) * C + h * DK + d] = vm;
    }
}

// ---------------------------------------------------------------------------
// MFMA attention on kept rows. (verified r6)
// ---------------------------------------------------------------------------
__global__ __launch_bounds__(256) void attn_mfma(
    const u16* __restrict__ qh_, const u16* __restrict__ ql_,
    const u16* __restrict__ kh_, const u16* __restrict__ kl_,
    const u16* __restrict__ vth_, const u16* __restrict__ vtl_,
    const float* __restrict__ rowmax, const int* __restrict__ kidx,
    float* __restrict__ attn_out)
{
    __shared__ __align__(16) u16 Kh[64 * 64], Kl[64 * 64];
    __shared__ __align__(16) u16 Vh[64 * 64], Vl[64 * 64];
    __shared__ __align__(16) u16 Ph[4][16 * 64], Pl[4][16 * 64];

    const int tid = threadIdx.x, lane = tid & 63, wave = tid >> 6;
    const int wg = blockIdx.x;
    const int bh = ((wg >> 6) << 3) | (wg & 7);
    const int xblk = (wg >> 3) & 7;
    const int b = bh >> 4, h = bh & 15;
    const int q0 = xblk * 64 + wave * 16;
    const int fr = lane & 15, sl = lane >> 4;

    const int* kix = kidx + bh * NTOP;
    const int qrow_f = kix[q0 + fr];
    int qr_o[4]; float rmax_r[4];
    #pragma unroll
    for (int r = 0; r < 4; ++r) {
        qr_o[r] = kix[q0 + sl * 4 + r];
        rmax_r[r] = rowmax[(size_t)bh * N + qr_o[r]];
    }

    short8v qfh[2], qfl[2];
    #pragma unroll
    for (int kk = 0; kk < 2; ++kk) {
        size_t qa = ((size_t)bh * N + qrow_f) * DK + kk * 32 + sl * 8;
        qfh[kk] = *(const short8v*)&qh_[qa];
        qfl[kk] = *(const short8v*)&ql_[qa];
    }

    f32x4 opv[4] = {};
    float lsum[4] = {};

    for (int kt = 0; kt < N; kt += 64) {
        __syncthreads();
        for (int c = tid; c < 512; c += 256) {
            int row = c >> 3, slot = c & 7;
            int off = row * 64 + ((slot ^ (row & 7)) * 8);
            size_t kga = ((size_t)bh * N + kt + row) * DK + slot * 8;
            size_t vga = ((size_t)bh * DK + row) * N + kt + slot * 8;
            *(uint4*)&Kh[off] = *(const uint4*)&kh_[kga];
            *(uint4*)&Kl[off] = *(const uint4*)&kl_[kga];
            *(uint4*)&Vh[off] = *(const uint4*)&vth_[vga];
            *(uint4*)&Vl[off] = *(const uint4*)&vtl_[vga];
        }
        __syncthreads();

        #pragma unroll
        for (int n = 0; n < 4; ++n) {
            f32x4 a = {};
            #pragma unroll
            for (int kk = 0; kk < 2; ++kk) {
                int key = n * 16 + fr;
                int off = key * 64 + (((sl + kk * 4) ^ (key & 7)) * 8);
                short8v bh_f = *(const short8v*)&Kh[off];
                short8v bl_f = *(const short8v*)&Kl[off];
                a = __builtin_amdgcn_mfma_f32_16x16x32_bf16(qfl[kk], bh_f, a, 0, 0, 0);
                a = __builtin_amdgcn_mfma_f32_16x16x32_bf16(qfh[kk], bl_f, a, 0, 0, 0);
                a = __builtin_amdgcn_mfma_f32_16x16x32_bf16(qfh[kk], bh_f, a, 0, 0, 0);
            }
            #pragma unroll
            for (int r = 0; r < 4; ++r) {
                float p = __expf(a[r] * SCALE - rmax_r[r]);
                lsum[r] += p;
                u16 ph = bf16_rne(p);
                u16 pl = bf16_rne(p - __uint_as_float((unsigned)ph << 16));
                int q_l = sl * 4 + r;
                int key = n * 16 + fr;
                int off = q_l * 64 + (((key >> 3) ^ (q_l & 7)) * 8) + (key & 7);
                Ph[wave][off] = ph;
                Pl[wave][off] = pl;
            }
        }

        #pragma unroll
        for (int kk = 0; kk < 2; ++kk) {
            int aoff = fr * 64 + (((kk * 4 + sl) ^ (fr & 7)) * 8);
            short8v pah = *(const short8v*)&Ph[wave][aoff];
            short8v pal = *(const short8v*)&Pl[wave][aoff];
            #pragma unroll
            for (int n = 0; n < 4; ++n) {
                int d = n * 16 + fr;
                int voff = d * 64 + (((kk * 4 + sl) ^ (d & 7)) * 8);
                short8v vhf = *(const short8v*)&Vh[voff];
                short8v vlf = *(const short8v*)&Vl[voff];
                opv[n] = __builtin_amdgcn_mfma_f32_16x16x32_bf16(pal, vhf, opv[n], 0, 0, 0);
                opv[n] = __builtin_amdgcn_mfma_f32_16x16x32_bf16(pah, vlf, opv[n], 0, 0, 0);
                opv[n] = __builtin_amdgcn_mfma_f32_16x16x32_bf16(pah, vhf, opv[n], 0, 0, 0);
            }
        }
    }

    #pragma unroll
    for (int w = 1; w < 16; w <<= 1)
        #pragma unroll
        for (int r = 0; r < 4; ++r)
            lsum[r] += __shfl_xor(lsum[r], w, 64);

    #pragma unroll
    for (int r = 0; r < 4; ++r) {
        const float inv = 1.0f / lsum[r];
        float* orow = attn_out + ((size_t)b * N + qr_o[r]) * C + h * DK;
        #pragma unroll
        for (int n = 0; n < 4; ++n)
            orow[n * 16 + fr] = opv[n][r] * inv;
    }
}

// ---------------------------------------------------------------------------
extern "C" void kernel_launch(void* const* d_in, const int* in_sizes, int n_in,
                              void* d_out, int out_size, void* d_ws, size_t ws_size,
                              hipStream_t stream)
{
    const float* x    = (const float*)d_in[0];
    const float* Wqkv = (const float*)d_in[1];
    const float* bqkv = (const float*)d_in[2];
    const float* Wout = (const float*)d_in[3];
    const float* bout = (const float*)d_in[4];
    float* out = (float*)d_out;

    char* ws = (char*)d_ws;
    size_t off = 0;
    auto alloc = [&](size_t bytes) -> void* {
        void* p = ws + off;
        off += (bytes + 255) & ~(size_t)255;
        return p;
    };

    const size_t BHND = (size_t)B * H * N * DK;       // 4 Mi elems
    float* q        = (float*)alloc(BHND * 4);
    float* kbuf     = (float*)alloc(BHND * 4);
    float* vbuf     = (float*)alloc(BHND * 4);
    float* attn_out = (float*)alloc((size_t)B * N * C * 4);
    u16* cvAhi = (u16*)alloc((size_t)B * N * C * 2);  // x / q_hi / attn_out hi
    u16* cvAlo = (u16*)alloc((size_t)B * N * C * 2);
    u16* cvBhi = (u16*)alloc((size_t)3 * C * C * 2);
    u16* cvBlo = (u16*)alloc((size_t)3 * C * C * 2);
    u16* khi   = (u16*)alloc(BHND * 2);
    u16* klo   = (u16*)alloc(BHND * 2);
    u16* vthi  = (u16*)alloc(BHND * 2);
    u16* vtlo  = (u16*)alloc(BHND * 2);
    float* Mbuf     = (float*)alloc((size_t)B * H * N * 4);
    float* rmaxbuf  = (float*)alloc((size_t)B * H * N * 4);
    float* Mdot     = (float*)alloc((size_t)B * H * N * 4);
    int*   keep     = (int*)  alloc((size_t)B * H * N * 4);
    int*   kidx     = (int*)  alloc((size_t)B * H * NTOP * 4);
    float* vmeanbuf = (float*)alloc((size_t)B * H * DK * 4);
    float* kmeanbuf = (float*)alloc((size_t)B * H * DK * 4);
    float* partbuf  = (float*)alloc((size_t)B * H * CSEG * DK * 4);
    float* thrbuf   = (float*)alloc((size_t)B * H * 4);
    int*   cntbuf   = (int*)  alloc((size_t)B * H * 4);
    int*   bandbuf  = (int*)  alloc((size_t)B * H * BAND_CAP * 4);

    const int nX = B * N * C;        // 4M
    const int nW = 3 * C * C;        // 3M
    const int nWo = C * C;           // 1M

    // 1. convert x, Wqkv to bf16 hi/lo
    convert_hilo<<<nX / 1024, 256, 0, stream>>>(x, cvAhi, cvAlo, nX);
    convert_hilo<<<nW / 1024, 256, 0, stream>>>(Wqkv, cvBhi, cvBlo, nW);

    // 2. QKV projection (split-bf16 MFMA), scatter to q/k/v
    gemm_mfma<0><<<dim3(3 * C / 128, (B * N) / 128), 256, 0, stream>>>(
        cvAhi, cvAlo, cvBhi, cvBlo, bqkv, nullptr, q, kbuf, vbuf, C);

    // 3. convert q,k hi/lo; v transposed hi/lo
    u16* qhi = cvAhi; u16* qlo = cvAlo;
    convert_hilo<<<nX / 1024, 256, 0, stream>>>(q, qhi, qlo, nX);
    convert_hilo<<<nX / 1024, 256, 0, stream>>>(kbuf, khi, klo, nX);
    convert_hilo_T<<<dim3(N / 64, B * H), 256, 0, stream>>>(vbuf, vthi, vtlo);

    // 4. column means of v (output fill) and k (exact mean-score term)
    colsum_part<<<dim3(CSEG, B * H), 256, 0, stream>>>(vbuf, partbuf);
    colsum_final<<<B * H, 64, 0, stream>>>(partbuf, vmeanbuf);
    colsum_part<<<dim3(CSEG, B * H), 256, 0, stream>>>(kbuf, partbuf);
    colsum_final<<<B * H, 64, 0, stream>>>(partbuf, kmeanbuf);

    // 5. mean term per row: Mdot = q . kmean
    qdot_kernel<<<dim3(N / 256, B * H), 256, 0, stream>>>(q, kmeanbuf, Mdot);

    // 6. MFMA approximate row max -> M, rowmax
    row_stats_mfma<<<dim3(N / 128, B * H), 256, 0, stream>>>(
        qhi, qlo, khi, klo, Mdot, Mbuf, rmaxbuf);

    // 7. boundary refinement: threshold -> band -> fp64 exact M
    zero_cnt<<<1, 64, 0, stream>>>(cntbuf);
    topk_thr<<<dim3(N / 256, B * H), 256, 0, stream>>>(Mbuf, thrbuf);
    band_collect<<<dim3(N / 256, B * H), 256, 0, stream>>>(Mbuf, thrbuf, cntbuf, bandbuf);
    refine_kernel<<<dim3(32, B * H), 256, 0, stream>>>(q, kbuf, cntbuf, bandbuf, Mbuf);

    // 8. final top-512 keep flags + compacted indices
    topk_keep<<<dim3(N / 256, B * H), 256, 0, stream>>>(Mbuf, keep, kidx);

    // 9. fill non-kept rows; MFMA attention on kept rows
    fill_nonkept<<<dim3(N / 64, B * H), 256, 0, stream>>>(keep, vmeanbuf, attn_out);
    attn_mfma<<<256, 256, 0, stream>>>(
        qhi, qlo, khi, klo, vthi, vtlo, rmaxbuf, kidx, attn_out);

    // 10. Output projection (split-bf16 MFMA)
    convert_hilo<<<nX / 1024, 256, 0, stream>>>(attn_out, cvAhi, cvAlo, nX);
    convert_hilo<<<nWo / 1024, 256, 0, stream>>>(Wout, cvBhi, cvBlo, nWo);
    gemm_mfma<1><<<dim3(C / 128, (B * N) / 128), 256, 0, stream>>>(
        cvAhi, cvAlo, cvBhi, cvBlo, bout, out, nullptr, nullptr, nullptr, C);
}

// Round 8
// 457.659 us; speedup vs baseline: 6.0130x; 1.0410x over previous
//
#include <hip/hip_runtime.h>
#include <math.h>

typedef unsigned short u16;
typedef __attribute__((ext_vector_type(8))) short short8v;  // 8 bf16 operand frag
typedef __attribute__((ext_vector_type(4))) float f32x4;    // MFMA accumulator

constexpr int B  = 2;
constexpr int N  = 2048;
constexpr int C  = 1024;
constexpr int H  = 16;
constexpr int DK = 64;
constexpr int NTOP = 512;
constexpr float SCALE = 0.125f;  // 1/sqrt(64)
constexpr int   BAND_CAP = 1024;
constexpr float BAND_EPS = 2e-3f;   // covers 3-term split-bf16 M error (~1e-4)
constexpr int   CSEG = 16;          // column-sum segments per bh

// ---------------------------------------------------------------------------
// async global -> LDS, 16B per lane. LDS dest must be wave-uniform base
// (HW adds lane*16); global src is per-lane (pre-swizzled).
// ---------------------------------------------------------------------------
__device__ __forceinline__ void gload16(const u16* g, u16* l) {
    __builtin_amdgcn_global_load_lds(
        (const __attribute__((address_space(1))) unsigned int*)g,
        (__attribute__((address_space(3))) unsigned int*)l,
        16, 0, 0);
}

// ---------------------------------------------------------------------------
// fp32 -> bf16 hi/lo split (RNE): hi = bf16(x), lo = bf16(x - hi)
// ---------------------------------------------------------------------------
__device__ __forceinline__ u16 bf16_rne(float x) {
    unsigned u = __float_as_uint(x);
    unsigned r = u + 0x7fffu + ((u >> 16) & 1u);
    return (u16)(r >> 16);
}

__global__ __launch_bounds__(256) void convert_hilo(
    const float* __restrict__ src, u16* __restrict__ hi, u16* __restrict__ lo, int n)
{
    int i = (blockIdx.x * 256 + threadIdx.x) * 4;
    if (i >= n) return;
    float4 v = *(const float4*)&src[i];
    u16 h0 = bf16_rne(v.x), h1 = bf16_rne(v.y), h2 = bf16_rne(v.z), h3 = bf16_rne(v.w);
    float f0 = __uint_as_float((unsigned)h0 << 16);
    float f1 = __uint_as_float((unsigned)h1 << 16);
    float f2 = __uint_as_float((unsigned)h2 << 16);
    float f3 = __uint_as_float((unsigned)h3 << 16);
    ushort4 hh = make_ushort4(h0, h1, h2, h3);
    ushort4 ll = make_ushort4(bf16_rne(v.x - f0), bf16_rne(v.y - f1),
                              bf16_rne(v.z - f2), bf16_rne(v.w - f3));
    *(ushort4*)&hi[i] = hh;
    *(ushort4*)&lo[i] = ll;
}

// ---------------------------------------------------------------------------
// Split-bf16 MFMA GEMM: 128x128 tile, BK=32, 4 waves, global_load_lds staging.
// LDS layout: LDS[row][s] = global[row][s ^ ((row>>1)&3)]  (slot = 8 u16).
// MODE 0: scatter q/k/v fp32 + q/k hi/lo + v^T hi/lo.  MODE 1: plain out.
// ---------------------------------------------------------------------------
template <int MODE>
__global__ __launch_bounds__(256) void gemm_mfma(
    const u16* __restrict__ Ahi, const u16* __restrict__ Alo,
    const u16* __restrict__ Bhi, const u16* __restrict__ Blo,
    const float* __restrict__ bias, float* __restrict__ out,
    float* __restrict__ qb, float* __restrict__ kb, float* __restrict__ vb,
    u16* __restrict__ qhi, u16* __restrict__ qlo,
    u16* __restrict__ khi, u16* __restrict__ klo,
    u16* __restrict__ vth, u16* __restrict__ vtl,
    int K)
{
    __shared__ __align__(16) u16 Ah[128 * 32], Al[128 * 32];
    __shared__ __align__(16) u16 Bh[128 * 32], Bl[128 * 32];

    const int tid = threadIdx.x;
    const int m0 = blockIdx.y * 128;
    const int n0 = blockIdx.x * 128;
    const int lane = tid & 63;
    const int wave = tid >> 6;
    const int wr = wave >> 1, wc = wave & 1;
    const int fr = lane & 15, sl = lane >> 4;

    // per-wave staging assignment
    const u16* gsrc = (wave == 0) ? Ahi + (size_t)m0 * K
                    : (wave == 1) ? Alo + (size_t)m0 * K
                    : (wave == 2) ? Bhi + (size_t)n0 * K
                                  : Blo + (size_t)n0 * K;
    u16* lbase = (wave == 0) ? Ah : (wave == 1) ? Al : (wave == 2) ? Bh : Bl;

    f32x4 acc[4][4] = {};

    for (int k0 = 0; k0 < K; k0 += 32) {
        __syncthreads();
        #pragma unroll
        for (int i = 0; i < 8; ++i) {
            int c = i * 64 + lane;               // chunk = 16B = 8 u16
            int row = c >> 2, sp = c & 3;
            int gs = sp ^ ((row >> 1) & 3);
            gload16(gsrc + (size_t)row * K + k0 + gs * 8, lbase + i * 512);
        }
        __syncthreads();

        short8v afh[4], afl[4], bfh[4], bfl[4];
        #pragma unroll
        for (int m = 0; m < 4; ++m) {
            int row = wr * 64 + m * 16 + fr;
            int off = row * 32 + ((sl ^ ((row >> 1) & 3)) * 8);
            afh[m] = *(const short8v*)&Ah[off];
            afl[m] = *(const short8v*)&Al[off];
        }
        #pragma unroll
        for (int n = 0; n < 4; ++n) {
            int row = wc * 64 + n * 16 + fr;
            int off = row * 32 + ((sl ^ ((row >> 1) & 3)) * 8);
            bfh[n] = *(const short8v*)&Bh[off];
            bfl[n] = *(const short8v*)&Bl[off];
        }
        #pragma unroll
        for (int m = 0; m < 4; ++m)
            #pragma unroll
            for (int n = 0; n < 4; ++n) {
                acc[m][n] = __builtin_amdgcn_mfma_f32_16x16x32_bf16(afh[m], bfh[n], acc[m][n], 0, 0, 0);
                acc[m][n] = __builtin_amdgcn_mfma_f32_16x16x32_bf16(afh[m], bfl[n], acc[m][n], 0, 0, 0);
                acc[m][n] = __builtin_amdgcn_mfma_f32_16x16x32_bf16(afl[m], bfh[n], acc[m][n], 0, 0, 0);
            }
    }

    #pragma unroll
    for (int m = 0; m < 4; ++m)
        #pragma unroll
        for (int n = 0; n < 4; ++n) {
            const int gcol = n0 + wc * 64 + n * 16 + fr;
            const int grow0 = m0 + wr * 64 + m * 16 + sl * 4;
            float val[4];
            #pragma unroll
            for (int r = 0; r < 4; ++r) val[r] = acc[m][n][r] + bias[gcol];
            if (MODE == 1) {
                #pragma unroll
                for (int r = 0; r < 4; ++r)
                    out[(size_t)(grow0 + r) * C + gcol] = val[r];
            } else {
                const int t = gcol >> 10, h = (gcol >> 6) & 15, d = gcol & 63;
                const int bb = grow0 >> 11, nn0 = grow0 & (N - 1);
                const int bhv = bb * H + h;
                u16 hh[4], ll[4];
                #pragma unroll
                for (int r = 0; r < 4; ++r) {
                    hh[r] = bf16_rne(val[r]);
                    ll[r] = bf16_rne(val[r] - __uint_as_float((unsigned)hh[r] << 16));
                }
                if (t == 2) {
                    #pragma unroll
                    for (int r = 0; r < 4; ++r)
                        vb[((size_t)bhv * N + nn0 + r) * DK + d] = val[r];
                    size_t vta = ((size_t)bhv * DK + d) * N + nn0;
                    *(ushort4*)&vth[vta] = make_ushort4(hh[0], hh[1], hh[2], hh[3]);
                    *(ushort4*)&vtl[vta] = make_ushort4(ll[0], ll[1], ll[2], ll[3]);
                } else {
                    float* fdst = (t == 0) ? qb : kb;
                    u16* hdst  = (t == 0) ? qhi : khi;
                    u16* ldst  = (t == 0) ? qlo : klo;
                    #pragma unroll
                    for (int r = 0; r < 4; ++r) {
                        size_t qi = ((size_t)bhv * N + nn0 + r) * DK + d;
                        fdst[qi] = val[r];
                        hdst[qi] = hh[r];
                        ldst[qi] = ll[r];
                    }
                }
            }
        }
}

// ---------------------------------------------------------------------------
// Column sums, two deterministic passes.
// ---------------------------------------------------------------------------
__global__ __launch_bounds__(256) void colsum_part(
    const float* __restrict__ src, float* __restrict__ partial)
{
    const int bh = blockIdx.y, seg = blockIdx.x;
    const int d = threadIdx.x & 63;
    const int sub = threadIdx.x >> 6;
    const int k0 = seg * (N / CSEG);
    float s = 0.f;
    for (int kk = sub; kk < N / CSEG; kk += 4)
        s += src[((size_t)bh * N + k0 + kk) * DK + d];
    __shared__ float part[4][64];
    part[sub][d] = s;
    __syncthreads();
    if (threadIdx.x < 64)
        partial[((size_t)bh * CSEG + seg) * DK + d] =
            part[0][d] + part[1][d] + part[2][d] + part[3][d];
}

__global__ __launch_bounds__(64) void colsum_final(
    const float* __restrict__ partial, float* __restrict__ mean)
{
    const int bh = blockIdx.x, d = threadIdx.x;
    float s = 0.f;
    #pragma unroll
    for (int g = 0; g < CSEG; ++g) s += partial[((size_t)bh * CSEG + g) * DK + d];
    mean[bh * DK + d] = s / (float)N;
}

// ---------------------------------------------------------------------------
// Mdot[bh,row] = dot(q_row, kmean_bh)
// ---------------------------------------------------------------------------
__global__ __launch_bounds__(256) void qdot_kernel(
    const float* __restrict__ q, const float* __restrict__ kmean,
    float* __restrict__ Mdot)
{
    const int bh = blockIdx.y;
    const int row = blockIdx.x * 256 + threadIdx.x;
    __shared__ float km[DK];
    if (threadIdx.x < DK) km[threadIdx.x] = kmean[bh * DK + threadIdx.x];
    __syncthreads();
    const float* qr = &q[((size_t)bh * N + row) * DK];
    float s = 0.f;
    #pragma unroll
    for (int d4 = 0; d4 < DK; d4 += 4) {
        float4 v = *(const float4*)&qr[d4];
        s += v.x * km[d4] + v.y * km[d4 + 1] + v.z * km[d4 + 2] + v.w * km[d4 + 3];
    }
    Mdot[(size_t)bh * N + row] = s;
}

// ---------------------------------------------------------------------------
// MFMA row-max (3-term split-bf16; refinement band covers the error).
// K staged via global_load_lds: LDS[row][s] = global[row][s ^ (row&7)].
// ---------------------------------------------------------------------------
__global__ __launch_bounds__(256) void row_stats_mfma(
    const u16* __restrict__ qh_, const u16* __restrict__ ql_,
    const u16* __restrict__ kh_, const u16* __restrict__ kl_,
    const float* __restrict__ Mdot, float* __restrict__ Mout,
    float* __restrict__ rowmax)
{
    __shared__ __align__(16) u16 Kh[64 * 64];
    __shared__ __align__(16) u16 Kl[64 * 64];
    const int tid = threadIdx.x, lane = tid & 63, wave = tid >> 6;
    const int bh = blockIdx.y;
    const int q0 = blockIdx.x * 128 + wave * 32;
    const int fr = lane & 15, g = lane >> 4;

    const u16* gsrc = (wave & 2) ? kl_ : kh_;
    u16* lbase = (wave & 2) ? Kl : Kh;
    const int cb = (wave & 1) * 256;

    short8v qfh[2][2], qfl[2][2];
    #pragma unroll
    for (int m = 0; m < 2; ++m)
        #pragma unroll
        for (int kk = 0; kk < 2; ++kk) {
            size_t qa = ((size_t)bh * N + q0 + m * 16 + fr) * DK + kk * 32 + g * 8;
            qfh[m][kk] = *(const short8v*)&qh_[qa];
            qfl[m][kk] = *(const short8v*)&ql_[qa];
        }

    f32x4 mx[2];
    mx[0] = (f32x4){-1e30f, -1e30f, -1e30f, -1e30f};
    mx[1] = mx[0];

    for (int kt = 0; kt < N; kt += 64) {
        __syncthreads();
        #pragma unroll
        for (int i = 0; i < 4; ++i) {
            int c = cb + i * 64 + lane;          // chunk = 8 u16
            int row = c >> 3, sp = c & 7;
            int gs = sp ^ (row & 7);
            gload16(gsrc + ((size_t)bh * N + kt + row) * DK + gs * 8,
                    lbase + (size_t)(cb + i * 64) * 8);
        }
        __syncthreads();
        short8v bfh[4][2], bfl[4][2];
        #pragma unroll
        for (int n = 0; n < 4; ++n)
            #pragma unroll
            for (int kk = 0; kk < 2; ++kk) {
                int key = n * 16 + fr;
                int off = key * 64 + (((g + kk * 4) ^ (key & 7)) * 8);
                bfh[n][kk] = *(const short8v*)&Kh[off];
                bfl[n][kk] = *(const short8v*)&Kl[off];
            }
        #pragma unroll
        for (int m = 0; m < 2; ++m)
            #pragma unroll
            for (int n = 0; n < 4; ++n) {
                f32x4 a = {};
                #pragma unroll
                for (int kk = 0; kk < 2; ++kk) {
                    a = __builtin_amdgcn_mfma_f32_16x16x32_bf16(qfl[m][kk], bfh[n][kk], a, 0, 0, 0);
                    a = __builtin_amdgcn_mfma_f32_16x16x32_bf16(qfh[m][kk], bfl[n][kk], a, 0, 0, 0);
                    a = __builtin_amdgcn_mfma_f32_16x16x32_bf16(qfh[m][kk], bfh[n][kk], a, 0, 0, 0);
                }
                #pragma unroll
                for (int r = 0; r < 4; ++r) mx[m][r] = fmaxf(mx[m][r], a[r]);
            }
    }

    #pragma unroll
    for (int w = 1; w < 16; w <<= 1)
        #pragma unroll
        for (int m = 0; m < 2; ++m)
            #pragma unroll
            for (int r = 0; r < 4; ++r)
                mx[m][r] = fmaxf(mx[m][r], __shfl_xor(mx[m][r], w, 64));

    if (fr == 0) {
        #pragma unroll
        for (int m = 0; m < 2; ++m)
            #pragma unroll
            for (int r = 0; r < 4; ++r) {
                int row = q0 + m * 16 + g * 4 + r;
                size_t idx = (size_t)bh * N + row;
                float v = mx[m][r];
                rowmax[idx] = SCALE * v;
                Mout[idx]   = SCALE * (v - Mdot[idx]);
            }
    }
}

// ---------------------------------------------------------------------------
// Boundary refinement: threshold -> band -> fp64 exact M for band rows.
// ---------------------------------------------------------------------------
__global__ void zero_cnt(int* cnt) { if (threadIdx.x < B * H) cnt[threadIdx.x] = 0; }

__global__ __launch_bounds__(256) void topk_thr(
    const float* __restrict__ Mv, float* __restrict__ thr)
{
    const int bh = blockIdx.y;
    const int qi = blockIdx.x * 256 + threadIdx.x;
    __shared__ float Ms[N];
    for (int e = threadIdx.x; e < N; e += 256) Ms[e] = Mv[(size_t)bh * N + e];
    __syncthreads();
    const float mq = Ms[qi];
    int rank = 0;
    for (int j = 0; j < N; ++j) {
        float mj = Ms[j];
        rank += (mj > mq) || (mj == mq && j < qi);
    }
    if (rank == NTOP - 1) thr[bh] = mq;   // smallest kept (approx boundary)
}

__global__ __launch_bounds__(256) void band_collect(
    const float* __restrict__ Mv, const float* __restrict__ thr,
    int* __restrict__ cnt, int* __restrict__ band)
{
    const int bh = blockIdx.y;
    const int row = blockIdx.x * 256 + threadIdx.x;
    const float m = Mv[(size_t)bh * N + row];
    if (fabsf(m - thr[bh]) <= BAND_EPS) {
        int pos = atomicAdd(&cnt[bh], 1);
        if (pos < BAND_CAP) band[bh * BAND_CAP + pos] = row;
    }
}

// Block-per-candidate (strided): LDS-staged coalesced K, fp64 exact dot.
__global__ __launch_bounds__(256) void refine_kernel(
    const float* __restrict__ q, const float* __restrict__ k,
    const int* __restrict__ cnt, const int* __restrict__ band,
    float* __restrict__ Mv)
{
    constexpr int LS = 69;
    __shared__ float Ks[64 * LS];
    __shared__ float qs[DK];
    const int bh = blockIdx.y;
    const int tid = threadIdx.x;
    const int n = min(cnt[bh], BAND_CAP);
    for (int ci = blockIdx.x; ci < n; ci += 32) {
        const int row = band[bh * BAND_CAP + ci];
        __syncthreads();
        if (tid < DK) qs[tid] = q[((size_t)bh * N + row) * DK + tid];
        double mx = -1e30, sm = 0.0;
        for (int kt = 0; kt < N; kt += 64) {
            __syncthreads();
            #pragma unroll
            for (int p = 0; p < 4; ++p) {
                int idx = tid * 4 + p * 1024;
                int kr = idx >> 6, d = idx & 63;
                float4 x4 = *(const float4*)&k[((size_t)bh * N + kt + kr) * DK + d];
                Ks[kr * LS + d]     = x4.x;
                Ks[kr * LS + d + 1] = x4.y;
                Ks[kr * LS + d + 2] = x4.z;
                Ks[kr * LS + d + 3] = x4.w;
            }
            __syncthreads();
            if (tid < 64) {
                double s = 0.0;
                #pragma unroll
                for (int d = 0; d < DK; ++d)
                    s += (double)qs[d] * (double)Ks[tid * LS + d];
                mx = fmax(mx, s);
                sm += s;
            }
        }
        if (tid < 64) {
            #pragma unroll
            for (int w = 1; w < 64; w <<= 1) {
                mx = fmax(mx, __shfl_xor(mx, w, 64));
                sm += __shfl_xor(sm, w, 64);
            }
            if (tid == 0)
                Mv[(size_t)bh * N + row] = (float)((double)SCALE * (mx - sm / (double)N));
        }
    }
}

// ---------------------------------------------------------------------------
// Final top-k on refined M: keep flag + compacted index list.
// ---------------------------------------------------------------------------
__global__ __launch_bounds__(256) void topk_keep(
    const float* __restrict__ Mv, int* __restrict__ keep, int* __restrict__ kidx)
{
    const int bh = blockIdx.y;
    const int qi = blockIdx.x * 256 + threadIdx.x;
    __shared__ float Ms[N];
    for (int e = threadIdx.x; e < N; e += 256) Ms[e] = Mv[(size_t)bh * N + e];
    __syncthreads();
    const float mq = Ms[qi];
    int rank = 0;
    for (int j = 0; j < N; ++j) {
        float mj = Ms[j];
        rank += (mj > mq) || (mj == mq && j < qi);
    }
    keep[(size_t)bh * N + qi] = (rank < NTOP) ? 1 : 0;
    if (rank < NTOP) kidx[bh * NTOP + rank] = qi;
}

// ---------------------------------------------------------------------------
// Fill non-kept rows of attn_out with vmean. grid (N/64, B*H)
// ---------------------------------------------------------------------------
__global__ __launch_bounds__(256) void fill_nonkept(
    const int* __restrict__ keep, const float* __restrict__ vmean,
    float* __restrict__ attn_out)
{
    const int bh = blockIdx.y;
    const int b = bh >> 4, h = bh & 15;
    const int d = threadIdx.x & 63;
    const int rr = threadIdx.x >> 6;
    const float vm = vmean[bh * DK + d];
    #pragma unroll
    for (int i = 0; i < 16; ++i) {
        int row = blockIdx.x * 64 + i * 4 + rr;
        if (!keep[(size_t)bh * N + row])
            attn_out[((size_t)b * N + row) * C + h * DK + d] = vm;
    }
}

// ---------------------------------------------------------------------------
// MFMA attention on kept rows; K/V staged via global_load_lds.
// ---------------------------------------------------------------------------
__global__ __launch_bounds__(256) void attn_mfma(
    const u16* __restrict__ qh_, const u16* __restrict__ ql_,
    const u16* __restrict__ kh_, const u16* __restrict__ kl_,
    const u16* __restrict__ vth_, const u16* __restrict__ vtl_,
    const float* __restrict__ rowmax, const int* __restrict__ kidx,
    float* __restrict__ attn_out)
{
    __shared__ __align__(16) u16 Kh[64 * 64], Kl[64 * 64];
    __shared__ __align__(16) u16 Vh[64 * 64], Vl[64 * 64];
    __shared__ __align__(16) u16 Ph[4][16 * 64], Pl[4][16 * 64];

    const int tid = threadIdx.x, lane = tid & 63, wave = tid >> 6;
    const int wg = blockIdx.x;
    const int bh = ((wg >> 6) << 3) | (wg & 7);
    const int xblk = (wg >> 3) & 7;
    const int b = bh >> 4, h = bh & 15;
    const int q0 = xblk * 64 + wave * 16;
    const int fr = lane & 15, sl = lane >> 4;

    const bool isV = (wave >= 2);
    const u16* ksrc = (wave & 1) ? kl_ : kh_;
    const u16* vsrc = (wave & 1) ? vtl_ : vth_;
    u16* lbase = (wave == 0) ? Kh : (wave == 1) ? Kl : (wave == 2) ? Vh : Vl;
    const size_t kbase0 = (size_t)bh * N * DK;
    const size_t vbase0 = (size_t)bh * DK * N;

    const int* kix = kidx + bh * NTOP;
    const int qrow_f = kix[q0 + fr];
    int qr_o[4]; float rmax_r[4];
    #pragma unroll
    for (int r = 0; r < 4; ++r) {
        qr_o[r] = kix[q0 + sl * 4 + r];
        rmax_r[r] = rowmax[(size_t)bh * N + qr_o[r]];
    }

    short8v qfh[2], qfl[2];
    #pragma unroll
    for (int kk = 0; kk < 2; ++kk) {
        size_t qa = ((size_t)bh * N + qrow_f) * DK + kk * 32 + sl * 8;
        qfh[kk] = *(const short8v*)&qh_[qa];
        qfl[kk] = *(const short8v*)&ql_[qa];
    }

    f32x4 opv[4] = {};
    float lsum[4] = {};

    for (int kt = 0; kt < N; kt += 64) {
        __syncthreads();
        #pragma unroll
        for (int i = 0; i < 8; ++i) {
            int c = i * 64 + lane;               // chunk = 8 u16
            int row = c >> 3, sp = c & 7;
            int gs = sp ^ (row & 7);
            const u16* g = isV ? (vsrc + vbase0 + (size_t)row * N + kt + gs * 8)
                               : (ksrc + kbase0 + (size_t)(kt + row) * DK + gs * 8);
            gload16(g, lbase + (size_t)i * 512);
        }
        __syncthreads();

        #pragma unroll
        for (int n = 0; n < 4; ++n) {
            f32x4 a = {};
            #pragma unroll
            for (int kk = 0; kk < 2; ++kk) {
                int key = n * 16 + fr;
                int off = key * 64 + (((sl + kk * 4) ^ (key & 7)) * 8);
                short8v bh_f = *(const short8v*)&Kh[off];
                short8v bl_f = *(const short8v*)&Kl[off];
                a = __builtin_amdgcn_mfma_f32_16x16x32_bf16(qfl[kk], bh_f, a, 0, 0, 0);
                a = __builtin_amdgcn_mfma_f32_16x16x32_bf16(qfh[kk], bl_f, a, 0, 0, 0);
                a = __builtin_amdgcn_mfma_f32_16x16x32_bf16(qfh[kk], bh_f, a, 0, 0, 0);
            }
            #pragma unroll
            for (int r = 0; r < 4; ++r) {
                float p = __expf(a[r] * SCALE - rmax_r[r]);
                lsum[r] += p;
                u16 ph = bf16_rne(p);
                u16 pl = bf16_rne(p - __uint_as_float((unsigned)ph << 16));
                int q_l = sl * 4 + r;
                int key = n * 16 + fr;
                int off = q_l * 64 + (((key >> 3) ^ (q_l & 7)) * 8) + (key & 7);
                Ph[wave][off] = ph;
                Pl[wave][off] = pl;
            }
        }

        #pragma unroll
        for (int kk = 0; kk < 2; ++kk) {
            int aoff = fr * 64 + (((kk * 4 + sl) ^ (fr & 7)) * 8);
            short8v pah = *(const short8v*)&Ph[wave][aoff];
            short8v pal = *(const short8v*)&Pl[wave][aoff];
            #pragma unroll
            for (int n = 0; n < 4; ++n) {
                int d = n * 16 + fr;
                int voff = d * 64 + (((kk * 4 + sl) ^ (d & 7)) * 8);
                short8v vhf = *(const short8v*)&Vh[voff];
                short8v vlf = *(const short8v*)&Vl[voff];
                opv[n] = __builtin_amdgcn_mfma_f32_16x16x32_bf16(pal, vhf, opv[n], 0, 0, 0);
                opv[n] = __builtin_amdgcn_mfma_f32_16x16x32_bf16(pah, vlf, opv[n], 0, 0, 0);
                opv[n] = __builtin_amdgcn_mfma_f32_16x16x32_bf16(pah, vhf, opv[n], 0, 0, 0);
            }
        }
    }

    #pragma unroll
    for (int w = 1; w < 16; w <<= 1)
        #pragma unroll
        for (int r = 0; r < 4; ++r)
            lsum[r] += __shfl_xor(lsum[r], w, 64);

    #pragma unroll
    for (int r = 0; r < 4; ++r) {
        const float inv = 1.0f / lsum[r];
        float* orow = attn_out + ((size_t)b * N + qr_o[r]) * C + h * DK;
        #pragma unroll
        for (int n = 0; n < 4; ++n)
            orow[n * 16 + fr] = opv[n][r] * inv;
    }
}

// ---------------------------------------------------------------------------
extern "C" void kernel_launch(void* const* d_in, const int* in_sizes, int n_in,
                              void* d_out, int out_size, void* d_ws, size_t ws_size,
                              hipStream_t stream)
{
    const float* x    = (const float*)d_in[0];
    const float* Wqkv = (const float*)d_in[1];
    const float* bqkv = (const float*)d_in[2];
    const float* Wout = (const float*)d_in[3];
    const float* bout = (const float*)d_in[4];
    float* out = (float*)d_out;

    char* ws = (char*)d_ws;
    size_t off = 0;
    auto alloc = [&](size_t bytes) -> void* {
        void* p = ws + off;
        off += (bytes + 255) & ~(size_t)255;
        return p;
    };

    const size_t BHND = (size_t)B * H * N * DK;       // 4 Mi elems
    float* q        = (float*)alloc(BHND * 4);
    float* kbuf     = (float*)alloc(BHND * 4);
    float* vbuf     = (float*)alloc(BHND * 4);
    float* attn_out = (float*)alloc((size_t)B * N * C * 4);
    u16* cvAhi = (u16*)alloc((size_t)B * N * C * 2);  // x / attn_out hi
    u16* cvAlo = (u16*)alloc((size_t)B * N * C * 2);
    u16* cvBhi = (u16*)alloc((size_t)3 * C * C * 2);
    u16* cvBlo = (u16*)alloc((size_t)3 * C * C * 2);
    u16* qhi   = (u16*)alloc(BHND * 2);
    u16* qlo   = (u16*)alloc(BHND * 2);
    u16* khi   = (u16*)alloc(BHND * 2);
    u16* klo   = (u16*)alloc(BHND * 2);
    u16* vthi  = (u16*)alloc(BHND * 2);
    u16* vtlo  = (u16*)alloc(BHND * 2);
    float* Mbuf     = (float*)alloc((size_t)B * H * N * 4);
    float* rmaxbuf  = (float*)alloc((size_t)B * H * N * 4);
    float* Mdot     = (float*)alloc((size_t)B * H * N * 4);
    int*   keep     = (int*)  alloc((size_t)B * H * N * 4);
    int*   kidx     = (int*)  alloc((size_t)B * H * NTOP * 4);
    float* vmeanbuf = (float*)alloc((size_t)B * H * DK * 4);
    float* kmeanbuf = (float*)alloc((size_t)B * H * DK * 4);
    float* partbuf  = (float*)alloc((size_t)B * H * CSEG * DK * 4);
    float* thrbuf   = (float*)alloc((size_t)B * H * 4);
    int*   cntbuf   = (int*)  alloc((size_t)B * H * 4);
    int*   bandbuf  = (int*)  alloc((size_t)B * H * BAND_CAP * 4);

    const int nX = B * N * C;        // 4M
    const int nW = 3 * C * C;        // 3M
    const int nWo = C * C;           // 1M

    // 1. convert x, Wqkv to bf16 hi/lo
    convert_hilo<<<nX / 1024, 256, 0, stream>>>(x, cvAhi, cvAlo, nX);
    convert_hilo<<<nW / 1024, 256, 0, stream>>>(Wqkv, cvBhi, cvBlo, nW);

    // 2. QKV projection: fp32 q/k/v + fused q/k hi/lo + v^T hi/lo
    gemm_mfma<0><<<dim3(3 * C / 128, (B * N) / 128), 256, 0, stream>>>(
        cvAhi, cvAlo, cvBhi, cvBlo, bqkv, nullptr, q, kbuf, vbuf,
        qhi, qlo, khi, klo, vthi, vtlo, C);

    // 3. column means of v (output fill) and k (exact mean-score term)
    colsum_part<<<dim3(CSEG, B * H), 256, 0, stream>>>(vbuf, partbuf);
    colsum_final<<<B * H, 64, 0, stream>>>(partbuf, vmeanbuf);
    colsum_part<<<dim3(CSEG, B * H), 256, 0, stream>>>(kbuf, partbuf);
    colsum_final<<<B * H, 64, 0, stream>>>(partbuf, kmeanbuf);

    // 4. mean term per row: Mdot = q . kmean
    qdot_kernel<<<dim3(N / 256, B * H), 256, 0, stream>>>(q, kmeanbuf, Mdot);

    // 5. MFMA approximate row max -> M, rowmax
    row_stats_mfma<<<dim3(N / 128, B * H), 256, 0, stream>>>(
        qhi, qlo, khi, klo, Mdot, Mbuf, rmaxbuf);

    // 6. boundary refinement: threshold -> band -> fp64 exact M
    zero_cnt<<<1, 64, 0, stream>>>(cntbuf);
    topk_thr<<<dim3(N / 256, B * H), 256, 0, stream>>>(Mbuf, thrbuf);
    band_collect<<<dim3(N / 256, B * H), 256, 0, stream>>>(Mbuf, thrbuf, cntbuf, bandbuf);
    refine_kernel<<<dim3(32, B * H), 256, 0, stream>>>(q, kbuf, cntbuf, bandbuf, Mbuf);

    // 7. final top-512 keep flags + compacted indices
    topk_keep<<<dim3(N / 256, B * H), 256, 0, stream>>>(Mbuf, keep, kidx);

    // 8. fill non-kept rows; MFMA attention on kept rows
    fill_nonkept<<<dim3(N / 64, B * H), 256, 0, stream>>>(keep, vmeanbuf, attn_out);
    attn_mfma<<<256, 256, 0, stream>>>(
        qhi, qlo, khi, klo, vthi, vtlo, rmaxbuf, kidx, attn_out);

    // 9. Output projection (split-bf16 MFMA)
    convert_hilo<<<nX / 1024, 256, 0, stream>>>(attn_out, cvAhi, cvAlo, nX);
    convert_hilo<<<nWo / 1024, 256, 0, stream>>>(Wout, cvBhi, cvBlo, nWo);
    gemm_mfma<1><<<dim3(C / 128, (B * N) / 128), 256, 0, stream>>>(
        cvAhi, cvAlo, cvBhi, cvBlo, bout, out, nullptr, nullptr, nullptr,
        nullptr, nullptr, nullptr, nullptr, nullptr, nullptr, C);
}

// Round 9
// 417.270 us; speedup vs baseline: 6.5950x; 1.0968x over previous
//
#include <hip/hip_runtime.h>
#include <math.h>

typedef unsigned short u16;
typedef __attribute__((ext_vector_type(8))) short short8v;  // 8 bf16 operand frag
typedef __attribute__((ext_vector_type(4))) float f32x4;    // MFMA accumulator

constexpr int B  = 2;
constexpr int N  = 2048;
constexpr int C  = 1024;
constexpr int H  = 16;
constexpr int DK = 64;
constexpr int NTOP = 512;
constexpr float SCALE = 0.125f;  // 1/sqrt(64)
constexpr int   BAND_CAP = 1024;
constexpr float BAND_EPS = 2e-3f;   // covers 3-term split-bf16 M error (~1e-4)
constexpr int   CSEG = 16;          // column-sum segments per bh

// ---------------------------------------------------------------------------
// async global -> LDS, 16B per lane. LDS dest is wave-uniform base (+lane*16);
// global src is per-lane (pre-swizzled).   (verified r8)
// ---------------------------------------------------------------------------
__device__ __forceinline__ void gload16(const u16* g, u16* l) {
    __builtin_amdgcn_global_load_lds(
        (const __attribute__((address_space(1))) unsigned int*)g,
        (__attribute__((address_space(3))) unsigned int*)l,
        16, 0, 0);
}

// ---------------------------------------------------------------------------
// fp32 -> bf16 hi/lo split (RNE): hi = bf16(x), lo = bf16(x - hi)
// ---------------------------------------------------------------------------
__device__ __forceinline__ u16 bf16_rne(float x) {
    unsigned u = __float_as_uint(x);
    unsigned r = u + 0x7fffu + ((u >> 16) & 1u);
    return (u16)(r >> 16);
}

__global__ __launch_bounds__(256) void convert_hilo(
    const float* __restrict__ src, u16* __restrict__ hi, u16* __restrict__ lo, int n)
{
    int i = (blockIdx.x * 256 + threadIdx.x) * 4;
    if (i >= n) return;
    float4 v = *(const float4*)&src[i];
    u16 h0 = bf16_rne(v.x), h1 = bf16_rne(v.y), h2 = bf16_rne(v.z), h3 = bf16_rne(v.w);
    float f0 = __uint_as_float((unsigned)h0 << 16);
    float f1 = __uint_as_float((unsigned)h1 << 16);
    float f2 = __uint_as_float((unsigned)h2 << 16);
    float f3 = __uint_as_float((unsigned)h3 << 16);
    *(ushort4*)&hi[i] = make_ushort4(h0, h1, h2, h3);
    *(ushort4*)&lo[i] = make_ushort4(bf16_rne(v.x - f0), bf16_rne(v.y - f1),
                                     bf16_rne(v.z - f2), bf16_rne(v.w - f3));
}

// ---------------------------------------------------------------------------
// Transposed convert: v (bh, key, d) fp32 -> vt hi/lo (bh, d, key) bf16. (r6)
// ---------------------------------------------------------------------------
__global__ __launch_bounds__(256) void convert_hilo_T(
    const float* __restrict__ v, u16* __restrict__ th, u16* __restrict__ tl)
{
    constexpr int LS = 68;
    __shared__ u16 Sh[64 * LS], Sl[64 * LS];
    const int bh = blockIdx.y;
    const int kt = blockIdx.x * 64;
    const int tid = threadIdx.x;
    #pragma unroll
    for (int p = 0; p < 4; ++p) {
        int idx = tid * 4 + p * 1024;
        int key = idx >> 6, d = idx & 63;
        float4 x4 = *(const float4*)&v[((size_t)bh * N + kt + key) * DK + d];
        float xs[4] = {x4.x, x4.y, x4.z, x4.w};
        ushort4 hh, ll;
        u16* hp = (u16*)&hh; u16* lp = (u16*)&ll;
        #pragma unroll
        for (int j = 0; j < 4; ++j) {
            u16 h = bf16_rne(xs[j]);
            hp[j] = h;
            lp[j] = bf16_rne(xs[j] - __uint_as_float((unsigned)h << 16));
        }
        *(ushort4*)&Sh[key * LS + d] = hh;
        *(ushort4*)&Sl[key * LS + d] = ll;
    }
    __syncthreads();
    const int d = tid >> 2, seg = tid & 3;
    u16 bufh[16], bufl[16];
    #pragma unroll
    for (int i = 0; i < 16; ++i) {
        bufh[i] = Sh[(seg * 16 + i) * LS + d];
        bufl[i] = Sl[(seg * 16 + i) * LS + d];
    }
    size_t oa = ((size_t)bh * DK + d) * N + kt + seg * 16;
    *(uint4*)&th[oa] = ((uint4*)bufh)[0];
    *(uint4*)&th[oa + 8] = ((uint4*)bufh)[1];
    *(uint4*)&tl[oa] = ((uint4*)bufl)[0];
    *(uint4*)&tl[oa + 8] = ((uint4*)bufl)[1];
}

// ---------------------------------------------------------------------------
// Split-bf16 MFMA GEMM: 128x128 tile, BK=32, 4 waves, global_load_lds staging
// (r8-verified). Epilogue: r7 form (fp32 scatter only).
// MODE 0: scatter q/k/v (B*H,N,DK).  MODE 1: plain (B*N, C).
// ---------------------------------------------------------------------------
template <int MODE>
__global__ __launch_bounds__(256) void gemm_mfma(
    const u16* __restrict__ Ahi, const u16* __restrict__ Alo,
    const u16* __restrict__ Bhi, const u16* __restrict__ Blo,
    const float* __restrict__ bias, float* __restrict__ out,
    float* __restrict__ qb, float* __restrict__ kb, float* __restrict__ vb,
    int K)
{
    __shared__ __align__(16) u16 Ah[128 * 32], Al[128 * 32];
    __shared__ __align__(16) u16 Bh[128 * 32], Bl[128 * 32];

    const int tid = threadIdx.x;
    const int m0 = blockIdx.y * 128;
    const int n0 = blockIdx.x * 128;
    const int lane = tid & 63;
    const int wave = tid >> 6;
    const int wr = wave >> 1, wc = wave & 1;
    const int fr = lane & 15, sl = lane >> 4;

    const u16* gsrc = (wave == 0) ? Ahi + (size_t)m0 * K
                    : (wave == 1) ? Alo + (size_t)m0 * K
                    : (wave == 2) ? Bhi + (size_t)n0 * K
                                  : Blo + (size_t)n0 * K;
    u16* lbase = (wave == 0) ? Ah : (wave == 1) ? Al : (wave == 2) ? Bh : Bl;

    f32x4 acc[4][4] = {};

    for (int k0 = 0; k0 < K; k0 += 32) {
        __syncthreads();
        #pragma unroll
        for (int i = 0; i < 8; ++i) {
            int c = i * 64 + lane;               // chunk = 16B = 8 u16
            int row = c >> 2, sp = c & 3;
            int gs = sp ^ ((row >> 1) & 3);
            gload16(gsrc + (size_t)row * K + k0 + gs * 8, lbase + i * 512);
        }
        __syncthreads();

        short8v afh[4], afl[4], bfh[4], bfl[4];
        #pragma unroll
        for (int m = 0; m < 4; ++m) {
            int row = wr * 64 + m * 16 + fr;
            int off = row * 32 + ((sl ^ ((row >> 1) & 3)) * 8);
            afh[m] = *(const short8v*)&Ah[off];
            afl[m] = *(const short8v*)&Al[off];
        }
        #pragma unroll
        for (int n = 0; n < 4; ++n) {
            int row = wc * 64 + n * 16 + fr;
            int off = row * 32 + ((sl ^ ((row >> 1) & 3)) * 8);
            bfh[n] = *(const short8v*)&Bh[off];
            bfl[n] = *(const short8v*)&Bl[off];
        }
        #pragma unroll
        for (int m = 0; m < 4; ++m)
            #pragma unroll
            for (int n = 0; n < 4; ++n) {
                acc[m][n] = __builtin_amdgcn_mfma_f32_16x16x32_bf16(afh[m], bfh[n], acc[m][n], 0, 0, 0);
                acc[m][n] = __builtin_amdgcn_mfma_f32_16x16x32_bf16(afh[m], bfl[n], acc[m][n], 0, 0, 0);
                acc[m][n] = __builtin_amdgcn_mfma_f32_16x16x32_bf16(afl[m], bfh[n], acc[m][n], 0, 0, 0);
            }
    }

    #pragma unroll
    for (int m = 0; m < 4; ++m)
        #pragma unroll
        for (int n = 0; n < 4; ++n)
            #pragma unroll
            for (int r = 0; r < 4; ++r) {
                int grow = m0 + wr * 64 + m * 16 + sl * 4 + r;
                int gcol = n0 + wc * 64 + n * 16 + fr;
                float val = acc[m][n][r] + bias[gcol];
                if (MODE == 0) {
                    int t = gcol >> 10, h = (gcol >> 6) & 15, d = gcol & 63;
                    int bb = grow >> 11, nn = grow & (N - 1);
                    float* dst = (t == 0) ? qb : (t == 1) ? kb : vb;
                    dst[(((size_t)bb * H + h) * N + nn) * DK + d] = val;
                } else {
                    out[(size_t)grow * C + gcol] = val;
                }
            }
}

// ---------------------------------------------------------------------------
// Column sums, two deterministic passes.
// ---------------------------------------------------------------------------
__global__ __launch_bounds__(256) void colsum_part(
    const float* __restrict__ src, float* __restrict__ partial)
{
    const int bh = blockIdx.y, seg = blockIdx.x;
    const int d = threadIdx.x & 63;
    const int sub = threadIdx.x >> 6;
    const int k0 = seg * (N / CSEG);
    float s = 0.f;
    for (int kk = sub; kk < N / CSEG; kk += 4)
        s += src[((size_t)bh * N + k0 + kk) * DK + d];
    __shared__ float part[4][64];
    part[sub][d] = s;
    __syncthreads();
    if (threadIdx.x < 64)
        partial[((size_t)bh * CSEG + seg) * DK + d] =
            part[0][d] + part[1][d] + part[2][d] + part[3][d];
}

__global__ __launch_bounds__(64) void colsum_final(
    const float* __restrict__ partial, float* __restrict__ mean)
{
    const int bh = blockIdx.x, d = threadIdx.x;
    float s = 0.f;
    #pragma unroll
    for (int g = 0; g < CSEG; ++g) s += partial[((size_t)bh * CSEG + g) * DK + d];
    mean[bh * DK + d] = s / (float)N;
}

// ---------------------------------------------------------------------------
// Mdot[bh,row] = dot(q_row, kmean_bh)
// ---------------------------------------------------------------------------
__global__ __launch_bounds__(256) void qdot_kernel(
    const float* __restrict__ q, const float* __restrict__ kmean,
    float* __restrict__ Mdot)
{
    const int bh = blockIdx.y;
    const int row = blockIdx.x * 256 + threadIdx.x;
    __shared__ float km[DK];
    if (threadIdx.x < DK) km[threadIdx.x] = kmean[bh * DK + threadIdx.x];
    __syncthreads();
    const float* qr = &q[((size_t)bh * N + row) * DK];
    float s = 0.f;
    #pragma unroll
    for (int d4 = 0; d4 < DK; d4 += 4) {
        float4 v = *(const float4*)&qr[d4];
        s += v.x * km[d4] + v.y * km[d4 + 1] + v.z * km[d4 + 2] + v.w * km[d4 + 3];
    }
    Mdot[(size_t)bh * N + row] = s;
}

// ---------------------------------------------------------------------------
// MFMA row-max (3-term split-bf16), gload staging (r8-verified).
// ---------------------------------------------------------------------------
__global__ __launch_bounds__(256) void row_stats_mfma(
    const u16* __restrict__ qh_, const u16* __restrict__ ql_,
    const u16* __restrict__ kh_, const u16* __restrict__ kl_,
    const float* __restrict__ Mdot, float* __restrict__ Mout,
    float* __restrict__ rowmax)
{
    __shared__ __align__(16) u16 Kh[64 * 64];
    __shared__ __align__(16) u16 Kl[64 * 64];
    const int tid = threadIdx.x, lane = tid & 63, wave = tid >> 6;
    const int bh = blockIdx.y;
    const int q0 = blockIdx.x * 128 + wave * 32;
    const int fr = lane & 15, g = lane >> 4;

    const u16* gsrc = (wave & 2) ? kl_ : kh_;
    u16* lbase = (wave & 2) ? Kl : Kh;
    const int cb = (wave & 1) * 256;

    short8v qfh[2][2], qfl[2][2];
    #pragma unroll
    for (int m = 0; m < 2; ++m)
        #pragma unroll
        for (int kk = 0; kk < 2; ++kk) {
            size_t qa = ((size_t)bh * N + q0 + m * 16 + fr) * DK + kk * 32 + g * 8;
            qfh[m][kk] = *(const short8v*)&qh_[qa];
            qfl[m][kk] = *(const short8v*)&ql_[qa];
        }

    f32x4 mx[2];
    mx[0] = (f32x4){-1e30f, -1e30f, -1e30f, -1e30f};
    mx[1] = mx[0];

    for (int kt = 0; kt < N; kt += 64) {
        __syncthreads();
        #pragma unroll
        for (int i = 0; i < 4; ++i) {
            int c = cb + i * 64 + lane;
            int row = c >> 3, sp = c & 7;
            int gs = sp ^ (row & 7);
            gload16(gsrc + ((size_t)bh * N + kt + row) * DK + gs * 8,
                    lbase + (size_t)(cb + i * 64) * 8);
        }
        __syncthreads();
        short8v bfh[4][2], bfl[4][2];
        #pragma unroll
        for (int n = 0; n < 4; ++n)
            #pragma unroll
            for (int kk = 0; kk < 2; ++kk) {
                int key = n * 16 + fr;
                int off = key * 64 + (((g + kk * 4) ^ (key & 7)) * 8);
                bfh[n][kk] = *(const short8v*)&Kh[off];
                bfl[n][kk] = *(const short8v*)&Kl[off];
            }
        #pragma unroll
        for (int m = 0; m < 2; ++m)
            #pragma unroll
            for (int n = 0; n < 4; ++n) {
                f32x4 a = {};
                #pragma unroll
                for (int kk = 0; kk < 2; ++kk) {
                    a = __builtin_amdgcn_mfma_f32_16x16x32_bf16(qfl[m][kk], bfh[n][kk], a, 0, 0, 0);
                    a = __builtin_amdgcn_mfma_f32_16x16x32_bf16(qfh[m][kk], bfl[n][kk], a, 0, 0, 0);
                    a = __builtin_amdgcn_mfma_f32_16x16x32_bf16(qfh[m][kk], bfh[n][kk], a, 0, 0, 0);
                }
                #pragma unroll
                for (int r = 0; r < 4; ++r) mx[m][r] = fmaxf(mx[m][r], a[r]);
            }
    }

    #pragma unroll
    for (int w = 1; w < 16; w <<= 1)
        #pragma unroll
        for (int m = 0; m < 2; ++m)
            #pragma unroll
            for (int r = 0; r < 4; ++r)
                mx[m][r] = fmaxf(mx[m][r], __shfl_xor(mx[m][r], w, 64));

    if (fr == 0) {
        #pragma unroll
        for (int m = 0; m < 2; ++m)
            #pragma unroll
            for (int r = 0; r < 4; ++r) {
                int row = q0 + m * 16 + g * 4 + r;
                size_t idx = (size_t)bh * N + row;
                float v = mx[m][r];
                rowmax[idx] = SCALE * v;
                Mout[idx]   = SCALE * (v - Mdot[idx]);
            }
    }
}

// ---------------------------------------------------------------------------
// Selection: thr (N^2 rank, once) -> classify (keep for non-band, band list)
// -> fp64 refine (band only) -> band ranks + kidx compaction.
// ---------------------------------------------------------------------------
__global__ void zero_cnt(int* cnt) { if (threadIdx.x < B * H) cnt[threadIdx.x] = 0; }

__global__ __launch_bounds__(256) void topk_thr(
    const float* __restrict__ Mv, float* __restrict__ thr)
{
    const int bh = blockIdx.y;
    const int qi = blockIdx.x * 256 + threadIdx.x;
    __shared__ float Ms[N];
    for (int e = threadIdx.x; e < N; e += 256) Ms[e] = Mv[(size_t)bh * N + e];
    __syncthreads();
    const float mq = Ms[qi];
    int rank = 0;
    for (int j = 0; j < N; ++j) {
        float mj = Ms[j];
        rank += (mj > mq) || (mj == mq && j < qi);
    }
    if (rank == NTOP - 1) thr[bh] = mq;   // smallest kept (approx boundary)
}

// non-band rows: keep decided here (provably exact given err << BAND_EPS).
// band rows: keep=0 placeholder, listed for refinement.
__global__ __launch_bounds__(256) void band_classify(
    const float* __restrict__ Mv, const float* __restrict__ thr,
    int* __restrict__ cnt, int* __restrict__ band, int* __restrict__ keep)
{
    const int bh = blockIdx.y;
    const int row = blockIdx.x * 256 + threadIdx.x;
    const float m = Mv[(size_t)bh * N + row];
    const float t = thr[bh];
    int kp;
    if (fabsf(m - t) <= BAND_EPS) {
        int pos = atomicAdd(&cnt[bh], 1);
        if (pos < BAND_CAP) band[bh * BAND_CAP + pos] = row;
        kp = 0;
    } else {
        kp = (m > t) ? 1 : 0;
    }
    keep[(size_t)bh * N + row] = kp;
}

// Block-per-candidate (strided): LDS-staged coalesced K, fp64 exact dot.
__global__ __launch_bounds__(256) void refine_kernel(
    const float* __restrict__ q, const float* __restrict__ k,
    const int* __restrict__ cnt, const int* __restrict__ band,
    float* __restrict__ Mv)
{
    constexpr int LS = 69;
    __shared__ float Ks[64 * LS];
    __shared__ float qs[DK];
    const int bh = blockIdx.y;
    const int tid = threadIdx.x;
    const int n = min(cnt[bh], BAND_CAP);
    for (int ci = blockIdx.x; ci < n; ci += 32) {
        const int row = band[bh * BAND_CAP + ci];
        __syncthreads();
        if (tid < DK) qs[tid] = q[((size_t)bh * N + row) * DK + tid];
        double mx = -1e30, sm = 0.0;
        for (int kt = 0; kt < N; kt += 64) {
            __syncthreads();
            #pragma unroll
            for (int p = 0; p < 4; ++p) {
                int idx = tid * 4 + p * 1024;
                int kr = idx >> 6, d = idx & 63;
                float4 x4 = *(const float4*)&k[((size_t)bh * N + kt + kr) * DK + d];
                Ks[kr * LS + d]     = x4.x;
                Ks[kr * LS + d + 1] = x4.y;
                Ks[kr * LS + d + 2] = x4.z;
                Ks[kr * LS + d + 3] = x4.w;
            }
            __syncthreads();
            if (tid < 64) {
                double s = 0.0;
                #pragma unroll
                for (int d = 0; d < DK; ++d)
                    s += (double)qs[d] * (double)Ks[tid * LS + d];
                mx = fmax(mx, s);
                sm += s;
            }
        }
        if (tid < 64) {
            #pragma unroll
            for (int w = 1; w < 64; w <<= 1) {
                mx = fmax(mx, __shfl_xor(mx, w, 64));
                sm += __shfl_xor(sm, w, 64);
            }
            if (tid == 0)
                Mv[(size_t)bh * N + row] = (float)((double)SCALE * (mx - sm / (double)N));
        }
    }
}

// band ranks (vs refined M) + final keep + deterministic kidx compaction.
// one block per bh.
__global__ __launch_bounds__(256) void band_finalize(
    const float* __restrict__ Mv, const int* __restrict__ cnt,
    const int* __restrict__ band, int* __restrict__ keep,
    int* __restrict__ kidx)
{
    __shared__ unsigned char kL[N];
    __shared__ int   bRow[BAND_CAP];
    __shared__ float bM[BAND_CAP];
    __shared__ int aW[4];
    __shared__ int scan[256];

    const int bh = blockIdx.x;
    const int tid = threadIdx.x;
    const int lane = tid & 63, wid = tid >> 6;
    const int nb = min(cnt[bh], BAND_CAP);

    // load keep -> LDS, count above-band kept rows
    int above = 0;
    #pragma unroll
    for (int w = 0; w < 8; ++w) {
        int row = w * 256 + tid;
        int kp = keep[(size_t)bh * N + row];
        kL[row] = (unsigned char)kp;
        above += kp;
    }
    #pragma unroll
    for (int w = 1; w < 64; w <<= 1) above += __shfl_xor(above, w, 64);
    if (lane == 0) aW[wid] = above;
    // load band rows
    for (int i = tid; i < nb; i += 256) {
        int r = band[bh * BAND_CAP + i];
        bRow[i] = r;
        bM[i] = Mv[(size_t)bh * N + r];
    }
    __syncthreads();
    const int nAbove = aW[0] + aW[1] + aW[2] + aW[3];

    // band ranks (tie: lower row index first == lax.top_k)
    for (int i = tid; i < nb; i += 256) {
        const float mi = bM[i];
        const int ri = bRow[i];
        int rank = nAbove;
        for (int j = 0; j < nb; ++j) {
            float mj = bM[j];
            rank += (mj > mi) || (mj == mi && bRow[j] < ri);
        }
        int kp = (rank < NTOP) ? 1 : 0;
        kL[ri] = (unsigned char)kp;
        keep[(size_t)bh * N + ri] = kp;
    }
    __syncthreads();

    // compaction: thread owns 8 consecutive rows; block-wide exclusive scan
    int cntL = 0;
    #pragma unroll
    for (int r = 0; r < 8; ++r) cntL += kL[tid * 8 + r];
    scan[tid] = cntL;
    __syncthreads();
    for (int s = 1; s < 256; s <<= 1) {
        int v = (tid >= s) ? scan[tid - s] : 0;
        __syncthreads();
        scan[tid] += v;
        __syncthreads();
    }
    int pos = scan[tid] - cntL;  // exclusive prefix
    #pragma unroll
    for (int r = 0; r < 8; ++r) {
        int row = tid * 8 + r;
        if (kL[row]) kidx[bh * NTOP + pos++] = row;
    }
}

// ---------------------------------------------------------------------------
// Fill non-kept rows of attn_out with vmean. grid (N/64, B*H)
// ---------------------------------------------------------------------------
__global__ __launch_bounds__(256) void fill_nonkept(
    const int* __restrict__ keep, const float* __restrict__ vmean,
    float* __restrict__ attn_out)
{
    const int bh = blockIdx.y;
    const int b = bh >> 4, h = bh & 15;
    const int d = threadIdx.x & 63;
    const int rr = threadIdx.x >> 6;
    const float vm = vmean[bh * DK + d];
    #pragma unroll
    for (int i = 0; i < 16; ++i) {
        int row = blockIdx.x * 64 + i * 4 + rr;
        if (!keep[(size_t)bh * N + row])
            attn_out[((size_t)b * N + row) * C + h * DK + d] = vm;
    }
}

// ---------------------------------------------------------------------------
// MFMA attention on kept rows; K/V staged via global_load_lds. (r8-verified)
// ---------------------------------------------------------------------------
__global__ __launch_bounds__(256) void attn_mfma(
    const u16* __restrict__ qh_, const u16* __restrict__ ql_,
    const u16* __restrict__ kh_, const u16* __restrict__ kl_,
    const u16* __restrict__ vth_, const u16* __restrict__ vtl_,
    const float* __restrict__ rowmax, const int* __restrict__ kidx,
    float* __restrict__ attn_out)
{
    __shared__ __align__(16) u16 Kh[64 * 64], Kl[64 * 64];
    __shared__ __align__(16) u16 Vh[64 * 64], Vl[64 * 64];
    __shared__ __align__(16) u16 Ph[4][16 * 64], Pl[4][16 * 64];

    const int tid = threadIdx.x, lane = tid & 63, wave = tid >> 6;
    const int wg = blockIdx.x;
    const int bh = ((wg >> 6) << 3) | (wg & 7);
    const int xblk = (wg >> 3) & 7;
    const int b = bh >> 4, h = bh & 15;
    const int q0 = xblk * 64 + wave * 16;
    const int fr = lane & 15, sl = lane >> 4;

    const bool isV = (wave >= 2);
    const u16* ksrc = (wave & 1) ? kl_ : kh_;
    const u16* vsrc = (wave & 1) ? vtl_ : vth_;
    u16* lbase = (wave == 0) ? Kh : (wave == 1) ? Kl : (wave == 2) ? Vh : Vl;
    const size_t kbase0 = (size_t)bh * N * DK;
    const size_t vbase0 = (size_t)bh * DK * N;

    const int* kix = kidx + bh * NTOP;
    const int qrow_f = kix[q0 + fr];
    int qr_o[4]; float rmax_r[4];
    #pragma unroll
    for (int r = 0; r < 4; ++r) {
        qr_o[r] = kix[q0 + sl * 4 + r];
        rmax_r[r] = rowmax[(size_t)bh * N + qr_o[r]];
    }

    short8v qfh[2], qfl[2];
    #pragma unroll
    for (int kk = 0; kk < 2; ++kk) {
        size_t qa = ((size_t)bh * N + qrow_f) * DK + kk * 32 + sl * 8;
        qfh[kk] = *(const short8v*)&qh_[qa];
        qfl[kk] = *(const short8v*)&ql_[qa];
    }

    f32x4 opv[4] = {};
    float lsum[4] = {};

    for (int kt = 0; kt < N; kt += 64) {
        __syncthreads();
        #pragma unroll
        for (int i = 0; i < 8; ++i) {
            int c = i * 64 + lane;
            int row = c >> 3, sp = c & 7;
            int gs = sp ^ (row & 7);
            const u16* g = isV ? (vsrc + vbase0 + (size_t)row * N + kt + gs * 8)
                               : (ksrc + kbase0 + (size_t)(kt + row) * DK + gs * 8);
            gload16(g, lbase + (size_t)i * 512);
        }
        __syncthreads();

        #pragma unroll
        for (int n = 0; n < 4; ++n) {
            f32x4 a = {};
            #pragma unroll
            for (int kk = 0; kk < 2; ++kk) {
                int key = n * 16 + fr;
                int off = key * 64 + (((sl + kk * 4) ^ (key & 7)) * 8);
                short8v bh_f = *(const short8v*)&Kh[off];
                short8v bl_f = *(const short8v*)&Kl[off];
                a = __builtin_amdgcn_mfma_f32_16x16x32_bf16(qfl[kk], bh_f, a, 0, 0, 0);
                a = __builtin_amdgcn_mfma_f32_16x16x32_bf16(qfh[kk], bl_f, a, 0, 0, 0);
                a = __builtin_amdgcn_mfma_f32_16x16x32_bf16(qfh[kk], bh_f, a, 0, 0, 0);
            }
            #pragma unroll
            for (int r = 0; r < 4; ++r) {
                float p = __expf(a[r] * SCALE - rmax_r[r]);
                lsum[r] += p;
                u16 ph = bf16_rne(p);
                u16 pl = bf16_rne(p - __uint_as_float((unsigned)ph << 16));
                int q_l = sl * 4 + r;
                int key = n * 16 + fr;
                int off = q_l * 64 + (((key >> 3) ^ (q_l & 7)) * 8) + (key & 7);
                Ph[wave][off] = ph;
                Pl[wave][off] = pl;
            }
        }

        #pragma unroll
        for (int kk = 0; kk < 2; ++kk) {
            int aoff = fr * 64 + (((kk * 4 + sl) ^ (fr & 7)) * 8);
            short8v pah = *(const short8v*)&Ph[wave][aoff];
            short8v pal = *(const short8v*)&Pl[wave][aoff];
            #pragma unroll
            for (int n = 0; n < 4; ++n) {
                int d = n * 16 + fr;
                int voff = d * 64 + (((kk * 4 + sl) ^ (d & 7)) * 8);
                short8v vhf = *(const short8v*)&Vh[voff];
                short8v vlf = *(const short8v*)&Vl[voff];
                opv[n] = __builtin_amdgcn_mfma_f32_16x16x32_bf16(pal, vhf, opv[n], 0, 0, 0);
                opv[n] = __builtin_amdgcn_mfma_f32_16x16x32_bf16(pah, vlf, opv[n], 0, 0, 0);
                opv[n] = __builtin_amdgcn_mfma_f32_16x16x32_bf16(pah, vhf, opv[n], 0, 0, 0);
            }
        }
    }

    #pragma unroll
    for (int w = 1; w < 16; w <<= 1)
        #pragma unroll
        for (int r = 0; r < 4; ++r)
            lsum[r] += __shfl_xor(lsum[r], w, 64);

    #pragma unroll
    for (int r = 0; r < 4; ++r) {
        const float inv = 1.0f / lsum[r];
        float* orow = attn_out + ((size_t)b * N + qr_o[r]) * C + h * DK;
        #pragma unroll
        for (int n = 0; n < 4; ++n)
            orow[n * 16 + fr] = opv[n][r] * inv;
    }
}

// ---------------------------------------------------------------------------
extern "C" void kernel_launch(void* const* d_in, const int* in_sizes, int n_in,
                              void* d_out, int out_size, void* d_ws, size_t ws_size,
                              hipStream_t stream)
{
    const float* x    = (const float*)d_in[0];
    const float* Wqkv = (const float*)d_in[1];
    const float* bqkv = (const float*)d_in[2];
    const float* Wout = (const float*)d_in[3];
    const float* bout = (const float*)d_in[4];
    float* out = (float*)d_out;

    char* ws = (char*)d_ws;
    size_t off = 0;
    auto alloc = [&](size_t bytes) -> void* {
        void* p = ws + off;
        off += (bytes + 255) & ~(size_t)255;
        return p;
    };

    const size_t BHND = (size_t)B * H * N * DK;       // 4 Mi elems
    float* q        = (float*)alloc(BHND * 4);
    float* kbuf     = (float*)alloc(BHND * 4);
    float* vbuf     = (float*)alloc(BHND * 4);
    float* attn_out = (float*)alloc((size_t)B * N * C * 4);
    u16* cvAhi = (u16*)alloc((size_t)B * N * C * 2);  // x / attn_out hi
    u16* cvAlo = (u16*)alloc((size_t)B * N * C * 2);
    u16* cvBhi = (u16*)alloc((size_t)3 * C * C * 2);
    u16* cvBlo = (u16*)alloc((size_t)3 * C * C * 2);
    u16* qhi   = (u16*)alloc(BHND * 2);
    u16* qlo   = (u16*)alloc(BHND * 2);
    u16* khi   = (u16*)alloc(BHND * 2);
    u16* klo   = (u16*)alloc(BHND * 2);
    u16* vthi  = (u16*)alloc(BHND * 2);
    u16* vtlo  = (u16*)alloc(BHND * 2);
    float* Mbuf     = (float*)alloc((size_t)B * H * N * 4);
    float* rmaxbuf  = (float*)alloc((size_t)B * H * N * 4);
    float* Mdot     = (float*)alloc((size_t)B * H * N * 4);
    int*   keep     = (int*)  alloc((size_t)B * H * N * 4);
    int*   kidx     = (int*)  alloc((size_t)B * H * NTOP * 4);
    float* vmeanbuf = (float*)alloc((size_t)B * H * DK * 4);
    float* kmeanbuf = (float*)alloc((size_t)B * H * DK * 4);
    float* partbuf  = (float*)alloc((size_t)B * H * CSEG * DK * 4);
    float* thrbuf   = (float*)alloc((size_t)B * H * 4);
    int*   cntbuf   = (int*)  alloc((size_t)B * H * 4);
    int*   bandbuf  = (int*)  alloc((size_t)B * H * BAND_CAP * 4);

    const int nX = B * N * C;        // 4M
    const int nW = 3 * C * C;        // 3M
    const int nWo = C * C;           // 1M

    // 1. convert x, Wqkv to bf16 hi/lo
    convert_hilo<<<nX / 1024, 256, 0, stream>>>(x, cvAhi, cvAlo, nX);
    convert_hilo<<<nW / 1024, 256, 0, stream>>>(Wqkv, cvBhi, cvBlo, nW);

    // 2. QKV projection (split-bf16 MFMA + gload staging), scatter q/k/v fp32
    gemm_mfma<0><<<dim3(3 * C / 128, (B * N) / 128), 256, 0, stream>>>(
        cvAhi, cvAlo, cvBhi, cvBlo, bqkv, nullptr, q, kbuf, vbuf, C);

    // 3. convert q,k hi/lo; v transposed hi/lo
    convert_hilo<<<nX / 1024, 256, 0, stream>>>(q, qhi, qlo, nX);
    convert_hilo<<<nX / 1024, 256, 0, stream>>>(kbuf, khi, klo, nX);
    convert_hilo_T<<<dim3(N / 64, B * H), 256, 0, stream>>>(vbuf, vthi, vtlo);

    // 4. column means of v (output fill) and k (exact mean-score term)
    colsum_part<<<dim3(CSEG, B * H), 256, 0, stream>>>(vbuf, partbuf);
    colsum_final<<<B * H, 64, 0, stream>>>(partbuf, vmeanbuf);
    colsum_part<<<dim3(CSEG, B * H), 256, 0, stream>>>(kbuf, partbuf);
    colsum_final<<<B * H, 64, 0, stream>>>(partbuf, kmeanbuf);

    // 5. mean term per row: Mdot = q . kmean
    qdot_kernel<<<dim3(N / 256, B * H), 256, 0, stream>>>(q, kmeanbuf, Mdot);

    // 6. MFMA approximate row max -> M, rowmax
    row_stats_mfma<<<dim3(N / 128, B * H), 256, 0, stream>>>(
        qhi, qlo, khi, klo, Mdot, Mbuf, rmaxbuf);

    // 7. selection: thr -> classify -> fp64 refine (band) -> finalize + kidx
    zero_cnt<<<1, 64, 0, stream>>>(cntbuf);
    topk_thr<<<dim3(N / 256, B * H), 256, 0, stream>>>(Mbuf, thrbuf);
    band_classify<<<dim3(N / 256, B * H), 256, 0, stream>>>(Mbuf, thrbuf, cntbuf, bandbuf, keep);
    refine_kernel<<<dim3(32, B * H), 256, 0, stream>>>(q, kbuf, cntbuf, bandbuf, Mbuf);
    band_finalize<<<B * H, 256, 0, stream>>>(Mbuf, cntbuf, bandbuf, keep, kidx);

    // 8. fill non-kept rows; MFMA attention on kept rows
    fill_nonkept<<<dim3(N / 64, B * H), 256, 0, stream>>>(keep, vmeanbuf, attn_out);
    attn_mfma<<<256, 256, 0, stream>>>(
        qhi, qlo, khi, klo, vthi, vtlo, rmaxbuf, kidx, attn_out);

    // 9. Output projection (split-bf16 MFMA)
    convert_hilo<<<nX / 1024, 256, 0, stream>>>(attn_out, cvAhi, cvAlo, nX);
    convert_hilo<<<nWo / 1024, 256, 0, stream>>>(Wout, cvBhi, cvBlo, nWo);
    gemm_mfma<1><<<dim3(C / 128, (B * N) / 128), 256, 0, stream>>>(
        cvAhi, cvAlo, cvBhi, cvBlo, bout, out, nullptr, nullptr, nullptr, C);
}

// Round 10
// 405.748 us; speedup vs baseline: 6.7823x; 1.0284x over previous
//
#include <hip/hip_runtime.h>
#include <math.h>

typedef unsigned short u16;
typedef __attribute__((ext_vector_type(8))) short short8v;  // 8 bf16 operand frag
typedef __attribute__((ext_vector_type(4))) float f32x4;    // MFMA accumulator

constexpr int B  = 2;
constexpr int N  = 2048;
constexpr int C  = 1024;
constexpr int H  = 16;
constexpr int DK = 64;
constexpr int NTOP = 512;
constexpr float SCALE = 0.125f;  // 1/sqrt(64)
constexpr int   BAND_CAP = 1024;
constexpr float BAND_EPS = 2e-3f;   // covers 3-term split-bf16 M error (~1e-4)
constexpr int   CSEG = 16;          // column-sum segments per bh

// ---------------------------------------------------------------------------
// async global -> LDS, 16B per lane. (verified r8)
// ---------------------------------------------------------------------------
__device__ __forceinline__ void gload16(const u16* g, u16* l) {
    __builtin_amdgcn_global_load_lds(
        (const __attribute__((address_space(1))) unsigned int*)g,
        (__attribute__((address_space(3))) unsigned int*)l,
        16, 0, 0);
}

// ---------------------------------------------------------------------------
// fp32 -> bf16 hi/lo split (RNE)
// ---------------------------------------------------------------------------
__device__ __forceinline__ u16 bf16_rne(float x) {
    unsigned u = __float_as_uint(x);
    unsigned r = u + 0x7fffu + ((u >> 16) & 1u);
    return (u16)(r >> 16);
}

__global__ __launch_bounds__(256) void convert_hilo(
    const float* __restrict__ src, u16* __restrict__ hi, u16* __restrict__ lo, int n)
{
    int i = (blockIdx.x * 256 + threadIdx.x) * 4;
    if (i >= n) return;
    float4 v = *(const float4*)&src[i];
    u16 h0 = bf16_rne(v.x), h1 = bf16_rne(v.y), h2 = bf16_rne(v.z), h3 = bf16_rne(v.w);
    float f0 = __uint_as_float((unsigned)h0 << 16);
    float f1 = __uint_as_float((unsigned)h1 << 16);
    float f2 = __uint_as_float((unsigned)h2 << 16);
    float f3 = __uint_as_float((unsigned)h3 << 16);
    *(ushort4*)&hi[i] = make_ushort4(h0, h1, h2, h3);
    *(ushort4*)&lo[i] = make_ushort4(bf16_rne(v.x - f0), bf16_rne(v.y - f1),
                                     bf16_rne(v.z - f2), bf16_rne(v.w - f3));
}

// two-source variant (q and k in one launch); grid (n/1024, 2)
__global__ __launch_bounds__(256) void convert_hilo2(
    const float* __restrict__ a, const float* __restrict__ b,
    u16* __restrict__ ah, u16* __restrict__ al,
    u16* __restrict__ bh_, u16* __restrict__ bl_, int n)
{
    const float* src = blockIdx.y ? b : a;
    u16* hi = blockIdx.y ? bh_ : ah;
    u16* lo = blockIdx.y ? bl_ : al;
    int i = (blockIdx.x * 256 + threadIdx.x) * 4;
    if (i >= n) return;
    float4 v = *(const float4*)&src[i];
    u16 h0 = bf16_rne(v.x), h1 = bf16_rne(v.y), h2 = bf16_rne(v.z), h3 = bf16_rne(v.w);
    float f0 = __uint_as_float((unsigned)h0 << 16);
    float f1 = __uint_as_float((unsigned)h1 << 16);
    float f2 = __uint_as_float((unsigned)h2 << 16);
    float f3 = __uint_as_float((unsigned)h3 << 16);
    *(ushort4*)&hi[i] = make_ushort4(h0, h1, h2, h3);
    *(ushort4*)&lo[i] = make_ushort4(bf16_rne(v.x - f0), bf16_rne(v.y - f1),
                                     bf16_rne(v.z - f2), bf16_rne(v.w - f3));
}

// ---------------------------------------------------------------------------
// Transposed convert: v (bh, key, d) fp32 -> vt hi/lo (bh, d, key) bf16. (r6)
// ---------------------------------------------------------------------------
__global__ __launch_bounds__(256) void convert_hilo_T(
    const float* __restrict__ v, u16* __restrict__ th, u16* __restrict__ tl)
{
    constexpr int LS = 68;
    __shared__ u16 Sh[64 * LS], Sl[64 * LS];
    const int bh = blockIdx.y;
    const int kt = blockIdx.x * 64;
    const int tid = threadIdx.x;
    #pragma unroll
    for (int p = 0; p < 4; ++p) {
        int idx = tid * 4 + p * 1024;
        int key = idx >> 6, d = idx & 63;
        float4 x4 = *(const float4*)&v[((size_t)bh * N + kt + key) * DK + d];
        float xs[4] = {x4.x, x4.y, x4.z, x4.w};
        ushort4 hh, ll;
        u16* hp = (u16*)&hh; u16* lp = (u16*)&ll;
        #pragma unroll
        for (int j = 0; j < 4; ++j) {
            u16 h = bf16_rne(xs[j]);
            hp[j] = h;
            lp[j] = bf16_rne(xs[j] - __uint_as_float((unsigned)h << 16));
        }
        *(ushort4*)&Sh[key * LS + d] = hh;
        *(ushort4*)&Sl[key * LS + d] = ll;
    }
    __syncthreads();
    const int d = tid >> 2, seg = tid & 3;
    u16 bufh[16], bufl[16];
    #pragma unroll
    for (int i = 0; i < 16; ++i) {
        bufh[i] = Sh[(seg * 16 + i) * LS + d];
        bufl[i] = Sl[(seg * 16 + i) * LS + d];
    }
    size_t oa = ((size_t)bh * DK + d) * N + kt + seg * 16;
    *(uint4*)&th[oa] = ((uint4*)bufh)[0];
    *(uint4*)&th[oa + 8] = ((uint4*)bufh)[1];
    *(uint4*)&tl[oa] = ((uint4*)bufl)[0];
    *(uint4*)&tl[oa + 8] = ((uint4*)bufl)[1];
}

// ---------------------------------------------------------------------------
// Split-bf16 MFMA GEMM, 128x128 tile, gload staging (r8/r9-verified) +
// XCD-bijective block swizzle (1D grid, nwg % 8 == 0).
// ---------------------------------------------------------------------------
template <int MODE>
__global__ __launch_bounds__(256) void gemm_mfma(
    const u16* __restrict__ Ahi, const u16* __restrict__ Alo,
    const u16* __restrict__ Bhi, const u16* __restrict__ Blo,
    const float* __restrict__ bias, float* __restrict__ out,
    float* __restrict__ qb, float* __restrict__ kb, float* __restrict__ vb,
    int K, int ntx)
{
    __shared__ __align__(16) u16 Ah[128 * 32], Al[128 * 32];
    __shared__ __align__(16) u16 Bh[128 * 32], Bl[128 * 32];

    const int nwg = gridDim.x;
    const int cpx = nwg >> 3;
    const int bid = blockIdx.x;
    const int swz = (bid & 7) * cpx + (bid >> 3);
    const int m0 = (swz / ntx) * 128;
    const int n0 = (swz % ntx) * 128;

    const int tid = threadIdx.x;
    const int lane = tid & 63;
    const int wave = tid >> 6;
    const int wr = wave >> 1, wc = wave & 1;
    const int fr = lane & 15, sl = lane >> 4;

    const u16* gsrc = (wave == 0) ? Ahi + (size_t)m0 * K
                    : (wave == 1) ? Alo + (size_t)m0 * K
                    : (wave == 2) ? Bhi + (size_t)n0 * K
                                  : Blo + (size_t)n0 * K;
    u16* lbase = (wave == 0) ? Ah : (wave == 1) ? Al : (wave == 2) ? Bh : Bl;

    f32x4 acc[4][4] = {};

    for (int k0 = 0; k0 < K; k0 += 32) {
        __syncthreads();
        #pragma unroll
        for (int i = 0; i < 8; ++i) {
            int c = i * 64 + lane;               // chunk = 16B = 8 u16
            int row = c >> 2, sp = c & 3;
            int gs = sp ^ ((row >> 1) & 3);
            gload16(gsrc + (size_t)row * K + k0 + gs * 8, lbase + i * 512);
        }
        __syncthreads();

        short8v afh[4], afl[4], bfh[4], bfl[4];
        #pragma unroll
        for (int m = 0; m < 4; ++m) {
            int row = wr * 64 + m * 16 + fr;
            int off = row * 32 + ((sl ^ ((row >> 1) & 3)) * 8);
            afh[m] = *(const short8v*)&Ah[off];
            afl[m] = *(const short8v*)&Al[off];
        }
        #pragma unroll
        for (int n = 0; n < 4; ++n) {
            int row = wc * 64 + n * 16 + fr;
            int off = row * 32 + ((sl ^ ((row >> 1) & 3)) * 8);
            bfh[n] = *(const short8v*)&Bh[off];
            bfl[n] = *(const short8v*)&Bl[off];
        }
        #pragma unroll
        for (int m = 0; m < 4; ++m)
            #pragma unroll
            for (int n = 0; n < 4; ++n) {
                acc[m][n] = __builtin_amdgcn_mfma_f32_16x16x32_bf16(afh[m], bfh[n], acc[m][n], 0, 0, 0);
                acc[m][n] = __builtin_amdgcn_mfma_f32_16x16x32_bf16(afh[m], bfl[n], acc[m][n], 0, 0, 0);
                acc[m][n] = __builtin_amdgcn_mfma_f32_16x16x32_bf16(afl[m], bfh[n], acc[m][n], 0, 0, 0);
            }
    }

    #pragma unroll
    for (int m = 0; m < 4; ++m)
        #pragma unroll
        for (int n = 0; n < 4; ++n)
            #pragma unroll
            for (int r = 0; r < 4; ++r) {
                int grow = m0 + wr * 64 + m * 16 + sl * 4 + r;
                int gcol = n0 + wc * 64 + n * 16 + fr;
                float val = acc[m][n][r] + bias[gcol];
                if (MODE == 0) {
                    int t = gcol >> 10, h = (gcol >> 6) & 15, d = gcol & 63;
                    int bb = grow >> 11, nn = grow & (N - 1);
                    float* dst = (t == 0) ? qb : (t == 1) ? kb : vb;
                    dst[(((size_t)bb * H + h) * N + nn) * DK + d] = val;
                } else {
                    out[(size_t)grow * C + gcol] = val;
                }
            }
}

// ---------------------------------------------------------------------------
// Column sums over v and k in one launch.  grid (CSEG, B*H, 2), z: 0=v 1=k.
// ---------------------------------------------------------------------------
__global__ __launch_bounds__(256) void colsum_part2(
    const float* __restrict__ v, const float* __restrict__ k,
    float* __restrict__ partial)
{
    const int bh = blockIdx.y, seg = blockIdx.x, which = blockIdx.z;
    const float* src = which ? k : v;
    const int d = threadIdx.x & 63;
    const int sub = threadIdx.x >> 6;
    const int k0 = seg * (N / CSEG);
    float s = 0.f;
    for (int kk = sub; kk < N / CSEG; kk += 4)
        s += src[((size_t)bh * N + k0 + kk) * DK + d];
    __shared__ float part[4][64];
    part[sub][d] = s;
    __syncthreads();
    if (threadIdx.x < 64)
        partial[(((size_t)which * B * H + bh) * CSEG + seg) * DK + d] =
            part[0][d] + part[1][d] + part[2][d] + part[3][d];
}

// grid (B*H), 128 threads: tid<64 -> vmean, tid>=64 -> kmean
__global__ __launch_bounds__(128) void colsum_final2(
    const float* __restrict__ partial, float* __restrict__ vmean,
    float* __restrict__ kmean)
{
    const int bh = blockIdx.x;
    const int d = threadIdx.x & 63;
    const int which = threadIdx.x >> 6;
    const float* p = partial + ((size_t)which * B * H + bh) * CSEG * DK;
    float s = 0.f;
    #pragma unroll
    for (int g = 0; g < CSEG; ++g) s += p[g * DK + d];
    float* dst = which ? kmean : vmean;
    dst[bh * DK + d] = s / (float)N;
}

// ---------------------------------------------------------------------------
// Mdot[bh,row] = dot(q_row, kmean_bh)
// ---------------------------------------------------------------------------
__global__ __launch_bounds__(256) void qdot_kernel(
    const float* __restrict__ q, const float* __restrict__ kmean,
    float* __restrict__ Mdot)
{
    const int bh = blockIdx.y;
    const int row = blockIdx.x * 256 + threadIdx.x;
    __shared__ float km[DK];
    if (threadIdx.x < DK) km[threadIdx.x] = kmean[bh * DK + threadIdx.x];
    __syncthreads();
    const float* qr = &q[((size_t)bh * N + row) * DK];
    float s = 0.f;
    #pragma unroll
    for (int d4 = 0; d4 < DK; d4 += 4) {
        float4 v = *(const float4*)&qr[d4];
        s += v.x * km[d4] + v.y * km[d4 + 1] + v.z * km[d4 + 2] + v.w * km[d4 + 3];
    }
    Mdot[(size_t)bh * N + row] = s;
}

// ---------------------------------------------------------------------------
// MFMA row-max (3-term), gload staging + XCD swizzle (1D grid, 512 blocks).
// ---------------------------------------------------------------------------
__global__ __launch_bounds__(256) void row_stats_mfma(
    const u16* __restrict__ qh_, const u16* __restrict__ ql_,
    const u16* __restrict__ kh_, const u16* __restrict__ kl_,
    const float* __restrict__ Mdot, float* __restrict__ Mout,
    float* __restrict__ rowmax)
{
    __shared__ __align__(16) u16 Kh[64 * 64];
    __shared__ __align__(16) u16 Kl[64 * 64];
    const int tid = threadIdx.x, lane = tid & 63, wave = tid >> 6;

    const int nwg = gridDim.x;             // 512
    const int cpx = nwg >> 3;              // 64 = 4 bh per XCD chunk
    const int bid = blockIdx.x;
    const int swz = (bid & 7) * cpx + (bid >> 3);
    const int bh = swz >> 4;
    const int q0 = (swz & 15) * 128 + wave * 32;
    const int fr = lane & 15, g = lane >> 4;

    const u16* gsrc = (wave & 2) ? kl_ : kh_;
    u16* lbase = (wave & 2) ? Kl : Kh;
    const int cb = (wave & 1) * 256;

    short8v qfh[2][2], qfl[2][2];
    #pragma unroll
    for (int m = 0; m < 2; ++m)
        #pragma unroll
        for (int kk = 0; kk < 2; ++kk) {
            size_t qa = ((size_t)bh * N + q0 + m * 16 + fr) * DK + kk * 32 + g * 8;
            qfh[m][kk] = *(const short8v*)&qh_[qa];
            qfl[m][kk] = *(const short8v*)&ql_[qa];
        }

    f32x4 mx[2];
    mx[0] = (f32x4){-1e30f, -1e30f, -1e30f, -1e30f};
    mx[1] = mx[0];

    for (int kt = 0; kt < N; kt += 64) {
        __syncthreads();
        #pragma unroll
        for (int i = 0; i < 4; ++i) {
            int c = cb + i * 64 + lane;
            int row = c >> 3, sp = c & 7;
            int gs = sp ^ (row & 7);
            gload16(gsrc + ((size_t)bh * N + kt + row) * DK + gs * 8,
                    lbase + (size_t)(cb + i * 64) * 8);
        }
        __syncthreads();
        short8v bfh[4][2], bfl[4][2];
        #pragma unroll
        for (int n = 0; n < 4; ++n)
            #pragma unroll
            for (int kk = 0; kk < 2; ++kk) {
                int key = n * 16 + fr;
                int off = key * 64 + (((g + kk * 4) ^ (key & 7)) * 8);
                bfh[n][kk] = *(const short8v*)&Kh[off];
                bfl[n][kk] = *(const short8v*)&Kl[off];
            }
        #pragma unroll
        for (int m = 0; m < 2; ++m)
            #pragma unroll
            for (int n = 0; n < 4; ++n) {
                f32x4 a = {};
                #pragma unroll
                for (int kk = 0; kk < 2; ++kk) {
                    a = __builtin_amdgcn_mfma_f32_16x16x32_bf16(qfl[m][kk], bfh[n][kk], a, 0, 0, 0);
                    a = __builtin_amdgcn_mfma_f32_16x16x32_bf16(qfh[m][kk], bfl[n][kk], a, 0, 0, 0);
                    a = __builtin_amdgcn_mfma_f32_16x16x32_bf16(qfh[m][kk], bfh[n][kk], a, 0, 0, 0);
                }
                #pragma unroll
                for (int r = 0; r < 4; ++r) mx[m][r] = fmaxf(mx[m][r], a[r]);
            }
    }

    #pragma unroll
    for (int w = 1; w < 16; w <<= 1)
        #pragma unroll
        for (int m = 0; m < 2; ++m)
            #pragma unroll
            for (int r = 0; r < 4; ++r)
                mx[m][r] = fmaxf(mx[m][r], __shfl_xor(mx[m][r], w, 64));

    if (fr == 0) {
        #pragma unroll
        for (int m = 0; m < 2; ++m)
            #pragma unroll
            for (int r = 0; r < 4; ++r) {
                int row = q0 + m * 16 + g * 4 + r;
                size_t idx = (size_t)bh * N + row;
                float v = mx[m][r];
                rowmax[idx] = SCALE * v;
                Mout[idx]   = SCALE * (v - Mdot[idx]);
            }
    }
}

// ---------------------------------------------------------------------------
// Selection (r9-verified): thr -> classify -> fp64 refine (band) -> finalize.
// cnt zero-init folded into topk_thr.
// ---------------------------------------------------------------------------
__global__ __launch_bounds__(256) void topk_thr(
    const float* __restrict__ Mv, float* __restrict__ thr, int* __restrict__ cnt)
{
    const int bh = blockIdx.y;
    const int qi = blockIdx.x * 256 + threadIdx.x;
    if (blockIdx.x == 0 && threadIdx.x == 0) cnt[bh] = 0;
    __shared__ float Ms[N];
    for (int e = threadIdx.x; e < N; e += 256) Ms[e] = Mv[(size_t)bh * N + e];
    __syncthreads();
    const float mq = Ms[qi];
    int rank = 0;
    for (int j = 0; j < N; ++j) {
        float mj = Ms[j];
        rank += (mj > mq) || (mj == mq && j < qi);
    }
    if (rank == NTOP - 1) thr[bh] = mq;   // smallest kept (approx boundary)
}

__global__ __launch_bounds__(256) void band_classify(
    const float* __restrict__ Mv, const float* __restrict__ thr,
    int* __restrict__ cnt, int* __restrict__ band, int* __restrict__ keep)
{
    const int bh = blockIdx.y;
    const int row = blockIdx.x * 256 + threadIdx.x;
    const float m = Mv[(size_t)bh * N + row];
    const float t = thr[bh];
    int kp;
    if (fabsf(m - t) <= BAND_EPS) {
        int pos = atomicAdd(&cnt[bh], 1);
        if (pos < BAND_CAP) band[bh * BAND_CAP + pos] = row;
        kp = 0;
    } else {
        kp = (m > t) ? 1 : 0;
    }
    keep[(size_t)bh * N + row] = kp;
}

__global__ __launch_bounds__(256) void refine_kernel(
    const float* __restrict__ q, const float* __restrict__ k,
    const int* __restrict__ cnt, const int* __restrict__ band,
    float* __restrict__ Mv)
{
    constexpr int LS = 69;
    __shared__ float Ks[64 * LS];
    __shared__ float qs[DK];
    const int bh = blockIdx.y;
    const int tid = threadIdx.x;
    const int n = min(cnt[bh], BAND_CAP);
    for (int ci = blockIdx.x; ci < n; ci += 32) {
        const int row = band[bh * BAND_CAP + ci];
        __syncthreads();
        if (tid < DK) qs[tid] = q[((size_t)bh * N + row) * DK + tid];
        double mx = -1e30, sm = 0.0;
        for (int kt = 0; kt < N; kt += 64) {
            __syncthreads();
            #pragma unroll
            for (int p = 0; p < 4; ++p) {
                int idx = tid * 4 + p * 1024;
                int kr = idx >> 6, d = idx & 63;
                float4 x4 = *(const float4*)&k[((size_t)bh * N + kt + kr) * DK + d];
                Ks[kr * LS + d]     = x4.x;
                Ks[kr * LS + d + 1] = x4.y;
                Ks[kr * LS + d + 2] = x4.z;
                Ks[kr * LS + d + 3] = x4.w;
            }
            __syncthreads();
            if (tid < 64) {
                double s = 0.0;
                #pragma unroll
                for (int d = 0; d < DK; ++d)
                    s += (double)qs[d] * (double)Ks[tid * LS + d];
                mx = fmax(mx, s);
                sm += s;
            }
        }
        if (tid < 64) {
            #pragma unroll
            for (int w = 1; w < 64; w <<= 1) {
                mx = fmax(mx, __shfl_xor(mx, w, 64));
                sm += __shfl_xor(sm, w, 64);
            }
            if (tid == 0)
                Mv[(size_t)bh * N + row] = (float)((double)SCALE * (mx - sm / (double)N));
        }
    }
}

__global__ __launch_bounds__(256) void band_finalize(
    const float* __restrict__ Mv, const int* __restrict__ cnt,
    const int* __restrict__ band, int* __restrict__ keep,
    int* __restrict__ kidx)
{
    __shared__ unsigned char kL[N];
    __shared__ int   bRow[BAND_CAP];
    __shared__ float bM[BAND_CAP];
    __shared__ int aW[4];
    __shared__ int scan[256];

    const int bh = blockIdx.x;
    const int tid = threadIdx.x;
    const int lane = tid & 63, wid = tid >> 6;
    const int nb = min(cnt[bh], BAND_CAP);

    int above = 0;
    #pragma unroll
    for (int w = 0; w < 8; ++w) {
        int row = w * 256 + tid;
        int kp = keep[(size_t)bh * N + row];
        kL[row] = (unsigned char)kp;
        above += kp;
    }
    #pragma unroll
    for (int w = 1; w < 64; w <<= 1) above += __shfl_xor(above, w, 64);
    if (lane == 0) aW[wid] = above;
    for (int i = tid; i < nb; i += 256) {
        int r = band[bh * BAND_CAP + i];
        bRow[i] = r;
        bM[i] = Mv[(size_t)bh * N + r];
    }
    __syncthreads();
    const int nAbove = aW[0] + aW[1] + aW[2] + aW[3];

    for (int i = tid; i < nb; i += 256) {
        const float mi = bM[i];
        const int ri = bRow[i];
        int rank = nAbove;
        for (int j = 0; j < nb; ++j) {
            float mj = bM[j];
            rank += (mj > mi) || (mj == mi && bRow[j] < ri);
        }
        int kp = (rank < NTOP) ? 1 : 0;
        kL[ri] = (unsigned char)kp;
        keep[(size_t)bh * N + ri] = kp;
    }
    __syncthreads();

    int cntL = 0;
    #pragma unroll
    for (int r = 0; r < 8; ++r) cntL += kL[tid * 8 + r];
    scan[tid] = cntL;
    __syncthreads();
    for (int s = 1; s < 256; s <<= 1) {
        int v = (tid >= s) ? scan[tid - s] : 0;
        __syncthreads();
        scan[tid] += v;
        __syncthreads();
    }
    int pos = scan[tid] - cntL;
    #pragma unroll
    for (int r = 0; r < 8; ++r) {
        int row = tid * 8 + r;
        if (kL[row]) kidx[bh * NTOP + pos++] = row;
    }
}

// ---------------------------------------------------------------------------
// Fill non-kept rows of attn_out with vmean. grid (N/64, B*H)
// ---------------------------------------------------------------------------
__global__ __launch_bounds__(256) void fill_nonkept(
    const int* __restrict__ keep, const float* __restrict__ vmean,
    float* __restrict__ attn_out)
{
    const int bh = blockIdx.y;
    const int b = bh >> 4, h = bh & 15;
    const int d = threadIdx.x & 63;
    const int rr = threadIdx.x >> 6;
    const float vm = vmean[bh * DK + d];
    #pragma unroll
    for (int i = 0; i < 16; ++i) {
        int row = blockIdx.x * 64 + i * 4 + rr;
        if (!keep[(size_t)bh * N + row])
            attn_out[((size_t)b * N + row) * C + h * DK + d] = vm;
    }
}

// ---------------------------------------------------------------------------
// MFMA attention on kept rows; gload staging (r8/r9-verified) + setprio (T5).
// ---------------------------------------------------------------------------
__global__ __launch_bounds__(256) void attn_mfma(
    const u16* __restrict__ qh_, const u16* __restrict__ ql_,
    const u16* __restrict__ kh_, const u16* __restrict__ kl_,
    const u16* __restrict__ vth_, const u16* __restrict__ vtl_,
    const float* __restrict__ rowmax, const int* __restrict__ kidx,
    float* __restrict__ attn_out)
{
    __shared__ __align__(16) u16 Kh[64 * 64], Kl[64 * 64];
    __shared__ __align__(16) u16 Vh[64 * 64], Vl[64 * 64];
    __shared__ __align__(16) u16 Ph[4][16 * 64], Pl[4][16 * 64];

    const int tid = threadIdx.x, lane = tid & 63, wave = tid >> 6;
    const int wg = blockIdx.x;
    const int bh = ((wg >> 6) << 3) | (wg & 7);
    const int xblk = (wg >> 3) & 7;
    const int b = bh >> 4, h = bh & 15;
    const int q0 = xblk * 64 + wave * 16;
    const int fr = lane & 15, sl = lane >> 4;

    const bool isV = (wave >= 2);
    const u16* ksrc = (wave & 1) ? kl_ : kh_;
    const u16* vsrc = (wave & 1) ? vtl_ : vth_;
    u16* lbase = (wave == 0) ? Kh : (wave == 1) ? Kl : (wave == 2) ? Vh : Vl;
    const size_t kbase0 = (size_t)bh * N * DK;
    const size_t vbase0 = (size_t)bh * DK * N;

    const int* kix = kidx + bh * NTOP;
    const int qrow_f = kix[q0 + fr];
    int qr_o[4]; float rmax_r[4];
    #pragma unroll
    for (int r = 0; r < 4; ++r) {
        qr_o[r] = kix[q0 + sl * 4 + r];
        rmax_r[r] = rowmax[(size_t)bh * N + qr_o[r]];
    }

    short8v qfh[2], qfl[2];
    #pragma unroll
    for (int kk = 0; kk < 2; ++kk) {
        size_t qa = ((size_t)bh * N + qrow_f) * DK + kk * 32 + sl * 8;
        qfh[kk] = *(const short8v*)&qh_[qa];
        qfl[kk] = *(const short8v*)&ql_[qa];
    }

    f32x4 opv[4] = {};
    float lsum[4] = {};

    for (int kt = 0; kt < N; kt += 64) {
        __syncthreads();
        #pragma unroll
        for (int i = 0; i < 8; ++i) {
            int c = i * 64 + lane;
            int row = c >> 3, sp = c & 7;
            int gs = sp ^ (row & 7);
            const u16* g = isV ? (vsrc + vbase0 + (size_t)row * N + kt + gs * 8)
                               : (ksrc + kbase0 + (size_t)(kt + row) * DK + gs * 8);
            gload16(g, lbase + (size_t)i * 512);
        }
        __syncthreads();

        #pragma unroll
        for (int n = 0; n < 4; ++n) {
            f32x4 a = {};
            __builtin_amdgcn_s_setprio(1);
            #pragma unroll
            for (int kk = 0; kk < 2; ++kk) {
                int key = n * 16 + fr;
                int off = key * 64 + (((sl + kk * 4) ^ (key & 7)) * 8);
                short8v bh_f = *(const short8v*)&Kh[off];
                short8v bl_f = *(const short8v*)&Kl[off];
                a = __builtin_amdgcn_mfma_f32_16x16x32_bf16(qfl[kk], bh_f, a, 0, 0, 0);
                a = __builtin_amdgcn_mfma_f32_16x16x32_bf16(qfh[kk], bl_f, a, 0, 0, 0);
                a = __builtin_amdgcn_mfma_f32_16x16x32_bf16(qfh[kk], bh_f, a, 0, 0, 0);
            }
            __builtin_amdgcn_s_setprio(0);
            #pragma unroll
            for (int r = 0; r < 4; ++r) {
                float p = __expf(a[r] * SCALE - rmax_r[r]);
                lsum[r] += p;
                u16 ph = bf16_rne(p);
                u16 pl = bf16_rne(p - __uint_as_float((unsigned)ph << 16));
                int q_l = sl * 4 + r;
                int key = n * 16 + fr;
                int off = q_l * 64 + (((key >> 3) ^ (q_l & 7)) * 8) + (key & 7);
                Ph[wave][off] = ph;
                Pl[wave][off] = pl;
            }
        }

        __builtin_amdgcn_s_setprio(1);
        #pragma unroll
        for (int kk = 0; kk < 2; ++kk) {
            int aoff = fr * 64 + (((kk * 4 + sl) ^ (fr & 7)) * 8);
            short8v pah = *(const short8v*)&Ph[wave][aoff];
            short8v pal = *(const short8v*)&Pl[wave][aoff];
            #pragma unroll
            for (int n = 0; n < 4; ++n) {
                int d = n * 16 + fr;
                int voff = d * 64 + (((kk * 4 + sl) ^ (d & 7)) * 8);
                short8v vhf = *(const short8v*)&Vh[voff];
                short8v vlf = *(const short8v*)&Vl[voff];
                opv[n] = __builtin_amdgcn_mfma_f32_16x16x32_bf16(pal, vhf, opv[n], 0, 0, 0);
                opv[n] = __builtin_amdgcn_mfma_f32_16x16x32_bf16(pah, vlf, opv[n], 0, 0, 0);
                opv[n] = __builtin_amdgcn_mfma_f32_16x16x32_bf16(pah, vhf, opv[n], 0, 0, 0);
            }
        }
        __builtin_amdgcn_s_setprio(0);
    }

    #pragma unroll
    for (int w = 1; w < 16; w <<= 1)
        #pragma unroll
        for (int r = 0; r < 4; ++r)
            lsum[r] += __shfl_xor(lsum[r], w, 64);

    #pragma unroll
    for (int r = 0; r < 4; ++r) {
        const float inv = 1.0f / lsum[r];
        float* orow = attn_out + ((size_t)b * N + qr_o[r]) * C + h * DK;
        #pragma unroll
        for (int n = 0; n < 4; ++n)
            orow[n * 16 + fr] = opv[n][r] * inv;
    }
}

// ---------------------------------------------------------------------------
extern "C" void kernel_launch(void* const* d_in, const int* in_sizes, int n_in,
                              void* d_out, int out_size, void* d_ws, size_t ws_size,
                              hipStream_t stream)
{
    const float* x    = (const float*)d_in[0];
    const float* Wqkv = (const float*)d_in[1];
    const float* bqkv = (const float*)d_in[2];
    const float* Wout = (const float*)d_in[3];
    const float* bout = (const float*)d_in[4];
    float* out = (float*)d_out;

    char* ws = (char*)d_ws;
    size_t off = 0;
    auto alloc = [&](size_t bytes) -> void* {
        void* p = ws + off;
        off += (bytes + 255) & ~(size_t)255;
        return p;
    };

    const size_t BHND = (size_t)B * H * N * DK;       // 4 Mi elems
    float* q        = (float*)alloc(BHND * 4);
    float* kbuf     = (float*)alloc(BHND * 4);
    float* vbuf     = (float*)alloc(BHND * 4);
    float* attn_out = (float*)alloc((size_t)B * N * C * 4);
    u16* cvAhi = (u16*)alloc((size_t)B * N * C * 2);  // x / attn_out hi
    u16* cvAlo = (u16*)alloc((size_t)B * N * C * 2);
    u16* cvBhi = (u16*)alloc((size_t)3 * C * C * 2);
    u16* cvBlo = (u16*)alloc((size_t)3 * C * C * 2);
    u16* qhi   = (u16*)alloc(BHND * 2);
    u16* qlo   = (u16*)alloc(BHND * 2);
    u16* khi   = (u16*)alloc(BHND * 2);
    u16* klo   = (u16*)alloc(BHND * 2);
    u16* vthi  = (u16*)alloc(BHND * 2);
    u16* vtlo  = (u16*)alloc(BHND * 2);
    float* Mbuf     = (float*)alloc((size_t)B * H * N * 4);
    float* rmaxbuf  = (float*)alloc((size_t)B * H * N * 4);
    float* Mdot     = (float*)alloc((size_t)B * H * N * 4);
    int*   keep     = (int*)  alloc((size_t)B * H * N * 4);
    int*   kidx     = (int*)  alloc((size_t)B * H * NTOP * 4);
    float* vmeanbuf = (float*)alloc((size_t)B * H * DK * 4);
    float* kmeanbuf = (float*)alloc((size_t)B * H * DK * 4);
    float* partbuf  = (float*)alloc((size_t)2 * B * H * CSEG * DK * 4);
    float* thrbuf   = (float*)alloc((size_t)B * H * 4);
    int*   cntbuf   = (int*)  alloc((size_t)B * H * 4);
    int*   bandbuf  = (int*)  alloc((size_t)B * H * BAND_CAP * 4);

    const int nX = B * N * C;        // 4M
    const int nW = 3 * C * C;        // 3M
    const int nWo = C * C;           // 1M

    // 1. convert x, Wqkv to bf16 hi/lo
    convert_hilo<<<nX / 1024, 256, 0, stream>>>(x, cvAhi, cvAlo, nX);
    convert_hilo<<<nW / 1024, 256, 0, stream>>>(Wqkv, cvBhi, cvBlo, nW);

    // 2. QKV projection (XCD-swizzled 1D grid: 24*32 = 768 blocks, 768%8==0)
    gemm_mfma<0><<<768, 256, 0, stream>>>(
        cvAhi, cvAlo, cvBhi, cvBlo, bqkv, nullptr, q, kbuf, vbuf, C, 24);

    // 3. convert q,k hi/lo (one launch); v transposed hi/lo
    convert_hilo2<<<dim3(nX / 1024, 2), 256, 0, stream>>>(
        q, kbuf, qhi, qlo, khi, klo, nX);
    convert_hilo_T<<<dim3(N / 64, B * H), 256, 0, stream>>>(vbuf, vthi, vtlo);

    // 4. column means of v and k (fused)
    colsum_part2<<<dim3(CSEG, B * H, 2), 256, 0, stream>>>(vbuf, kbuf, partbuf);
    colsum_final2<<<B * H, 128, 0, stream>>>(partbuf, vmeanbuf, kmeanbuf);

    // 5. mean term per row: Mdot = q . kmean
    qdot_kernel<<<dim3(N / 256, B * H), 256, 0, stream>>>(q, kmeanbuf, Mdot);

    // 6. MFMA approximate row max -> M, rowmax (XCD-swizzled 1D grid)
    row_stats_mfma<<<512, 256, 0, stream>>>(
        qhi, qlo, khi, klo, Mdot, Mbuf, rmaxbuf);

    // 7. selection: thr (+cnt init) -> classify -> fp64 refine -> finalize
    topk_thr<<<dim3(N / 256, B * H), 256, 0, stream>>>(Mbuf, thrbuf, cntbuf);
    band_classify<<<dim3(N / 256, B * H), 256, 0, stream>>>(Mbuf, thrbuf, cntbuf, bandbuf, keep);
    refine_kernel<<<dim3(32, B * H), 256, 0, stream>>>(q, kbuf, cntbuf, bandbuf, Mbuf);
    band_finalize<<<B * H, 256, 0, stream>>>(Mbuf, cntbuf, bandbuf, keep, kidx);

    // 8. fill non-kept rows; MFMA attention on kept rows
    fill_nonkept<<<dim3(N / 64, B * H), 256, 0, stream>>>(keep, vmeanbuf, attn_out);
    attn_mfma<<<256, 256, 0, stream>>>(
        qhi, qlo, khi, klo, vthi, vtlo, rmaxbuf, kidx, attn_out);

    // 9. Output projection (XCD-swizzled 1D grid: 8*32 = 256 blocks)
    convert_hilo<<<nX / 1024, 256, 0, stream>>>(attn_out, cvAhi, cvAlo, nX);
    convert_hilo<<<nWo / 1024, 256, 0, stream>>>(Wout, cvBhi, cvBlo, nWo);
    gemm_mfma<1><<<256, 256, 0, stream>>>(
        cvAhi, cvAlo, cvBhi, cvBlo, bout, out, nullptr, nullptr, nullptr, C, 8);
}